// Round 1
// 2172.232 us; speedup vs baseline: 1.4096x; 1.4096x over previous
//
#include <hip/hip_runtime.h>

#define NN 100000
#define EE 1000000
#define DDIM 192
#define NLAYER 6
#define TRAIN 8192
#define SLOPE 0.01f
#define EPS_LN 1e-5f
#define TOTSEG (2 * NN)
#define SCAN_NB 98           /* ceil(200000 / 2048) */

typedef float f32x4 __attribute__((ext_vector_type(4)));
typedef __bf16 bf16x8 __attribute__((ext_vector_type(8)));
typedef unsigned short ushort_t;
typedef unsigned int uint_t;

__device__ __forceinline__ float lrelu(float v) { return v > 0.0f ? v : SLOPE * v; }

__device__ __forceinline__ ushort_t f2bf(float f) {
    union { float f; uint_t u; } v; v.f = f;
    uint_t u = v.u;
    u += 0x7fffu + ((u >> 16) & 1u);   // RNE
    return (ushort_t)(u >> 16);
}

__device__ __forceinline__ float bf2f(ushort_t b) {
    union { uint_t u; float f; } v; v.u = ((uint_t)b) << 16; return v.f;
}

__device__ __forceinline__ float wave_sum(float s) {
    #pragma unroll
    for (int off = 32; off > 0; off >>= 1) s += __shfl_down(s, off);
    return __shfl(s, 0);
}

// ---------------------------------------------------------------------------
// One-shot weight prep: transpose + convert to bf16.  WT[m][k] = W[k][m].
// Wroot+Wrel go into the concat matrix WTg[m][576] = [Wroot^T | W0^T | W1^T].
// ---------------------------------------------------------------------------
__global__ __launch_bounds__(256) void prep_w(
    const float* __restrict__ Wt, const float* __restrict__ Wv,
    const float* __restrict__ Wo, const float* __restrict__ W1,
    const float* __restrict__ W2, const float* __restrict__ Wrel,
    const float* __restrict__ Wroot, const float* __restrict__ Wm1,
    const float* __restrict__ Wm2, ushort_t* __restrict__ WTt,
    ushort_t* __restrict__ WTs, ushort_t* __restrict__ WTg)
{
    const int bid = blockIdx.x;
    if (bid < 29 * 144) {
        const int mat = bid / 144;
        const int o = (bid % 144) * 256 + threadIdx.x;   // < 36864
        const float* src;
        if      (mat <  6) src = Wv   + (size_t)mat * 36864;
        else if (mat < 12) src = Wo   + (size_t)(mat - 6)  * 36864;
        else if (mat < 18) src = W1   + (size_t)(mat - 12) * 36864;
        else if (mat < 24) src = W2   + (size_t)(mat - 18) * 36864;
        else if (mat < 26) src = Wrel + (size_t)(mat - 24) * 36864;
        else if (mat == 26) src = Wroot;
        else if (mat == 27) src = Wm1;
        else                src = Wm2;
        const int m = o / 192, k = o - m * 192;
        const ushort_t b = f2bf(src[(size_t)k * 192 + m]);
        if (mat == 24 || mat == 25)
            WTg[(size_t)m * 576 + 192 + (mat - 24) * 192 + k] = b;
        else if (mat == 26)
            WTg[(size_t)m * 576 + k] = b;
        else
            WTs[(size_t)mat * 36864 + o] = b;
    } else {
        const int o = (bid - 29 * 144) * 256 + threadIdx.x;  // < 49152
        const int m = o / 768, k = o - m * 768;
        WTt[o] = f2bf(Wt[(size_t)k * 64 + m]);
    }
}

// ---------------------------------------------------------------------------
// Single MFMA GEMM (kept for the tweet embedding, K=768, M=64).
// ---------------------------------------------------------------------------
template <int NFRAG, bool BIAS, bool RELU>
__global__ __launch_bounds__(256) void gemm_mfma(
    const float* __restrict__ A, const ushort_t* __restrict__ WT,
    const float* __restrict__ bias, float* __restrict__ C,
    int n, int K, int ldc)
{
    __shared__ ushort_t As[128 * 32];
    __shared__ ushort_t Ws[NFRAG * 16 * 32];
    const int tid = threadIdx.x;
    const int lane = tid & 63, w = tid >> 6;
    const int quad = lane >> 4, l15 = lane & 15;
    const int row0 = blockIdx.x * 128;

    f32x4 acc[2][NFRAG];
    #pragma unroll
    for (int m = 0; m < 2; ++m)
        #pragma unroll
        for (int nf = 0; nf < NFRAG; ++nf)
            acc[m][nf] = (f32x4){0.f, 0.f, 0.f, 0.f};

    const int srow = tid >> 1, shalf = tid & 1;
    const bool arow_ok = (row0 + srow) < n;
    const float* aptr = A + (size_t)(row0 + srow) * K + shalf * 16;
    const int ktiles = K >> 5;

    float f[16];
    if (arow_ok) {
        const float4* p = (const float4*)aptr;
        #pragma unroll
        for (int i = 0; i < 4; ++i) {
            const float4 t4 = p[i];
            f[i * 4 + 0] = t4.x; f[i * 4 + 1] = t4.y;
            f[i * 4 + 2] = t4.z; f[i * 4 + 3] = t4.w;
        }
    } else {
        #pragma unroll
        for (int i = 0; i < 16; ++i) f[i] = 0.f;
    }

    for (int t = 0; t < ktiles; ++t) {
        const int k0 = t << 5;
        uint_t u[8];
        #pragma unroll
        for (int i = 0; i < 8; ++i)
            u[i] = (uint_t)f2bf(f[2 * i]) | ((uint_t)f2bf(f[2 * i + 1]) << 16);
        uint4* dsta = (uint4*)&As[srow * 32 + shalf * 16];
        dsta[0] = make_uint4(u[0], u[1], u[2], u[3]);
        dsta[1] = make_uint4(u[4], u[5], u[6], u[7]);

        #pragma unroll
        for (int s = tid; s < NFRAG * 64; s += 256) {
            const int col = s >> 2, part = s & 3;
            *(uint4*)&Ws[col * 32 + part * 8] =
                *(const uint4*)(WT + (size_t)col * K + k0 + part * 8);
        }
        __syncthreads();

        float fn_[16];
        const bool more = (t + 1 < ktiles);
        if (more) {
            if (arow_ok) {
                const float4* p = (const float4*)(aptr + k0 + 32);
                #pragma unroll
                for (int i = 0; i < 4; ++i) {
                    const float4 t4 = p[i];
                    fn_[i * 4 + 0] = t4.x; fn_[i * 4 + 1] = t4.y;
                    fn_[i * 4 + 2] = t4.z; fn_[i * 4 + 3] = t4.w;
                }
            } else {
                #pragma unroll
                for (int i = 0; i < 16; ++i) fn_[i] = 0.f;
            }
        }

        const bf16x8 a0 = *(const bf16x8*)&As[(w * 32 + l15) * 32 + quad * 8];
        const bf16x8 a1 = *(const bf16x8*)&As[(w * 32 + 16 + l15) * 32 + quad * 8];
        #pragma unroll
        for (int nf = 0; nf < NFRAG; ++nf) {
            const bf16x8 b = *(const bf16x8*)&Ws[(nf * 16 + l15) * 32 + quad * 8];
            acc[0][nf] = __builtin_amdgcn_mfma_f32_16x16x32_bf16(a0, b, acc[0][nf], 0, 0, 0);
            acc[1][nf] = __builtin_amdgcn_mfma_f32_16x16x32_bf16(a1, b, acc[1][nf], 0, 0, 0);
        }
        __syncthreads();
        if (more) {
            #pragma unroll
            for (int i = 0; i < 16; ++i) f[i] = fn_[i];
        }
    }

    #pragma unroll
    for (int m = 0; m < 2; ++m) {
        #pragma unroll
        for (int reg = 0; reg < 4; ++reg) {
            const int gr = row0 + w * 32 + m * 16 + quad * 4 + reg;
            if (gr >= n) continue;
            #pragma unroll
            for (int nf = 0; nf < NFRAG; ++nf) {
                const int col = nf * 16 + l15;
                float x = acc[m][nf][reg] + (BIAS ? bias[col] : 0.f);
                if (RELU) x = lrelu(x);
                C[(size_t)gr * ldc + col] = x;
            }
        }
    }
}

// ---------------------------------------------------------------------------
// Fused double GEMM: C = epi2( epi1(A@Wa + ba) @ Wb + bb [+ res] ).
// Intermediate (128x192) lives in LDS as bf16 (same rounding point as the
// old global round trip).  BM=128, K=M=192 fixed, 4 waves, NFRAG=12.
// Vs row stride 200 ushorts => 16B granules hit 8 distinct bank slots (floor).
// ---------------------------------------------------------------------------
template <bool RELU1, bool RELU2, bool RES, bool LNORM, bool BNIN,
          bool BNRES, bool BNSTAT, bool CBF>
__global__ __launch_bounds__(256, 2) void gemm2_mfma(
    const float* __restrict__ A, const ushort_t* __restrict__ wta,
    const float* __restrict__ bias1, const ushort_t* __restrict__ wtb,
    const float* __restrict__ bias2, const float* __restrict__ res,
    float* __restrict__ C, ushort_t* __restrict__ Cbf,
    const float* __restrict__ bns, float* __restrict__ bnacc,
    const float* __restrict__ lg, const float* __restrict__ lb, int n)
{
    constexpr int VST = 200;
    __shared__ ushort_t Vs[128 * VST];   // 51200 B; front 8 KB doubles as As
    __shared__ ushort_t Ws[192 * 32];    // 12288 B; doubles as bsum after use
    ushort_t* As = Vs;
    const int tid = threadIdx.x;
    const int lane = tid & 63, w = tid >> 6;
    const int quad = lane >> 4, l15 = lane & 15;
    const int row0 = blockIdx.x * 128;

    f32x4 acc[2][12];
    #pragma unroll
    for (int m = 0; m < 2; ++m)
        #pragma unroll
        for (int nf = 0; nf < 12; ++nf)
            acc[m][nf] = (f32x4){0.f, 0.f, 0.f, 0.f};

    const int srow = tid >> 1, shalf = tid & 1;
    const bool arow_ok = (row0 + srow) < n;
    const float* aptr = A + (size_t)(row0 + srow) * DDIM + shalf * 16;

    float f[16];
    if (arow_ok) {
        const float4* p = (const float4*)aptr;
        #pragma unroll
        for (int i = 0; i < 4; ++i) {
            const float4 t4 = p[i];
            f[i * 4 + 0] = t4.x; f[i * 4 + 1] = t4.y;
            f[i * 4 + 2] = t4.z; f[i * 4 + 3] = t4.w;
        }
    } else {
        #pragma unroll
        for (int i = 0; i < 16; ++i) f[i] = 0.f;
    }

    // ---------------- phase 1: acc = A @ Wa ----------------
    #pragma unroll 1
    for (int t = 0; t < 6; ++t) {
        const int k0 = t << 5;
        if (BNIN) {
            const float4* scp = (const float4*)(bns + 2 * DDIM + k0 + shalf * 16);
            const float4* shp = (const float4*)(bns + 3 * DDIM + k0 + shalf * 16);
            #pragma unroll
            for (int i = 0; i < 4; ++i) {
                const float4 sc = scp[i], sh = shp[i];
                f[i * 4 + 0] = fmaf(f[i * 4 + 0], sc.x, sh.x);
                f[i * 4 + 1] = fmaf(f[i * 4 + 1], sc.y, sh.y);
                f[i * 4 + 2] = fmaf(f[i * 4 + 2], sc.z, sh.z);
                f[i * 4 + 3] = fmaf(f[i * 4 + 3], sc.w, sh.w);
            }
        }
        uint_t u[8];
        #pragma unroll
        for (int i = 0; i < 8; ++i)
            u[i] = (uint_t)f2bf(f[2 * i]) | ((uint_t)f2bf(f[2 * i + 1]) << 16);
        uint4* dsta = (uint4*)&As[srow * 32 + shalf * 16];
        dsta[0] = make_uint4(u[0], u[1], u[2], u[3]);
        dsta[1] = make_uint4(u[4], u[5], u[6], u[7]);

        #pragma unroll
        for (int s = tid; s < 768; s += 256) {
            const int col = s >> 2, part = s & 3;
            *(uint4*)&Ws[col * 32 + part * 8] =
                *(const uint4*)(wta + (size_t)col * DDIM + k0 + part * 8);
        }
        __syncthreads();

        float fn_[16];
        const bool more = (t < 5);
        if (more) {
            if (arow_ok) {
                const float4* p = (const float4*)(aptr + k0 + 32);
                #pragma unroll
                for (int i = 0; i < 4; ++i) {
                    const float4 t4 = p[i];
                    fn_[i * 4 + 0] = t4.x; fn_[i * 4 + 1] = t4.y;
                    fn_[i * 4 + 2] = t4.z; fn_[i * 4 + 3] = t4.w;
                }
            } else {
                #pragma unroll
                for (int i = 0; i < 16; ++i) fn_[i] = 0.f;
            }
        }

        const bf16x8 a0 = *(const bf16x8*)&As[(w * 32 + l15) * 32 + quad * 8];
        const bf16x8 a1 = *(const bf16x8*)&As[(w * 32 + 16 + l15) * 32 + quad * 8];
        #pragma unroll
        for (int nf = 0; nf < 12; ++nf) {
            const bf16x8 b = *(const bf16x8*)&Ws[(nf * 16 + l15) * 32 + quad * 8];
            acc[0][nf] = __builtin_amdgcn_mfma_f32_16x16x32_bf16(a0, b, acc[0][nf], 0, 0, 0);
            acc[1][nf] = __builtin_amdgcn_mfma_f32_16x16x32_bf16(a1, b, acc[1][nf], 0, 0, 0);
        }
        __syncthreads();
        if (more) {
            #pragma unroll
            for (int i = 0; i < 16; ++i) f[i] = fn_[i];
        }
    }

    // ---- phase-1 epilogue: bias (+relu) -> Vs bf16; re-zero acc
    {
        float b1r[12];
        #pragma unroll
        for (int nf = 0; nf < 12; ++nf) b1r[nf] = bias1[nf * 16 + l15];
        #pragma unroll
        for (int m = 0; m < 2; ++m) {
            #pragma unroll
            for (int reg = 0; reg < 4; ++reg) {
                ushort_t* vrow = &Vs[(w * 32 + m * 16 + quad * 4 + reg) * VST + l15];
                #pragma unroll
                for (int nf = 0; nf < 12; ++nf) {
                    float x = acc[m][nf][reg] + b1r[nf];
                    if (RELU1) x = lrelu(x);
                    vrow[nf * 16] = f2bf(x);
                    acc[m][nf][reg] = 0.f;
                }
            }
        }
    }
    __syncthreads();

    // ---------------- phase 2: acc = V @ Wb ----------------
    #pragma unroll 1
    for (int t = 0; t < 6; ++t) {
        const int k0 = t << 5;
        #pragma unroll
        for (int s = tid; s < 768; s += 256) {
            const int col = s >> 2, part = s & 3;
            *(uint4*)&Ws[col * 32 + part * 8] =
                *(const uint4*)(wtb + (size_t)col * DDIM + k0 + part * 8);
        }
        __syncthreads();
        const bf16x8 a0 = *(const bf16x8*)&Vs[(w * 32 + l15) * VST + k0 + quad * 8];
        const bf16x8 a1 = *(const bf16x8*)&Vs[(w * 32 + 16 + l15) * VST + k0 + quad * 8];
        #pragma unroll
        for (int nf = 0; nf < 12; ++nf) {
            const bf16x8 b = *(const bf16x8*)&Ws[(nf * 16 + l15) * 32 + quad * 8];
            acc[0][nf] = __builtin_amdgcn_mfma_f32_16x16x32_bf16(a0, b, acc[0][nf], 0, 0, 0);
            acc[1][nf] = __builtin_amdgcn_mfma_f32_16x16x32_bf16(a1, b, acc[1][nf], 0, 0, 0);
        }
        __syncthreads();
    }

    // ---------------- phase-2 epilogue ----------------
    int   col[12];
    float bia[12];
    #pragma unroll
    for (int nf = 0; nf < 12; ++nf) {
        col[nf] = nf * 16 + l15;
        bia[nf] = bias2[col[nf]];
    }
    float rsc[12], rsh[12];
    if (BNRES) {
        #pragma unroll
        for (int nf = 0; nf < 12; ++nf) {
            rsc[nf] = bns[2 * DDIM + col[nf]];
            rsh[nf] = bns[3 * DDIM + col[nf]];
        }
    }
    float cs[12], cs2[12];
    if (BNSTAT) {
        #pragma unroll
        for (int nf = 0; nf < 12; ++nf) { cs[nf] = 0.f; cs2[nf] = 0.f; }
    }
    #pragma unroll
    for (int m = 0; m < 2; ++m) {
        #pragma unroll
        for (int reg = 0; reg < 4; ++reg) {
            const int gr = row0 + w * 32 + m * 16 + quad * 4 + reg;
            const bool ok = gr < n;
            float v[12];
            #pragma unroll
            for (int nf = 0; nf < 12; ++nf) {
                float x = acc[m][nf][reg] + bia[nf];
                if (RES) {
                    float r = ok ? res[(size_t)gr * DDIM + col[nf]] : 0.f;
                    if (BNRES) r = fmaf(r, rsc[nf], rsh[nf]);
                    x += r;
                }
                v[nf] = x;
            }
            if (LNORM) {
                float s = 0.f, s2 = 0.f;
                #pragma unroll
                for (int nf = 0; nf < 12; ++nf) { s += v[nf]; s2 = fmaf(v[nf], v[nf], s2); }
                #pragma unroll
                for (int off = 1; off < 16; off <<= 1) {
                    s  += __shfl_xor(s, off);
                    s2 += __shfl_xor(s2, off);
                }
                const float mu = s * (1.0f / DDIM);
                const float var = s2 * (1.0f / DDIM) - mu * mu;
                const float rs = rsqrtf(var + EPS_LN);
                #pragma unroll
                for (int nf = 0; nf < 12; ++nf)
                    v[nf] = fmaf((v[nf] - mu) * rs, lg[col[nf]], lb[col[nf]]);
            }
            #pragma unroll
            for (int nf = 0; nf < 12; ++nf) {
                float x = v[nf];
                if (RELU2) x = lrelu(x);
                if (BNSTAT) {
                    const float xa = ok ? x : 0.f;
                    cs[nf] += xa;
                    cs2[nf] = fmaf(xa, xa, cs2[nf]);
                }
                if (ok) {
                    C[(size_t)gr * DDIM + col[nf]] = x;
                    if (CBF) Cbf[(size_t)gr * DDIM + col[nf]] = f2bf(x);
                }
            }
        }
    }
    if (BNSTAT) {
        float* bsA = (float*)Ws;            // [4][192], aliases Ws (reads done)
        float* bsB = bsA + 4 * 192;
        #pragma unroll
        for (int nf = 0; nf < 12; ++nf) {
            cs[nf]  += __shfl_xor(cs[nf], 16);  cs[nf]  += __shfl_xor(cs[nf], 32);
            cs2[nf] += __shfl_xor(cs2[nf], 16); cs2[nf] += __shfl_xor(cs2[nf], 32);
        }
        if (quad == 0) {
            #pragma unroll
            for (int nf = 0; nf < 12; ++nf) {
                bsA[w * 192 + col[nf]] = cs[nf];
                bsB[w * 192 + col[nf]] = cs2[nf];
            }
        }
        __syncthreads();
        if (tid < DDIM) {
            const float s  = bsA[tid] + bsA[192 + tid] + bsA[384 + tid] + bsA[576 + tid];
            const float s2 = bsB[tid] + bsB[192 + tid] + bsB[384 + tid] + bsB[576 + tid];
            atomicAdd(&bnacc[tid], s);
            atomicAdd(&bnacc[DDIM + tid], s2);
        }
    }
}

// ---------------------------------------------------------------------------
// RGCN concat GEMM: C = [A1(bf16, K=192) | A2(bf16, K=384)] @ WT[192][576] + b
// ---------------------------------------------------------------------------
template <bool CBF>
__global__ __launch_bounds__(256) void gemm_cat(
    const ushort_t* __restrict__ A1, const ushort_t* __restrict__ A2,
    const ushort_t* __restrict__ WT, const float* __restrict__ bias,
    float* __restrict__ C, ushort_t* __restrict__ Cbf, int n)
{
    __shared__ ushort_t As[128 * 32];
    __shared__ ushort_t Ws[192 * 32];
    const int tid = threadIdx.x;
    const int lane = tid & 63, w = tid >> 6;
    const int quad = lane >> 4, l15 = lane & 15;
    const int row0 = blockIdx.x * 128;

    f32x4 acc[2][12];
    #pragma unroll
    for (int m = 0; m < 2; ++m)
        #pragma unroll
        for (int nf = 0; nf < 12; ++nf)
            acc[m][nf] = (f32x4){0.f, 0.f, 0.f, 0.f};

    const int srow = tid >> 1, shalf = tid & 1;
    const bool arow_ok = (row0 + srow) < n;
    const ushort_t* a1p = A1 + (size_t)(row0 + srow) * 192 + shalf * 16;
    const ushort_t* a2p = A2 + (size_t)(row0 + srow) * 384 + shalf * 16;

    uint_t u[8];
    if (arow_ok) {
        const uint4* p = (const uint4*)a1p;
        const uint4 q0 = p[0], q1 = p[1];
        u[0] = q0.x; u[1] = q0.y; u[2] = q0.z; u[3] = q0.w;
        u[4] = q1.x; u[5] = q1.y; u[6] = q1.z; u[7] = q1.w;
    } else {
        #pragma unroll
        for (int i = 0; i < 8; ++i) u[i] = 0u;
    }

    #pragma unroll 1
    for (int t = 0; t < 18; ++t) {
        uint4* dsta = (uint4*)&As[srow * 32 + shalf * 16];
        dsta[0] = make_uint4(u[0], u[1], u[2], u[3]);
        dsta[1] = make_uint4(u[4], u[5], u[6], u[7]);

        #pragma unroll
        for (int s = tid; s < 768; s += 256) {
            const int col = s >> 2, part = s & 3;
            *(uint4*)&Ws[col * 32 + part * 8] =
                *(const uint4*)(WT + (size_t)col * 576 + t * 32 + part * 8);
        }
        __syncthreads();

        uint_t un[8];
        const bool more = (t < 17);
        if (more) {
            if (arow_ok) {
                const int tn = t + 1;
                const ushort_t* np = (tn < 6) ? (a1p + tn * 32)
                                              : (a2p + (tn - 6) * 32);
                const uint4* p = (const uint4*)np;
                const uint4 q0 = p[0], q1 = p[1];
                un[0] = q0.x; un[1] = q0.y; un[2] = q0.z; un[3] = q0.w;
                un[4] = q1.x; un[5] = q1.y; un[6] = q1.z; un[7] = q1.w;
            } else {
                #pragma unroll
                for (int i = 0; i < 8; ++i) un[i] = 0u;
            }
        }

        const bf16x8 a0 = *(const bf16x8*)&As[(w * 32 + l15) * 32 + quad * 8];
        const bf16x8 a1 = *(const bf16x8*)&As[(w * 32 + 16 + l15) * 32 + quad * 8];
        #pragma unroll
        for (int nf = 0; nf < 12; ++nf) {
            const bf16x8 b = *(const bf16x8*)&Ws[(nf * 16 + l15) * 32 + quad * 8];
            acc[0][nf] = __builtin_amdgcn_mfma_f32_16x16x32_bf16(a0, b, acc[0][nf], 0, 0, 0);
            acc[1][nf] = __builtin_amdgcn_mfma_f32_16x16x32_bf16(a1, b, acc[1][nf], 0, 0, 0);
        }
        __syncthreads();
        if (more) {
            #pragma unroll
            for (int i = 0; i < 8; ++i) u[i] = un[i];
        }
    }

    #pragma unroll
    for (int m = 0; m < 2; ++m) {
        #pragma unroll
        for (int reg = 0; reg < 4; ++reg) {
            const int gr = row0 + w * 32 + m * 16 + quad * 4 + reg;
            if (gr >= n) continue;
            #pragma unroll
            for (int nf = 0; nf < 12; ++nf) {
                const int col = nf * 16 + l15;
                const float x = acc[m][nf][reg] + bias[col];
                C[(size_t)gr * DDIM + col] = x;
                if (CBF) Cbf[(size_t)gr * DDIM + col] = f2bf(x);
            }
        }
    }
}

// ---------------------------------------------------------------------------
__global__ __launch_bounds__(256) void embed_nc_k(
    const float* __restrict__ np_, const float* __restrict__ cp,
    const float* __restrict__ Wn, const float* __restrict__ bnum,
    const float* __restrict__ Wc, const float* __restrict__ bc,
    float* __restrict__ x)
{
    const int idx = blockIdx.x * 256 + threadIdx.x;
    if (idx >= NN * 128) return;
    const int node = idx >> 7;
    const int c = idx & 127;
    float acc;
    if (c < 64) {
        acc = bnum[c];
        #pragma unroll
        for (int k = 0; k < 6; ++k) acc = fmaf(np_[node * 6 + k], Wn[k * 64 + c], acc);
    } else {
        const int cc = c - 64;
        acc = bc[cc];
        #pragma unroll
        for (int k = 0; k < 7; ++k) acc = fmaf(cp[node * 7 + k], Wc[k * 64 + cc], acc);
    }
    x[(size_t)node * DDIM + 64 + c] = lrelu(acc);
}

__global__ __launch_bounds__(192) void bn_fin_k(float* __restrict__ bns,
    const float* __restrict__ g, const float* __restrict__ b)
{
    const int j = threadIdx.x;
    const float invN = 1.0f / (float)NN;
    const float mu = bns[j] * invN;
    const float var = bns[DDIM + j] * invN - mu * mu;
    const float sc = g[j] * rsqrtf(var + EPS_LN);
    bns[2 * DDIM + j] = sc;
    bns[3 * DDIM + j] = fmaf(-mu, sc, b[j]);
}

// ---------------------------------------------------------------------------
// Contrastive: fnorm -> bf16 rows, MFMA sim, closs
// ---------------------------------------------------------------------------
__global__ __launch_bounds__(256) void fnorm_k(const float* __restrict__ x,
                                               ushort_t* __restrict__ fnb)
{
    const int wave = threadIdx.x >> 6, lane = threadIdx.x & 63;
    const int row = blockIdx.x * 4 + wave;
    if (row >= TRAIN) return;
    const float* xr = x + (size_t)row * DDIM;
    const float v0 = xr[lane], v1 = xr[lane + 64], v2 = xr[lane + 128];
    const float q = wave_sum(v0 * v0 + v1 * v1 + v2 * v2);
    const float inv = 1.0f / sqrtf(q);
    ushort_t* fr = fnb + (size_t)row * DDIM;
    fr[lane]       = f2bf(v0 * inv);
    fr[lane + 64]  = f2bf(v1 * inv);
    fr[lane + 128] = f2bf(v2 * inv);
}

__global__ __launch_bounds__(256) void sim_mfma(const ushort_t* __restrict__ fnb,
    const int* __restrict__ lab, float* __restrict__ row_ex, float* __restrict__ row_mt)
{
    __shared__ ushort_t Ai[128 * 32];
    __shared__ ushort_t Bj[128 * 32];
    __shared__ int Li[128], Lj[128];
    const int tid = threadIdx.x, lane = tid & 63, w = tid >> 6;
    const int quad = lane >> 4, l15 = lane & 15;
    const int i0 = blockIdx.x * 128, j0 = blockIdx.y * 128;
    if (tid < 128) Li[tid] = lab[i0 + tid];
    else           Lj[tid - 128] = lab[j0 + tid - 128];
    const int iw = (w >> 1) * 64, jw = (w & 1) * 64;

    f32x4 acc[4][4];
    #pragma unroll
    for (int m = 0; m < 4; ++m)
        #pragma unroll
        for (int nf = 0; nf < 4; ++nf)
            acc[m][nf] = (f32x4){0.f, 0.f, 0.f, 0.f};

    for (int k0 = 0; k0 < DDIM; k0 += 32) {
        #pragma unroll
        for (int s = tid; s < 512; s += 256) {
            const int row = s >> 2, part = s & 3;
            *(uint4*)&Ai[row * 32 + part * 8] =
                *(const uint4*)(fnb + (size_t)(i0 + row) * DDIM + k0 + part * 8);
            *(uint4*)&Bj[row * 32 + part * 8] =
                *(const uint4*)(fnb + (size_t)(j0 + row) * DDIM + k0 + part * 8);
        }
        __syncthreads();
        bf16x8 a[4], b[4];
        #pragma unroll
        for (int m = 0; m < 4; ++m)
            a[m] = *(const bf16x8*)&Ai[(iw + m * 16 + l15) * 32 + quad * 8];
        #pragma unroll
        for (int nf = 0; nf < 4; ++nf)
            b[nf] = *(const bf16x8*)&Bj[(jw + nf * 16 + l15) * 32 + quad * 8];
        #pragma unroll
        for (int m = 0; m < 4; ++m)
            #pragma unroll
            for (int nf = 0; nf < 4; ++nf)
                acc[m][nf] = __builtin_amdgcn_mfma_f32_16x16x32_bf16(a[m], b[nf], acc[m][nf], 0, 0, 0);
        __syncthreads();
    }

    int lj[4];
    #pragma unroll
    for (int nf = 0; nf < 4; ++nf) lj[nf] = Lj[jw + nf * 16 + l15];
    #pragma unroll
    for (int m = 0; m < 4; ++m) {
        #pragma unroll
        for (int reg = 0; reg < 4; ++reg) {
            const int rl = iw + m * 16 + quad * 4 + reg;
            const int li = Li[rl];
            float se = 0.f, sm = 0.f;
            #pragma unroll
            for (int nf = 0; nf < 4; ++nf) {
                const float e = __expf(acc[m][nf][reg] * 2.0f);  // 1/TEMP = 2
                se += e;
                if (li == lj[nf]) sm += e;
            }
            #pragma unroll
            for (int off = 1; off < 16; off <<= 1) {
                se += __shfl_xor(se, off);
                sm += __shfl_xor(sm, off);
            }
            if (l15 == 0) {
                atomicAdd(&row_ex[i0 + rl], se);
                atomicAdd(&row_mt[i0 + rl], sm);
            }
        }
    }
}

__global__ __launch_bounds__(256) void closs_k(const float* __restrict__ ex,
    const float* __restrict__ mt, float* __restrict__ out)
{
    float s = 0.f;
    for (int i = threadIdx.x; i < TRAIN; i += 256) s += -logf(mt[i] / ex[i]);
    s = wave_sum(s);
    __shared__ float red[4];
    const int wave = threadIdx.x >> 6, lane = threadIdx.x & 63;
    if (lane == 0) red[wave] = s;
    __syncthreads();
    if (threadIdx.x == 0) out[0] = (red[0] + red[1] + red[2] + red[3]) / (float)TRAIN;
}

// ---------------------------------------------------------------------------
// CSR build: counts -> 3-kernel parallel exclusive scan -> fill.
// ---------------------------------------------------------------------------
__global__ __launch_bounds__(256) void cnt_i_k(const int* __restrict__ dst,
    const int* __restrict__ ety, int* __restrict__ cnti)
{
    const int e = blockIdx.x * 256 + threadIdx.x;
    if (e >= EE) return;
    atomicAdd(&cnti[(size_t)ety[e] * NN + dst[e]], 1);
}

__global__ __launch_bounds__(256) void part_k(const int* __restrict__ cnti,
                                              int* __restrict__ part)
{
    __shared__ int sh[256];
    const int tid = threadIdx.x;
    const int i0 = blockIdx.x * 2048 + tid * 8;
    int s = 0;
    #pragma unroll
    for (int j = 0; j < 8; ++j) {
        const int i = i0 + j;
        s += (i < TOTSEG) ? cnti[i] : 0;
    }
    sh[tid] = s;
    __syncthreads();
    #pragma unroll
    for (int off = 128; off > 0; off >>= 1) {
        if (tid < off) sh[tid] += sh[tid + off];
        __syncthreads();
    }
    if (tid == 0) part[blockIdx.x] = sh[0];
}

__global__ __launch_bounds__(128) void scanp_k(int* __restrict__ part)
{
    __shared__ int sh[128];
    const int tid = threadIdx.x;
    const int v = (tid < SCAN_NB) ? part[tid] : 0;
    sh[tid] = v;
    __syncthreads();
    #pragma unroll
    for (int off = 1; off < 128; off <<= 1) {
        const int t = (tid >= off) ? sh[tid - off] : 0;
        __syncthreads();
        sh[tid] += t;
        __syncthreads();
    }
    if (tid < SCAN_NB) part[tid] = sh[tid] - v;   // exclusive
}

__global__ __launch_bounds__(256) void offs_k(const int* __restrict__ cnti,
    const int* __restrict__ part, int* __restrict__ offs)
{
    __shared__ int sh[256];
    const int tid = threadIdx.x;
    const int i0 = blockIdx.x * 2048 + tid * 8;
    int v[8];
    int loc = 0;
    #pragma unroll
    for (int j = 0; j < 8; ++j) {
        const int i = i0 + j;
        v[j] = (i < TOTSEG) ? cnti[i] : 0;
        loc += v[j];
    }
    sh[tid] = loc;
    __syncthreads();
    #pragma unroll
    for (int off = 1; off < 256; off <<= 1) {
        const int t = (tid >= off) ? sh[tid - off] : 0;
        __syncthreads();
        sh[tid] += t;
        __syncthreads();
    }
    int pre = part[blockIdx.x] + sh[tid] - loc;
    #pragma unroll
    for (int j = 0; j < 8; ++j) {
        const int i = i0 + j;
        if (i < TOTSEG) offs[i] = pre;
        pre += v[j];
    }
}

__global__ __launch_bounds__(256) void fill_k(const int* __restrict__ src,
    const int* __restrict__ dst, const int* __restrict__ ety,
    int* __restrict__ offs, int* __restrict__ elist)
{
    const int e = blockIdx.x * 256 + threadIdx.x;
    if (e >= EE) return;
    const int pos = atomicAdd(&offs[(size_t)ety[e] * NN + dst[e]], 1);
    elist[pos] = src[e];
}

// ---------------------------------------------------------------------------
// Gather (bf16 in, bf16 out): AGGB[d][r*192+c] = mean of xb[src][c] (bf16).
// ---------------------------------------------------------------------------
__global__ __launch_bounds__(256) void gather_bf_k(const ushort_t* __restrict__ xb,
    const int* __restrict__ elist, const int* __restrict__ offs,
    const int* __restrict__ cnti, ushort_t* __restrict__ aggb)
{
    const int wave = threadIdx.x >> 6, lane = threadIdx.x & 63;
    const int d = blockIdx.x * 4 + wave;
    if (d >= NN) return;
    #pragma unroll
    for (int r = 0; r < 2; ++r) {
        const int seg = r * NN + d;
        const int end = offs[seg];
        const int c = cnti[seg];
        float a0 = 0.f, a1 = 0.f, a2 = 0.f;
        for (int e = end - c; e < end; ++e) {
            const int s = elist[e];
            const ushort_t* xr = xb + (size_t)s * DDIM;
            a0 += bf2f(xr[lane]); a1 += bf2f(xr[lane + 64]); a2 += bf2f(xr[lane + 128]);
        }
        const float inv = 1.0f / (float)max(c, 1);
        ushort_t* ar = aggb + (size_t)d * 384 + r * DDIM;
        ar[lane]       = f2bf(a0 * inv);
        ar[lane + 64]  = f2bf(a1 * inv);
        ar[lane + 128] = f2bf(a2 * inv);
    }
}

__global__ __launch_bounds__(256) void logits_k(const float* __restrict__ h,
    const float* __restrict__ Wm3, const float* __restrict__ bm3, float* __restrict__ out)
{
    const int wave = threadIdx.x >> 6, lane = threadIdx.x & 63;
    const int row = blockIdx.x * 4 + wave;
    if (row >= NN) return;
    const float* hr = h + (size_t)row * DDIM;
    float s0 = 0.f, s1 = 0.f;
    #pragma unroll
    for (int p = 0; p < 3; ++p) {
        const int k = lane + p * 64;
        const float v = hr[k];
        s0 = fmaf(v, Wm3[k * 2 + 0], s0);
        s1 = fmaf(v, Wm3[k * 2 + 1], s1);
    }
    #pragma unroll
    for (int off = 32; off > 0; off >>= 1) {
        s0 += __shfl_down(s0, off);
        s1 += __shfl_down(s1, off);
    }
    if (lane == 0) {
        out[(size_t)row * 2 + 0] = s0 + bm3[0];
        out[(size_t)row * 2 + 1] = s1 + bm3[1];
    }
}

// ---------------------------------------------------------------------------
extern "C" void kernel_launch(void* const* d_in, const int* in_sizes, int n_in,
                              void* d_out, int out_size, void* d_ws, size_t ws_size,
                              hipStream_t stream)
{
    const float* tweet   = (const float*)d_in[0];
    const float* np_     = (const float*)d_in[1];
    const float* cp      = (const float*)d_in[2];
    const float* Wt      = (const float*)d_in[3];
    const float* bt      = (const float*)d_in[4];
    const float* Wn      = (const float*)d_in[5];
    const float* bnum    = (const float*)d_in[6];
    const float* Wc      = (const float*)d_in[7];
    const float* bc      = (const float*)d_in[8];
    const float* Wv      = (const float*)d_in[9];
    const float* bv      = (const float*)d_in[10];
    const float* Wo      = (const float*)d_in[11];
    const float* bo      = (const float*)d_in[12];
    const float* ln1g    = (const float*)d_in[13];
    const float* ln1b    = (const float*)d_in[14];
    const float* bng     = (const float*)d_in[15];
    const float* bnb     = (const float*)d_in[16];
    const float* W1      = (const float*)d_in[17];
    const float* b1      = (const float*)d_in[18];
    const float* W2      = (const float*)d_in[19];
    const float* b2      = (const float*)d_in[20];
    const float* ln2g    = (const float*)d_in[21];
    const float* ln2b    = (const float*)d_in[22];
    const float* Wrel    = (const float*)d_in[23];
    const float* Wroot   = (const float*)d_in[24];
    const float* rgcnb   = (const float*)d_in[25];
    const float* Wm1     = (const float*)d_in[26];
    const float* bm1     = (const float*)d_in[27];
    const float* Wm2     = (const float*)d_in[28];
    const float* bm2     = (const float*)d_in[29];
    const float* Wm3     = (const float*)d_in[30];
    const float* bm3     = (const float*)d_in[31];
    const int*   eidx    = (const int*)d_in[32];
    const int*   esrc    = eidx;
    const int*   edst    = eidx + EE;
    const int*   ety     = (const int*)d_in[33];
    const int*   labels  = (const int*)d_in[34];
    float* out = (float*)d_out;

    float* ws = (float*)d_ws;
    const size_t ND = (size_t)NN * DDIM;
    float* B0    = ws;
    float* B1    = B0 + ND;       // (unused after fusion; kept for layout)
    float* B2    = B1 + ND;       // pair1 output; AGGB (bf16) during RGCN; MLP out
    float* B3    = B2 + ND;       // front: XBF (bf16 x/h); then WTg
    float* ROWEX = B3 + ND;
    float* ROWMT = ROWEX + TRAIN;
    float* BNS   = ROWMT + TRAIN;             // [sum | sumsq | scale | shift]
    int*   CNTI  = (int*)(BNS + 4 * DDIM);    // 2*NN
    int*   OFFS  = CNTI + 2 * NN;             // 2*NN (becomes end-offsets)
    int*   ELIST = OFFS + 2 * NN;             // EE
    int*   PART  = ELIST + EE;                // 128
    ushort_t* FNb = (ushort_t*)(PART + 128);
    ushort_t* WTt = FNb + (size_t)TRAIN * DDIM;   // 64x768
    ushort_t* WTs = WTt + 49152;                  // 29 x 36864 (24/25/26 unused)
    ushort_t* WTv    = WTs;
    ushort_t* WTo    = WTs + (size_t)6  * 36864;
    ushort_t* WT1    = WTs + (size_t)12 * 36864;
    ushort_t* WT2    = WTs + (size_t)18 * 36864;
    ushort_t* WTm1   = WTs + (size_t)27 * 36864;
    ushort_t* WTm2   = WTs + (size_t)28 * 36864;
    ushort_t* XBF  = (ushort_t*)B3;               // NN x 192 bf16
    ushort_t* WTg  = (ushort_t*)B3 + ND;          // 192 x 576 bf16 (in B3 tail)
    ushort_t* AGGB = (ushort_t*)B2;               // NN x 384 bf16 (RGCN only)

    const int gx = (NN + 127) / 128;   // 782
    const dim3 blk(256);

    prep_w<<<29 * 144 + 192, blk, 0, stream>>>(Wt, Wv, Wo, W1, W2, Wrel, Wroot, Wm1, Wm2, WTt, WTs, WTg);

    // ---- CSR build (edge structure only; reused by both RGCN layers)
    hipMemsetAsync(CNTI, 0, 2 * NN * sizeof(int), stream);
    cnt_i_k<<<(EE + 255) / 256, blk, 0, stream>>>(edst, ety, CNTI);
    part_k<<<SCAN_NB, blk, 0, stream>>>(CNTI, PART);
    scanp_k<<<1, 128, 0, stream>>>(PART);
    offs_k<<<SCAN_NB, blk, 0, stream>>>(CNTI, PART, OFFS);
    fill_k<<<(EE + 255) / 256, blk, 0, stream>>>(esrc, edst, ety, OFFS, ELIST);

    // ---- input embedding
    gemm_mfma<4, true, true><<<gx, blk, 0, stream>>>(tweet, WTt, bt, B0, NN, 768, DDIM);
    embed_nc_k<<<(NN * 128 + 255) / 256, blk, 0, stream>>>(np_, cp, Wn, bnum, Wc, bc, B0);

    // ---- 6 layers, each = 2 fused double-GEMMs + BN finalize
    for (int i = 0; i < NLAYER; ++i) {
        const size_t wo = (size_t)i * 36864;
        hipMemsetAsync(BNS, 0, 2 * DDIM * sizeof(float), stream);
        // B2 = ln1(B0 + (B0@Wv+bv)@Wo + bo), BN-stat accumulate
        gemm2_mfma<false, false, true, true, false, false, true, false><<<gx, blk, 0, stream>>>(
            B0, WTv + wo, bv + i * DDIM, WTo + wo, bo + i * DDIM,
            B0, B2, nullptr, nullptr, BNS, ln1g + i * DDIM, ln1b + i * DDIM, NN);
        bn_fin_k<<<1, dim3(192), 0, stream>>>(BNS, bng + i * DDIM, bnb + i * DDIM);
        // B0 = ln2(bn(B2) + lrelu(bn(B2)@W1+b1)@W2 + b2); last layer also emits bf16 x
        if (i < NLAYER - 1)
            gemm2_mfma<true, false, true, true, true, true, false, false><<<gx, blk, 0, stream>>>(
                B2, WT1 + wo, b1 + i * DDIM, WT2 + wo, b2 + i * DDIM,
                B2, B0, nullptr, BNS, nullptr, ln2g + i * DDIM, ln2b + i * DDIM, NN);
        else
            gemm2_mfma<true, false, true, true, true, true, false, true><<<gx, blk, 0, stream>>>(
                B2, WT1 + wo, b1 + i * DDIM, WT2 + wo, b2 + i * DDIM,
                B2, B0, XBF, BNS, nullptr, ln2g + i * DDIM, ln2b + i * DDIM, NN);
    }

    // ---- contrastive loss (before RGCN so B2/B3 can be reused)
    hipMemsetAsync(ROWEX, 0, 2 * TRAIN * sizeof(float), stream);
    fnorm_k<<<TRAIN / 4, blk, 0, stream>>>(B0, FNb);
    sim_mfma<<<dim3(TRAIN / 128, TRAIN / 128), blk, 0, stream>>>(FNb, labels, ROWEX, ROWMT);
    closs_k<<<1, blk, 0, stream>>>(ROWEX, ROWMT, out + 2 * (size_t)NN);

    // ---- RGCN pass 1: h = [x | agg(x)] @ [Wroot; Wcat] + b   (also emits bf16 h)
    gather_bf_k<<<(NN + 3) / 4, blk, 0, stream>>>(XBF, ELIST, OFFS, CNTI, AGGB);
    gemm_cat<true><<<gx, blk, 0, stream>>>(XBF, AGGB, WTg, rgcnb, B0, XBF, NN);

    // ---- RGCN pass 2
    gather_bf_k<<<(NN + 3) / 4, blk, 0, stream>>>(XBF, ELIST, OFFS, CNTI, AGGB);
    gemm_cat<false><<<gx, blk, 0, stream>>>(XBF, AGGB, WTg, rgcnb, B0, nullptr, NN);

    // ---- MLP head (fused pair) + logits
    gemm2_mfma<true, true, false, false, false, false, false, false><<<gx, blk, 0, stream>>>(
        B0, WTm1, bm1, WTm2, bm2, nullptr, B2, nullptr,
        nullptr, nullptr, nullptr, nullptr, NN);
    logits_k<<<(NN + 3) / 4, blk, 0, stream>>>(B2, Wm3, bm3, out);
}

// Round 2
// 2105.116 us; speedup vs baseline: 1.4545x; 1.0319x over previous
//
#include <hip/hip_runtime.h>

#define NN 100000
#define EE 1000000
#define DDIM 192
#define NLAYER 6
#define TRAIN 8192
#define SLOPE 0.01f
#define EPS_LN 1e-5f
#define TOTSEG (2 * NN)
#define SCAN_NB 98           /* ceil(200000 / 2048) */

typedef float f32x4 __attribute__((ext_vector_type(4)));
typedef __bf16 bf16x8 __attribute__((ext_vector_type(8)));
typedef unsigned short ushort_t;
typedef unsigned int uint_t;

__device__ __forceinline__ float lrelu(float v) { return v > 0.0f ? v : SLOPE * v; }

__device__ __forceinline__ ushort_t f2bf(float f) {
    union { float f; uint_t u; } v; v.f = f;
    uint_t u = v.u;
    u += 0x7fffu + ((u >> 16) & 1u);   // RNE
    return (ushort_t)(u >> 16);
}

__device__ __forceinline__ float bf2f(ushort_t b) {
    union { uint_t u; float f; } v; v.u = ((uint_t)b) << 16; return v.f;
}

__device__ __forceinline__ float wave_sum(float s) {
    #pragma unroll
    for (int off = 32; off > 0; off >>= 1) s += __shfl_down(s, off);
    return __shfl(s, 0);
}

// ---------------------------------------------------------------------------
// One-shot weight prep: transpose + convert to bf16.  WT[m][k] = W[k][m].
// Wroot+Wrel go into the concat matrix WTg[m][576] = [Wroot^T | W0^T | W1^T].
// ---------------------------------------------------------------------------
__global__ __launch_bounds__(256) void prep_w(
    const float* __restrict__ Wt, const float* __restrict__ Wv,
    const float* __restrict__ Wo, const float* __restrict__ W1,
    const float* __restrict__ W2, const float* __restrict__ Wrel,
    const float* __restrict__ Wroot, const float* __restrict__ Wm1,
    const float* __restrict__ Wm2, ushort_t* __restrict__ WTt,
    ushort_t* __restrict__ WTs, ushort_t* __restrict__ WTg)
{
    const int bid = blockIdx.x;
    if (bid < 29 * 144) {
        const int mat = bid / 144;
        const int o = (bid % 144) * 256 + threadIdx.x;   // < 36864
        const float* src;
        if      (mat <  6) src = Wv   + (size_t)mat * 36864;
        else if (mat < 12) src = Wo   + (size_t)(mat - 6)  * 36864;
        else if (mat < 18) src = W1   + (size_t)(mat - 12) * 36864;
        else if (mat < 24) src = W2   + (size_t)(mat - 18) * 36864;
        else if (mat < 26) src = Wrel + (size_t)(mat - 24) * 36864;
        else if (mat == 26) src = Wroot;
        else if (mat == 27) src = Wm1;
        else                src = Wm2;
        const int m = o / 192, k = o - m * 192;
        const ushort_t b = f2bf(src[(size_t)k * 192 + m]);
        if (mat == 24 || mat == 25)
            WTg[(size_t)m * 576 + 192 + (mat - 24) * 192 + k] = b;
        else if (mat == 26)
            WTg[(size_t)m * 576 + k] = b;
        else
            WTs[(size_t)mat * 36864 + o] = b;
    } else {
        const int o = (bid - 29 * 144) * 256 + threadIdx.x;  // < 49152
        const int m = o / 768, k = o - m * 768;
        WTt[o] = f2bf(Wt[(size_t)k * 64 + m]);
    }
}

// ---------------------------------------------------------------------------
// Single MFMA GEMM (kept for the tweet embedding, K=768, M=64).
// ---------------------------------------------------------------------------
template <int NFRAG, bool BIAS, bool RELU>
__global__ __launch_bounds__(256) void gemm_mfma(
    const float* __restrict__ A, const ushort_t* __restrict__ WT,
    const float* __restrict__ bias, float* __restrict__ C,
    int n, int K, int ldc)
{
    __shared__ ushort_t As[128 * 32];
    __shared__ ushort_t Ws[NFRAG * 16 * 32];
    const int tid = threadIdx.x;
    const int lane = tid & 63, w = tid >> 6;
    const int quad = lane >> 4, l15 = lane & 15;
    const int row0 = blockIdx.x * 128;

    f32x4 acc[2][NFRAG];
    #pragma unroll
    for (int m = 0; m < 2; ++m)
        #pragma unroll
        for (int nf = 0; nf < NFRAG; ++nf)
            acc[m][nf] = (f32x4){0.f, 0.f, 0.f, 0.f};

    const int srow = tid >> 1, shalf = tid & 1;
    const bool arow_ok = (row0 + srow) < n;
    const float* aptr = A + (size_t)(row0 + srow) * K + shalf * 16;
    const int ktiles = K >> 5;

    float f[16];
    if (arow_ok) {
        const float4* p = (const float4*)aptr;
        #pragma unroll
        for (int i = 0; i < 4; ++i) {
            const float4 t4 = p[i];
            f[i * 4 + 0] = t4.x; f[i * 4 + 1] = t4.y;
            f[i * 4 + 2] = t4.z; f[i * 4 + 3] = t4.w;
        }
    } else {
        #pragma unroll
        for (int i = 0; i < 16; ++i) f[i] = 0.f;
    }

    for (int t = 0; t < ktiles; ++t) {
        const int k0 = t << 5;
        uint_t u[8];
        #pragma unroll
        for (int i = 0; i < 8; ++i)
            u[i] = (uint_t)f2bf(f[2 * i]) | ((uint_t)f2bf(f[2 * i + 1]) << 16);
        uint4* dsta = (uint4*)&As[srow * 32 + shalf * 16];
        dsta[0] = make_uint4(u[0], u[1], u[2], u[3]);
        dsta[1] = make_uint4(u[4], u[5], u[6], u[7]);

        #pragma unroll
        for (int s = tid; s < NFRAG * 64; s += 256) {
            const int col = s >> 2, part = s & 3;
            *(uint4*)&Ws[col * 32 + part * 8] =
                *(const uint4*)(WT + (size_t)col * K + k0 + part * 8);
        }
        __syncthreads();

        float fn_[16];
        const bool more = (t + 1 < ktiles);
        if (more) {
            if (arow_ok) {
                const float4* p = (const float4*)(aptr + k0 + 32);
                #pragma unroll
                for (int i = 0; i < 4; ++i) {
                    const float4 t4 = p[i];
                    fn_[i * 4 + 0] = t4.x; fn_[i * 4 + 1] = t4.y;
                    fn_[i * 4 + 2] = t4.z; fn_[i * 4 + 3] = t4.w;
                }
            } else {
                #pragma unroll
                for (int i = 0; i < 16; ++i) fn_[i] = 0.f;
            }
        }

        const bf16x8 a0 = *(const bf16x8*)&As[(w * 32 + l15) * 32 + quad * 8];
        const bf16x8 a1 = *(const bf16x8*)&As[(w * 32 + 16 + l15) * 32 + quad * 8];
        #pragma unroll
        for (int nf = 0; nf < NFRAG; ++nf) {
            const bf16x8 b = *(const bf16x8*)&Ws[(nf * 16 + l15) * 32 + quad * 8];
            acc[0][nf] = __builtin_amdgcn_mfma_f32_16x16x32_bf16(a0, b, acc[0][nf], 0, 0, 0);
            acc[1][nf] = __builtin_amdgcn_mfma_f32_16x16x32_bf16(a1, b, acc[1][nf], 0, 0, 0);
        }
        __syncthreads();
        if (more) {
            #pragma unroll
            for (int i = 0; i < 16; ++i) f[i] = fn_[i];
        }
    }

    #pragma unroll
    for (int m = 0; m < 2; ++m) {
        #pragma unroll
        for (int reg = 0; reg < 4; ++reg) {
            const int gr = row0 + w * 32 + m * 16 + quad * 4 + reg;
            if (gr >= n) continue;
            #pragma unroll
            for (int nf = 0; nf < NFRAG; ++nf) {
                const int col = nf * 16 + l15;
                float x = acc[m][nf][reg] + (BIAS ? bias[col] : 0.f);
                if (RELU) x = lrelu(x);
                C[(size_t)gr * ldc + col] = x;
            }
        }
    }
}

// ---------------------------------------------------------------------------
// Fused double GEMM: C = epi2( epi1(A@Wa + ba) @ Wb + bb [+ res] ).
// Intermediate (128x192) lives in LDS as bf16.  BM=128, K=M=192 fixed.
// ABF: A (and res) are bf16.  BN: apply batchnorm (computed in-kernel from
// raw sums bnsum + bng/bnb) to A on load and to res on the residual add.
// BNSTAT: accumulate BN statistics of the output into bnacc.
// CF32/CBF: write f32 C and/or bf16 Cbf.
// ---------------------------------------------------------------------------
template <bool ABF, bool RELU1, bool RELU2, bool RES, bool LNORM, bool BN,
          bool BNSTAT, bool CF32, bool CBF>
__global__ __launch_bounds__(256, 2) void gemm2_mfma(
    const void* __restrict__ Ain, const ushort_t* __restrict__ wta,
    const float* __restrict__ bias1, const ushort_t* __restrict__ wtb,
    const float* __restrict__ bias2, const void* __restrict__ resin,
    float* __restrict__ C, ushort_t* __restrict__ Cbf,
    const float* __restrict__ bnsum, const float* __restrict__ bng,
    const float* __restrict__ bnb, float* __restrict__ bnacc,
    const float* __restrict__ lg, const float* __restrict__ lb, int n)
{
    constexpr int VST = 200;
    __shared__ ushort_t Vs[128 * VST];   // 51200 B; front 8 KB doubles as As
    __shared__ ushort_t Ws[192 * 32];    // 12288 B; doubles as bsum after use
    __shared__ float scs[DDIM], shs[DDIM];
    ushort_t* As = Vs;
    const int tid = threadIdx.x;
    const int lane = tid & 63, w = tid >> 6;
    const int quad = lane >> 4, l15 = lane & 15;
    const int row0 = blockIdx.x * 128;

    if constexpr (BN) {
        const float invN = 1.0f / (float)NN;
        for (int j = tid; j < DDIM; j += 256) {
            const float mu = bnsum[j] * invN;
            const float var = bnsum[DDIM + j] * invN - mu * mu;
            const float sc = bng[j] * rsqrtf(var + EPS_LN);
            scs[j] = sc;
            shs[j] = fmaf(-mu, sc, bnb[j]);
        }
        __syncthreads();
    }

    f32x4 acc[2][12];
    #pragma unroll
    for (int m = 0; m < 2; ++m)
        #pragma unroll
        for (int nf = 0; nf < 12; ++nf)
            acc[m][nf] = (f32x4){0.f, 0.f, 0.f, 0.f};

    const int srow = tid >> 1, shalf = tid & 1;
    const bool arow_ok = (row0 + srow) < n;
    const float*    aF = (const float*)Ain + (size_t)(row0 + srow) * DDIM + shalf * 16;
    const ushort_t* aB = (const ushort_t*)Ain + (size_t)(row0 + srow) * DDIM + shalf * 16;

    float f[16];
    uint4 ub[2];

    // prefetch tile 0 of A
    if constexpr (!ABF) {
        if (arow_ok) {
            const float4* p = (const float4*)aF;
            #pragma unroll
            for (int i = 0; i < 4; ++i) {
                const float4 t4 = p[i];
                f[i * 4 + 0] = t4.x; f[i * 4 + 1] = t4.y;
                f[i * 4 + 2] = t4.z; f[i * 4 + 3] = t4.w;
            }
        } else {
            #pragma unroll
            for (int i = 0; i < 16; ++i) f[i] = 0.f;
        }
    } else {
        if (arow_ok) {
            const uint4* p = (const uint4*)aB;
            ub[0] = p[0]; ub[1] = p[1];
        } else {
            ub[0] = make_uint4(0, 0, 0, 0); ub[1] = make_uint4(0, 0, 0, 0);
        }
    }

    // ---------------- phase 1: acc = A @ Wa ----------------
    #pragma unroll 1
    for (int t = 0; t < 6; ++t) {
        const int k0 = t << 5;
        uint4* dsta = (uint4*)&As[srow * 32 + shalf * 16];
        if constexpr (!ABF) {
            uint_t u[8];
            #pragma unroll
            for (int i = 0; i < 8; ++i)
                u[i] = (uint_t)f2bf(f[2 * i]) | ((uint_t)f2bf(f[2 * i + 1]) << 16);
            dsta[0] = make_uint4(u[0], u[1], u[2], u[3]);
            dsta[1] = make_uint4(u[4], u[5], u[6], u[7]);
        } else if constexpr (BN) {
            const float4* scp = (const float4*)&scs[k0 + shalf * 16];
            const float4* shp = (const float4*)&shs[k0 + shalf * 16];
            const uint_t* uw = (const uint_t*)ub;
            uint_t u[8];
            #pragma unroll
            for (int i = 0; i < 4; ++i) {
                const float4 sc = scp[i], sh = shp[i];
                float x0 = bf2f((ushort_t)(uw[2 * i] & 0xffffu));
                float x1 = bf2f((ushort_t)(uw[2 * i] >> 16));
                float x2 = bf2f((ushort_t)(uw[2 * i + 1] & 0xffffu));
                float x3 = bf2f((ushort_t)(uw[2 * i + 1] >> 16));
                x0 = fmaf(x0, sc.x, sh.x); x1 = fmaf(x1, sc.y, sh.y);
                x2 = fmaf(x2, sc.z, sh.z); x3 = fmaf(x3, sc.w, sh.w);
                u[2 * i]     = (uint_t)f2bf(x0) | ((uint_t)f2bf(x1) << 16);
                u[2 * i + 1] = (uint_t)f2bf(x2) | ((uint_t)f2bf(x3) << 16);
            }
            dsta[0] = make_uint4(u[0], u[1], u[2], u[3]);
            dsta[1] = make_uint4(u[4], u[5], u[6], u[7]);
        } else {
            dsta[0] = ub[0]; dsta[1] = ub[1];
        }

        // ---- stage Wa tile (L2-resident)
        #pragma unroll
        for (int s = tid; s < 768; s += 256) {
            const int col = s >> 2, part = s & 3;
            *(uint4*)&Ws[col * 32 + part * 8] =
                *(const uint4*)(wta + (size_t)col * DDIM + k0 + part * 8);
        }
        __syncthreads();

        // ---- issue next A tile's loads (overlap with MFMA)
        float fn_[16];
        uint4 ubn[2];
        const bool more = (t < 5);
        if (more) {
            if constexpr (!ABF) {
                if (arow_ok) {
                    const float4* p = (const float4*)(aF + k0 + 32);
                    #pragma unroll
                    for (int i = 0; i < 4; ++i) {
                        const float4 t4 = p[i];
                        fn_[i * 4 + 0] = t4.x; fn_[i * 4 + 1] = t4.y;
                        fn_[i * 4 + 2] = t4.z; fn_[i * 4 + 3] = t4.w;
                    }
                } else {
                    #pragma unroll
                    for (int i = 0; i < 16; ++i) fn_[i] = 0.f;
                }
            } else {
                if (arow_ok) {
                    const uint4* p = (const uint4*)(aB + k0 + 32);
                    ubn[0] = p[0]; ubn[1] = p[1];
                } else {
                    ubn[0] = make_uint4(0, 0, 0, 0); ubn[1] = make_uint4(0, 0, 0, 0);
                }
            }
        }

        const bf16x8 a0 = *(const bf16x8*)&As[(w * 32 + l15) * 32 + quad * 8];
        const bf16x8 a1 = *(const bf16x8*)&As[(w * 32 + 16 + l15) * 32 + quad * 8];
        #pragma unroll
        for (int nf = 0; nf < 12; ++nf) {
            const bf16x8 b = *(const bf16x8*)&Ws[(nf * 16 + l15) * 32 + quad * 8];
            acc[0][nf] = __builtin_amdgcn_mfma_f32_16x16x32_bf16(a0, b, acc[0][nf], 0, 0, 0);
            acc[1][nf] = __builtin_amdgcn_mfma_f32_16x16x32_bf16(a1, b, acc[1][nf], 0, 0, 0);
        }
        __syncthreads();
        if (more) {
            if constexpr (!ABF) {
                #pragma unroll
                for (int i = 0; i < 16; ++i) f[i] = fn_[i];
            } else {
                ub[0] = ubn[0]; ub[1] = ubn[1];
            }
        }
    }

    // ---- phase-1 epilogue: bias (+relu) -> Vs bf16; re-zero acc
    {
        float b1r[12];
        #pragma unroll
        for (int nf = 0; nf < 12; ++nf) b1r[nf] = bias1[nf * 16 + l15];
        #pragma unroll
        for (int m = 0; m < 2; ++m) {
            #pragma unroll
            for (int reg = 0; reg < 4; ++reg) {
                ushort_t* vrow = &Vs[(w * 32 + m * 16 + quad * 4 + reg) * VST + l15];
                #pragma unroll
                for (int nf = 0; nf < 12; ++nf) {
                    float x = acc[m][nf][reg] + b1r[nf];
                    if (RELU1) x = lrelu(x);
                    vrow[nf * 16] = f2bf(x);
                    acc[m][nf][reg] = 0.f;
                }
            }
        }
    }
    __syncthreads();

    // ---------------- phase 2: acc = V @ Wb ----------------
    #pragma unroll 1
    for (int t = 0; t < 6; ++t) {
        const int k0 = t << 5;
        #pragma unroll
        for (int s = tid; s < 768; s += 256) {
            const int col = s >> 2, part = s & 3;
            *(uint4*)&Ws[col * 32 + part * 8] =
                *(const uint4*)(wtb + (size_t)col * DDIM + k0 + part * 8);
        }
        __syncthreads();
        const bf16x8 a0 = *(const bf16x8*)&Vs[(w * 32 + l15) * VST + k0 + quad * 8];
        const bf16x8 a1 = *(const bf16x8*)&Vs[(w * 32 + 16 + l15) * VST + k0 + quad * 8];
        #pragma unroll
        for (int nf = 0; nf < 12; ++nf) {
            const bf16x8 b = *(const bf16x8*)&Ws[(nf * 16 + l15) * 32 + quad * 8];
            acc[0][nf] = __builtin_amdgcn_mfma_f32_16x16x32_bf16(a0, b, acc[0][nf], 0, 0, 0);
            acc[1][nf] = __builtin_amdgcn_mfma_f32_16x16x32_bf16(a1, b, acc[1][nf], 0, 0, 0);
        }
        __syncthreads();
    }

    // ---------------- phase-2 epilogue ----------------
    int   col[12];
    float bia[12];
    #pragma unroll
    for (int nf = 0; nf < 12; ++nf) {
        col[nf] = nf * 16 + l15;
        bia[nf] = bias2[col[nf]];
    }
    float rsc[12], rsh[12];
    if constexpr (BN && RES) {
        #pragma unroll
        for (int nf = 0; nf < 12; ++nf) {
            rsc[nf] = scs[col[nf]];
            rsh[nf] = shs[col[nf]];
        }
    }
    float cs[12], cs2[12];
    if constexpr (BNSTAT) {
        #pragma unroll
        for (int nf = 0; nf < 12; ++nf) { cs[nf] = 0.f; cs2[nf] = 0.f; }
    }
    #pragma unroll
    for (int m = 0; m < 2; ++m) {
        #pragma unroll
        for (int reg = 0; reg < 4; ++reg) {
            const int gr = row0 + w * 32 + m * 16 + quad * 4 + reg;
            const bool ok = gr < n;
            float v[12];
            #pragma unroll
            for (int nf = 0; nf < 12; ++nf) {
                float x = acc[m][nf][reg] + bia[nf];
                if constexpr (RES) {
                    float r;
                    if constexpr (ABF)
                        r = ok ? bf2f(((const ushort_t*)resin)[(size_t)gr * DDIM + col[nf]]) : 0.f;
                    else
                        r = ok ? ((const float*)resin)[(size_t)gr * DDIM + col[nf]] : 0.f;
                    if constexpr (BN) r = fmaf(r, rsc[nf], rsh[nf]);
                    x += r;
                }
                v[nf] = x;
            }
            if constexpr (LNORM) {
                float s = 0.f, s2 = 0.f;
                #pragma unroll
                for (int nf = 0; nf < 12; ++nf) { s += v[nf]; s2 = fmaf(v[nf], v[nf], s2); }
                #pragma unroll
                for (int off = 1; off < 16; off <<= 1) {
                    s  += __shfl_xor(s, off);
                    s2 += __shfl_xor(s2, off);
                }
                const float mu = s * (1.0f / DDIM);
                const float var = s2 * (1.0f / DDIM) - mu * mu;
                const float rs = rsqrtf(var + EPS_LN);
                #pragma unroll
                for (int nf = 0; nf < 12; ++nf)
                    v[nf] = fmaf((v[nf] - mu) * rs, lg[col[nf]], lb[col[nf]]);
            }
            #pragma unroll
            for (int nf = 0; nf < 12; ++nf) {
                float x = v[nf];
                if (RELU2) x = lrelu(x);
                if constexpr (BNSTAT) {
                    const float xa = ok ? x : 0.f;
                    cs[nf] += xa;
                    cs2[nf] = fmaf(xa, xa, cs2[nf]);
                }
                if (ok) {
                    if constexpr (CF32) C[(size_t)gr * DDIM + col[nf]] = x;
                    if constexpr (CBF)  Cbf[(size_t)gr * DDIM + col[nf]] = f2bf(x);
                }
            }
        }
    }
    if constexpr (BNSTAT) {
        float* bsA = (float*)Ws;            // [4][192], aliases Ws (reads done)
        float* bsB = bsA + 4 * 192;
        #pragma unroll
        for (int nf = 0; nf < 12; ++nf) {
            cs[nf]  += __shfl_xor(cs[nf], 16);  cs[nf]  += __shfl_xor(cs[nf], 32);
            cs2[nf] += __shfl_xor(cs2[nf], 16); cs2[nf] += __shfl_xor(cs2[nf], 32);
        }
        if (quad == 0) {
            #pragma unroll
            for (int nf = 0; nf < 12; ++nf) {
                bsA[w * 192 + col[nf]] = cs[nf];
                bsB[w * 192 + col[nf]] = cs2[nf];
            }
        }
        __syncthreads();
        if (tid < DDIM) {
            const float s  = bsA[tid] + bsA[192 + tid] + bsA[384 + tid] + bsA[576 + tid];
            const float s2 = bsB[tid] + bsB[192 + tid] + bsB[384 + tid] + bsB[576 + tid];
            atomicAdd(&bnacc[tid], s);
            atomicAdd(&bnacc[DDIM + tid], s2);
        }
    }
}

// ---------------------------------------------------------------------------
// RGCN concat GEMM: Cbf = bf16([A1(bf16,K=192) | A2(bf16,K=384)] @ WT + b).
// In-place safe for Cbf == A1 (each block reads only its own rows, fully
// consumed before the epilogue writes them).
// ---------------------------------------------------------------------------
__global__ __launch_bounds__(256) void gemm_cat(
    const ushort_t* __restrict__ A1, const ushort_t* __restrict__ A2,
    const ushort_t* __restrict__ WT, const float* __restrict__ bias,
    ushort_t* __restrict__ Cbf, int n)
{
    __shared__ ushort_t As[128 * 32];
    __shared__ ushort_t Ws[192 * 32];
    const int tid = threadIdx.x;
    const int lane = tid & 63, w = tid >> 6;
    const int quad = lane >> 4, l15 = lane & 15;
    const int row0 = blockIdx.x * 128;

    f32x4 acc[2][12];
    #pragma unroll
    for (int m = 0; m < 2; ++m)
        #pragma unroll
        for (int nf = 0; nf < 12; ++nf)
            acc[m][nf] = (f32x4){0.f, 0.f, 0.f, 0.f};

    const int srow = tid >> 1, shalf = tid & 1;
    const bool arow_ok = (row0 + srow) < n;
    const ushort_t* a1p = A1 + (size_t)(row0 + srow) * 192 + shalf * 16;
    const ushort_t* a2p = A2 + (size_t)(row0 + srow) * 384 + shalf * 16;

    uint4 u0, u1;
    if (arow_ok) {
        const uint4* p = (const uint4*)a1p;
        u0 = p[0]; u1 = p[1];
    } else {
        u0 = make_uint4(0, 0, 0, 0); u1 = make_uint4(0, 0, 0, 0);
    }

    #pragma unroll 1
    for (int t = 0; t < 18; ++t) {
        uint4* dsta = (uint4*)&As[srow * 32 + shalf * 16];
        dsta[0] = u0;
        dsta[1] = u1;

        #pragma unroll
        for (int s = tid; s < 768; s += 256) {
            const int col = s >> 2, part = s & 3;
            *(uint4*)&Ws[col * 32 + part * 8] =
                *(const uint4*)(WT + (size_t)col * 576 + t * 32 + part * 8);
        }
        __syncthreads();

        uint4 un0, un1;
        const bool more = (t < 17);
        if (more) {
            if (arow_ok) {
                const int tn = t + 1;
                const ushort_t* np = (tn < 6) ? (a1p + tn * 32)
                                              : (a2p + (tn - 6) * 32);
                const uint4* p = (const uint4*)np;
                un0 = p[0]; un1 = p[1];
            } else {
                un0 = make_uint4(0, 0, 0, 0); un1 = make_uint4(0, 0, 0, 0);
            }
        }

        const bf16x8 a0 = *(const bf16x8*)&As[(w * 32 + l15) * 32 + quad * 8];
        const bf16x8 a1 = *(const bf16x8*)&As[(w * 32 + 16 + l15) * 32 + quad * 8];
        #pragma unroll
        for (int nf = 0; nf < 12; ++nf) {
            const bf16x8 b = *(const bf16x8*)&Ws[(nf * 16 + l15) * 32 + quad * 8];
            acc[0][nf] = __builtin_amdgcn_mfma_f32_16x16x32_bf16(a0, b, acc[0][nf], 0, 0, 0);
            acc[1][nf] = __builtin_amdgcn_mfma_f32_16x16x32_bf16(a1, b, acc[1][nf], 0, 0, 0);
        }
        __syncthreads();
        if (more) { u0 = un0; u1 = un1; }
    }

    #pragma unroll
    for (int m = 0; m < 2; ++m) {
        #pragma unroll
        for (int reg = 0; reg < 4; ++reg) {
            const int gr = row0 + w * 32 + m * 16 + quad * 4 + reg;
            if (gr >= n) continue;
            #pragma unroll
            for (int nf = 0; nf < 12; ++nf) {
                const int col = nf * 16 + l15;
                Cbf[(size_t)gr * DDIM + col] = f2bf(acc[m][nf][reg] + bias[col]);
            }
        }
    }
}

// ---------------------------------------------------------------------------
__global__ __launch_bounds__(256) void embed_nc_k(
    const float* __restrict__ np_, const float* __restrict__ cp,
    const float* __restrict__ Wn, const float* __restrict__ bnum,
    const float* __restrict__ Wc, const float* __restrict__ bc,
    float* __restrict__ x)
{
    const int idx = blockIdx.x * 256 + threadIdx.x;
    if (idx >= NN * 128) return;
    const int node = idx >> 7;
    const int c = idx & 127;
    float acc;
    if (c < 64) {
        acc = bnum[c];
        #pragma unroll
        for (int k = 0; k < 6; ++k) acc = fmaf(np_[node * 6 + k], Wn[k * 64 + c], acc);
    } else {
        const int cc = c - 64;
        acc = bc[cc];
        #pragma unroll
        for (int k = 0; k < 7; ++k) acc = fmaf(cp[node * 7 + k], Wc[k * 64 + cc], acc);
    }
    x[(size_t)node * DDIM + 64 + c] = lrelu(acc);
}

// ---------------------------------------------------------------------------
// Contrastive: fnorm -> bf16 rows, MFMA sim, closs
// ---------------------------------------------------------------------------
__global__ __launch_bounds__(256) void fnorm_k(const float* __restrict__ x,
                                               ushort_t* __restrict__ fnb)
{
    const int wave = threadIdx.x >> 6, lane = threadIdx.x & 63;
    const int row = blockIdx.x * 4 + wave;
    if (row >= TRAIN) return;
    const float* xr = x + (size_t)row * DDIM;
    const float v0 = xr[lane], v1 = xr[lane + 64], v2 = xr[lane + 128];
    const float q = wave_sum(v0 * v0 + v1 * v1 + v2 * v2);
    const float inv = 1.0f / sqrtf(q);
    ushort_t* fr = fnb + (size_t)row * DDIM;
    fr[lane]       = f2bf(v0 * inv);
    fr[lane + 64]  = f2bf(v1 * inv);
    fr[lane + 128] = f2bf(v2 * inv);
}

__global__ __launch_bounds__(256) void sim_mfma(const ushort_t* __restrict__ fnb,
    const int* __restrict__ lab, float* __restrict__ row_ex, float* __restrict__ row_mt)
{
    __shared__ ushort_t Ai[128 * 32];
    __shared__ ushort_t Bj[128 * 32];
    __shared__ int Li[128], Lj[128];
    const int tid = threadIdx.x, lane = tid & 63, w = tid >> 6;
    const int quad = lane >> 4, l15 = lane & 15;
    const int i0 = blockIdx.x * 128, j0 = blockIdx.y * 128;
    if (tid < 128) Li[tid] = lab[i0 + tid];
    else           Lj[tid - 128] = lab[j0 + tid - 128];
    const int iw = (w >> 1) * 64, jw = (w & 1) * 64;

    f32x4 acc[4][4];
    #pragma unroll
    for (int m = 0; m < 4; ++m)
        #pragma unroll
        for (int nf = 0; nf < 4; ++nf)
            acc[m][nf] = (f32x4){0.f, 0.f, 0.f, 0.f};

    for (int k0 = 0; k0 < DDIM; k0 += 32) {
        #pragma unroll
        for (int s = tid; s < 512; s += 256) {
            const int row = s >> 2, part = s & 3;
            *(uint4*)&Ai[row * 32 + part * 8] =
                *(const uint4*)(fnb + (size_t)(i0 + row) * DDIM + k0 + part * 8);
            *(uint4*)&Bj[row * 32 + part * 8] =
                *(const uint4*)(fnb + (size_t)(j0 + row) * DDIM + k0 + part * 8);
        }
        __syncthreads();
        bf16x8 a[4], b[4];
        #pragma unroll
        for (int m = 0; m < 4; ++m)
            a[m] = *(const bf16x8*)&Ai[(iw + m * 16 + l15) * 32 + quad * 8];
        #pragma unroll
        for (int nf = 0; nf < 4; ++nf)
            b[nf] = *(const bf16x8*)&Bj[(jw + nf * 16 + l15) * 32 + quad * 8];
        #pragma unroll
        for (int m = 0; m < 4; ++m)
            #pragma unroll
            for (int nf = 0; nf < 4; ++nf)
                acc[m][nf] = __builtin_amdgcn_mfma_f32_16x16x32_bf16(a[m], b[nf], acc[m][nf], 0, 0, 0);
        __syncthreads();
    }

    int lj[4];
    #pragma unroll
    for (int nf = 0; nf < 4; ++nf) lj[nf] = Lj[jw + nf * 16 + l15];
    #pragma unroll
    for (int m = 0; m < 4; ++m) {
        #pragma unroll
        for (int reg = 0; reg < 4; ++reg) {
            const int rl = iw + m * 16 + quad * 4 + reg;
            const int li = Li[rl];
            float se = 0.f, sm = 0.f;
            #pragma unroll
            for (int nf = 0; nf < 4; ++nf) {
                const float e = __expf(acc[m][nf][reg] * 2.0f);  // 1/TEMP = 2
                se += e;
                if (li == lj[nf]) sm += e;
            }
            #pragma unroll
            for (int off = 1; off < 16; off <<= 1) {
                se += __shfl_xor(se, off);
                sm += __shfl_xor(sm, off);
            }
            if (l15 == 0) {
                atomicAdd(&row_ex[i0 + rl], se);
                atomicAdd(&row_mt[i0 + rl], sm);
            }
        }
    }
}

__global__ __launch_bounds__(256) void closs_k(const float* __restrict__ ex,
    const float* __restrict__ mt, float* __restrict__ out)
{
    float s = 0.f;
    for (int i = threadIdx.x; i < TRAIN; i += 256) s += -logf(mt[i] / ex[i]);
    s = wave_sum(s);
    __shared__ float red[4];
    const int wave = threadIdx.x >> 6, lane = threadIdx.x & 63;
    if (lane == 0) red[wave] = s;
    __syncthreads();
    if (threadIdx.x == 0) out[0] = (red[0] + red[1] + red[2] + red[3]) / (float)TRAIN;
}

// ---------------------------------------------------------------------------
// CSR build: counts -> 3-kernel parallel exclusive scan -> fill.
// ---------------------------------------------------------------------------
__global__ __launch_bounds__(256) void cnt_i_k(const int* __restrict__ dst,
    const int* __restrict__ ety, int* __restrict__ cnti)
{
    const int e = blockIdx.x * 256 + threadIdx.x;
    if (e >= EE) return;
    atomicAdd(&cnti[(size_t)ety[e] * NN + dst[e]], 1);
}

__global__ __launch_bounds__(256) void part_k(const int* __restrict__ cnti,
                                              int* __restrict__ part)
{
    __shared__ int sh[256];
    const int tid = threadIdx.x;
    const int i0 = blockIdx.x * 2048 + tid * 8;
    int s = 0;
    #pragma unroll
    for (int j = 0; j < 8; ++j) {
        const int i = i0 + j;
        s += (i < TOTSEG) ? cnti[i] : 0;
    }
    sh[tid] = s;
    __syncthreads();
    #pragma unroll
    for (int off = 128; off > 0; off >>= 1) {
        if (tid < off) sh[tid] += sh[tid + off];
        __syncthreads();
    }
    if (tid == 0) part[blockIdx.x] = sh[0];
}

__global__ __launch_bounds__(128) void scanp_k(int* __restrict__ part)
{
    __shared__ int sh[128];
    const int tid = threadIdx.x;
    const int v = (tid < SCAN_NB) ? part[tid] : 0;
    sh[tid] = v;
    __syncthreads();
    #pragma unroll
    for (int off = 1; off < 128; off <<= 1) {
        const int t = (tid >= off) ? sh[tid - off] : 0;
        __syncthreads();
        sh[tid] += t;
        __syncthreads();
    }
    if (tid < SCAN_NB) part[tid] = sh[tid] - v;   // exclusive
}

__global__ __launch_bounds__(256) void offs_k(const int* __restrict__ cnti,
    const int* __restrict__ part, int* __restrict__ offs)
{
    __shared__ int sh[256];
    const int tid = threadIdx.x;
    const int i0 = blockIdx.x * 2048 + tid * 8;
    int v[8];
    int loc = 0;
    #pragma unroll
    for (int j = 0; j < 8; ++j) {
        const int i = i0 + j;
        v[j] = (i < TOTSEG) ? cnti[i] : 0;
        loc += v[j];
    }
    sh[tid] = loc;
    __syncthreads();
    #pragma unroll
    for (int off = 1; off < 256; off <<= 1) {
        const int t = (tid >= off) ? sh[tid - off] : 0;
        __syncthreads();
        sh[tid] += t;
        __syncthreads();
    }
    int pre = part[blockIdx.x] + sh[tid] - loc;
    #pragma unroll
    for (int j = 0; j < 8; ++j) {
        const int i = i0 + j;
        if (i < TOTSEG) offs[i] = pre;
        pre += v[j];
    }
}

__global__ __launch_bounds__(256) void fill_k(const int* __restrict__ src,
    const int* __restrict__ dst, const int* __restrict__ ety,
    int* __restrict__ offs, int* __restrict__ elist)
{
    const int e = blockIdx.x * 256 + threadIdx.x;
    if (e >= EE) return;
    const int pos = atomicAdd(&offs[(size_t)ety[e] * NN + dst[e]], 1);
    elist[pos] = src[e];
}

// ---------------------------------------------------------------------------
// Gather (bf16 in, bf16 out), uint-vectorized: row of 192 bf16 = 96 uints;
// lane handles uints {lane, lane+64 (lane<32)} = cols {2l,2l+1, 128+2l,129+2l}.
// Column-wise accumulation order identical to the scalar version.
// ---------------------------------------------------------------------------
__global__ __launch_bounds__(256) void gather_bf_k(const ushort_t* __restrict__ xb,
    const int* __restrict__ elist, const int* __restrict__ offs,
    const int* __restrict__ cnti, ushort_t* __restrict__ aggb)
{
    const int wave = threadIdx.x >> 6, lane = threadIdx.x & 63;
    const int d = blockIdx.x * 4 + wave;
    if (d >= NN) return;
    const bool lo = lane < 32;
    #pragma unroll
    for (int r = 0; r < 2; ++r) {
        const int seg = r * NN + d;
        const int end = offs[seg];
        const int c = cnti[seg];
        float a0 = 0.f, a1 = 0.f, b0 = 0.f, b1 = 0.f;
        int e = end - c;
        for (; e + 1 < end; e += 2) {
            const int s0 = elist[e], s1 = elist[e + 1];
            const uint_t* r0 = (const uint_t*)(xb + (size_t)s0 * DDIM);
            const uint_t* r1 = (const uint_t*)(xb + (size_t)s1 * DDIM);
            const uint_t x0 = r0[lane], x1 = r1[lane];
            uint_t y0 = 0u, y1 = 0u;
            if (lo) { y0 = r0[64 + lane]; y1 = r1[64 + lane]; }
            a0 += bf2f((ushort_t)(x0 & 0xffffu)) + bf2f((ushort_t)(x1 & 0xffffu));
            a1 += bf2f((ushort_t)(x0 >> 16))     + bf2f((ushort_t)(x1 >> 16));
            b0 += bf2f((ushort_t)(y0 & 0xffffu)) + bf2f((ushort_t)(y1 & 0xffffu));
            b1 += bf2f((ushort_t)(y0 >> 16))     + bf2f((ushort_t)(y1 >> 16));
        }
        if (e < end) {
            const int s0 = elist[e];
            const uint_t* r0 = (const uint_t*)(xb + (size_t)s0 * DDIM);
            const uint_t x0 = r0[lane];
            uint_t y0 = 0u;
            if (lo) y0 = r0[64 + lane];
            a0 += bf2f((ushort_t)(x0 & 0xffffu));
            a1 += bf2f((ushort_t)(x0 >> 16));
            b0 += bf2f((ushort_t)(y0 & 0xffffu));
            b1 += bf2f((ushort_t)(y0 >> 16));
        }
        const float inv = 1.0f / (float)max(c, 1);
        uint_t* ar = (uint_t*)(aggb + (size_t)d * 384 + r * DDIM);
        ar[lane] = (uint_t)f2bf(a0 * inv) | ((uint_t)f2bf(a1 * inv) << 16);
        if (lo)
            ar[64 + lane] = (uint_t)f2bf(b0 * inv) | ((uint_t)f2bf(b1 * inv) << 16);
    }
}

__global__ __launch_bounds__(256) void logits_k(const float* __restrict__ h,
    const float* __restrict__ Wm3, const float* __restrict__ bm3, float* __restrict__ out)
{
    const int wave = threadIdx.x >> 6, lane = threadIdx.x & 63;
    const int row = blockIdx.x * 4 + wave;
    if (row >= NN) return;
    const float* hr = h + (size_t)row * DDIM;
    float s0 = 0.f, s1 = 0.f;
    #pragma unroll
    for (int p = 0; p < 3; ++p) {
        const int k = lane + p * 64;
        const float v = hr[k];
        s0 = fmaf(v, Wm3[k * 2 + 0], s0);
        s1 = fmaf(v, Wm3[k * 2 + 1], s1);
    }
    #pragma unroll
    for (int off = 32; off > 0; off >>= 1) {
        s0 += __shfl_down(s0, off);
        s1 += __shfl_down(s1, off);
    }
    if (lane == 0) {
        out[(size_t)row * 2 + 0] = s0 + bm3[0];
        out[(size_t)row * 2 + 1] = s1 + bm3[1];
    }
}

// ---------------------------------------------------------------------------
extern "C" void kernel_launch(void* const* d_in, const int* in_sizes, int n_in,
                              void* d_out, int out_size, void* d_ws, size_t ws_size,
                              hipStream_t stream)
{
    const float* tweet   = (const float*)d_in[0];
    const float* np_     = (const float*)d_in[1];
    const float* cp      = (const float*)d_in[2];
    const float* Wt      = (const float*)d_in[3];
    const float* bt      = (const float*)d_in[4];
    const float* Wn      = (const float*)d_in[5];
    const float* bnum    = (const float*)d_in[6];
    const float* Wc      = (const float*)d_in[7];
    const float* bc      = (const float*)d_in[8];
    const float* Wv      = (const float*)d_in[9];
    const float* bv      = (const float*)d_in[10];
    const float* Wo      = (const float*)d_in[11];
    const float* bo      = (const float*)d_in[12];
    const float* ln1g    = (const float*)d_in[13];
    const float* ln1b    = (const float*)d_in[14];
    const float* bng     = (const float*)d_in[15];
    const float* bnb     = (const float*)d_in[16];
    const float* W1      = (const float*)d_in[17];
    const float* b1      = (const float*)d_in[18];
    const float* W2      = (const float*)d_in[19];
    const float* b2      = (const float*)d_in[20];
    const float* ln2g    = (const float*)d_in[21];
    const float* ln2b    = (const float*)d_in[22];
    const float* Wrel    = (const float*)d_in[23];
    const float* Wroot   = (const float*)d_in[24];
    const float* rgcnb   = (const float*)d_in[25];
    const float* Wm1     = (const float*)d_in[26];
    const float* bm1     = (const float*)d_in[27];
    const float* Wm2     = (const float*)d_in[28];
    const float* bm2     = (const float*)d_in[29];
    const float* Wm3     = (const float*)d_in[30];
    const float* bm3     = (const float*)d_in[31];
    const int*   eidx    = (const int*)d_in[32];
    const int*   esrc    = eidx;
    const int*   edst    = eidx + EE;
    const int*   ety     = (const int*)d_in[33];
    const int*   labels  = (const int*)d_in[34];
    float* out = (float*)d_out;

    float* ws = (float*)d_ws;
    const size_t ND = (size_t)NN * DDIM;
    float* B0    = ws;
    float* B1    = B0 + ND;       // unused (layout keeper)
    float* B2    = B1 + ND;       // X1BF (bf16 ln1-out); AGGB during RGCN; MLP f32 out
    float* B3    = B2 + ND;       // front: XBF (bf16 x/h); then WTg
    float* ROWEX = B3 + ND;
    float* ROWMT = ROWEX + TRAIN;
    float* BNS   = ROWMT + TRAIN;             // 6 layers x [sum(192) | sumsq(192)]
    int*   CNTI  = (int*)(BNS + 12 * DDIM);   // 2*NN
    int*   OFFS  = CNTI + 2 * NN;             // 2*NN (becomes end-offsets)
    int*   ELIST = OFFS + 2 * NN;             // EE
    int*   PART  = ELIST + EE;                // 128
    ushort_t* FNb = (ushort_t*)(PART + 128);
    ushort_t* WTt = FNb + (size_t)TRAIN * DDIM;   // 64x768
    ushort_t* WTs = WTt + 49152;                  // 29 x 36864 (24/25/26 unused)
    ushort_t* WTv    = WTs;
    ushort_t* WTo    = WTs + (size_t)6  * 36864;
    ushort_t* WT1    = WTs + (size_t)12 * 36864;
    ushort_t* WT2    = WTs + (size_t)18 * 36864;
    ushort_t* WTm1   = WTs + (size_t)27 * 36864;
    ushort_t* WTm2   = WTs + (size_t)28 * 36864;
    ushort_t* XBF  = (ushort_t*)B3;               // NN x 192 bf16 (x, then h1, h2)
    ushort_t* WTg  = (ushort_t*)B3 + ND;          // 192 x 576 bf16 (in B3 tail)
    ushort_t* X1BF = (ushort_t*)B2;               // NN x 192 bf16 (ln1 out)
    ushort_t* AGGB = (ushort_t*)B2;               // NN x 384 bf16 (RGCN only)

    const int gx = (NN + 127) / 128;   // 782
    const dim3 blk(256);

    prep_w<<<29 * 144 + 192, blk, 0, stream>>>(Wt, Wv, Wo, W1, W2, Wrel, Wroot, Wm1, Wm2, WTt, WTs, WTg);

    // ---- CSR build (edge structure only; reused by both RGCN layers)
    hipMemsetAsync(CNTI, 0, 2 * NN * sizeof(int), stream);
    cnt_i_k<<<(EE + 255) / 256, blk, 0, stream>>>(edst, ety, CNTI);
    part_k<<<SCAN_NB, blk, 0, stream>>>(CNTI, PART);
    scanp_k<<<1, 128, 0, stream>>>(PART);
    offs_k<<<SCAN_NB, blk, 0, stream>>>(CNTI, PART, OFFS);
    fill_k<<<(EE + 255) / 256, blk, 0, stream>>>(esrc, edst, ety, OFFS, ELIST);

    // ---- input embedding
    gemm_mfma<4, true, true><<<gx, blk, 0, stream>>>(tweet, WTt, bt, B0, NN, 768, DDIM);
    embed_nc_k<<<(NN * 128 + 255) / 256, blk, 0, stream>>>(np_, cp, Wn, bnum, Wc, bc, B0);

    // ---- 6 layers, each = 2 fused double-GEMMs (BN finalize folded in)
    hipMemsetAsync(BNS, 0, 12 * DDIM * sizeof(float), stream);
    for (int i = 0; i < NLAYER; ++i) {
        const size_t wo = (size_t)i * 36864;
        float* bnacc_i = BNS + (size_t)i * 2 * DDIM;
        // X1BF = bf16( ln1(B0 + (B0@Wv+bv)@Wo + bo) ), BN-stat accumulate
        gemm2_mfma<false, false, false, true, true, false, true, false, true>
            <<<gx, blk, 0, stream>>>(
            B0, WTv + wo, bv + i * DDIM, WTo + wo, bo + i * DDIM, B0,
            nullptr, X1BF, nullptr, nullptr, nullptr, bnacc_i,
            ln1g + i * DDIM, ln1b + i * DDIM, NN);
        // B0 = ln2( bn(x1) + lrelu(bn(x1)@W1+b1)@W2 + b2 ); last layer also bf16 x
        if (i < NLAYER - 1)
            gemm2_mfma<true, true, false, true, true, true, false, true, false>
                <<<gx, blk, 0, stream>>>(
                X1BF, WT1 + wo, b1 + i * DDIM, WT2 + wo, b2 + i * DDIM, X1BF,
                B0, nullptr, bnacc_i, bng + i * DDIM, bnb + i * DDIM, nullptr,
                ln2g + i * DDIM, ln2b + i * DDIM, NN);
        else
            gemm2_mfma<true, true, false, true, true, true, false, true, true>
                <<<gx, blk, 0, stream>>>(
                X1BF, WT1 + wo, b1 + i * DDIM, WT2 + wo, b2 + i * DDIM, X1BF,
                B0, XBF, bnacc_i, bng + i * DDIM, bnb + i * DDIM, nullptr,
                ln2g + i * DDIM, ln2b + i * DDIM, NN);
    }

    // ---- contrastive loss (before RGCN so B2/B3 can be reused)
    hipMemsetAsync(ROWEX, 0, 2 * TRAIN * sizeof(float), stream);
    fnorm_k<<<TRAIN / 4, blk, 0, stream>>>(B0, FNb);
    sim_mfma<<<dim3(TRAIN / 128, TRAIN / 128), blk, 0, stream>>>(FNb, labels, ROWEX, ROWMT);
    closs_k<<<1, blk, 0, stream>>>(ROWEX, ROWMT, out + 2 * (size_t)NN);

    // ---- RGCN pass 1: h1 = bf16([x | agg(x)] @ [Wroot;Wcat] + b), in place
    gather_bf_k<<<(NN + 3) / 4, blk, 0, stream>>>(XBF, ELIST, OFFS, CNTI, AGGB);
    gemm_cat<<<gx, blk, 0, stream>>>(XBF, AGGB, WTg, rgcnb, XBF, NN);

    // ---- RGCN pass 2
    gather_bf_k<<<(NN + 3) / 4, blk, 0, stream>>>(XBF, ELIST, OFFS, CNTI, AGGB);
    gemm_cat<<<gx, blk, 0, stream>>>(XBF, AGGB, WTg, rgcnb, XBF, NN);

    // ---- MLP head (fused pair, bf16 in) + logits
    gemm2_mfma<true, true, true, false, false, false, false, true, false>
        <<<gx, blk, 0, stream>>>(
        XBF, WTm1, bm1, WTm2, bm2, nullptr, B2, nullptr,
        nullptr, nullptr, nullptr, nullptr, nullptr, nullptr, NN);
    logits_k<<<(NN + 3) / 4, blk, 0, stream>>>(B2, Wm3, bm3, out);
}

// Round 3
// 1893.561 us; speedup vs baseline: 1.6170x; 1.1117x over previous
//
#include <hip/hip_runtime.h>

#define NN 100000
#define EE 1000000
#define DDIM 192
#define NLAYER 6
#define TRAIN 8192
#define SLOPE 0.01f
#define EPS_LN 1e-5f
#define TOTSEG (2 * NN)
#define SCAN_NB 98           /* ceil(200000 / 2048) */

typedef float f32x4 __attribute__((ext_vector_type(4)));
typedef __bf16 bf16x8 __attribute__((ext_vector_type(8)));
typedef unsigned short ushort_t;
typedef unsigned int uint_t;

__device__ __forceinline__ float lrelu(float v) { return v > 0.0f ? v : SLOPE * v; }

__device__ __forceinline__ ushort_t f2bf(float f) {
    __bf16 h = (__bf16)f;              // HW RNE convert (v_cvt_pk when paired)
    return __builtin_bit_cast(ushort_t, h);
}

__device__ __forceinline__ float bf2f(ushort_t b) {
    union { uint_t u; float f; } v; v.u = ((uint_t)b) << 16; return v.f;
}

__device__ __forceinline__ float wave_sum(float s) {
    #pragma unroll
    for (int off = 32; off > 0; off >>= 1) s += __shfl_down(s, off);
    return __shfl(s, 0);
}

// ---------------------------------------------------------------------------
// One-shot weight prep: transpose + convert to bf16.  WT[m][k] = W[k][m].
// Wroot+Wrel go into the concat matrix WTg[m][576] = [Wroot^T | W0^T | W1^T].
// ---------------------------------------------------------------------------
__global__ __launch_bounds__(256) void prep_w(
    const float* __restrict__ Wt, const float* __restrict__ Wv,
    const float* __restrict__ Wo, const float* __restrict__ W1,
    const float* __restrict__ W2, const float* __restrict__ Wrel,
    const float* __restrict__ Wroot, const float* __restrict__ Wm1,
    const float* __restrict__ Wm2, ushort_t* __restrict__ WTt,
    ushort_t* __restrict__ WTs, ushort_t* __restrict__ WTg)
{
    const int bid = blockIdx.x;
    if (bid < 29 * 144) {
        const int mat = bid / 144;
        const int o = (bid % 144) * 256 + threadIdx.x;   // < 36864
        const float* src;
        if      (mat <  6) src = Wv   + (size_t)mat * 36864;
        else if (mat < 12) src = Wo   + (size_t)(mat - 6)  * 36864;
        else if (mat < 18) src = W1   + (size_t)(mat - 12) * 36864;
        else if (mat < 24) src = W2   + (size_t)(mat - 18) * 36864;
        else if (mat < 26) src = Wrel + (size_t)(mat - 24) * 36864;
        else if (mat == 26) src = Wroot;
        else if (mat == 27) src = Wm1;
        else                src = Wm2;
        const int m = o / 192, k = o - m * 192;
        const ushort_t b = f2bf(src[(size_t)k * 192 + m]);
        if (mat == 24 || mat == 25)
            WTg[(size_t)m * 576 + 192 + (mat - 24) * 192 + k] = b;
        else if (mat == 26)
            WTg[(size_t)m * 576 + k] = b;
        else
            WTs[(size_t)mat * 36864 + o] = b;
    } else {
        const int o = (bid - 29 * 144) * 256 + threadIdx.x;  // < 49152
        const int m = o / 768, k = o - m * 768;
        WTt[o] = f2bf(Wt[(size_t)k * 64 + m]);
    }
}

// ---------------------------------------------------------------------------
// Single MFMA GEMM (kept for the tweet embedding, K=768, M=64).
// ---------------------------------------------------------------------------
template <int NFRAG, bool BIAS, bool RELU>
__global__ __launch_bounds__(256) void gemm_mfma(
    const float* __restrict__ A, const ushort_t* __restrict__ WT,
    const float* __restrict__ bias, float* __restrict__ C,
    int n, int K, int ldc)
{
    __shared__ ushort_t As[128 * 32];
    __shared__ ushort_t Ws[NFRAG * 16 * 32];
    const int tid = threadIdx.x;
    const int lane = tid & 63, w = tid >> 6;
    const int quad = lane >> 4, l15 = lane & 15;
    const int row0 = blockIdx.x * 128;

    f32x4 acc[2][NFRAG];
    #pragma unroll
    for (int m = 0; m < 2; ++m)
        #pragma unroll
        for (int nf = 0; nf < NFRAG; ++nf)
            acc[m][nf] = (f32x4){0.f, 0.f, 0.f, 0.f};

    const int srow = tid >> 1, shalf = tid & 1;
    const bool arow_ok = (row0 + srow) < n;
    const float* aptr = A + (size_t)(row0 + srow) * K + shalf * 16;
    const int ktiles = K >> 5;

    float f[16];
    if (arow_ok) {
        const float4* p = (const float4*)aptr;
        #pragma unroll
        for (int i = 0; i < 4; ++i) {
            const float4 t4 = p[i];
            f[i * 4 + 0] = t4.x; f[i * 4 + 1] = t4.y;
            f[i * 4 + 2] = t4.z; f[i * 4 + 3] = t4.w;
        }
    } else {
        #pragma unroll
        for (int i = 0; i < 16; ++i) f[i] = 0.f;
    }

    for (int t = 0; t < ktiles; ++t) {
        const int k0 = t << 5;
        uint_t u[8];
        #pragma unroll
        for (int i = 0; i < 8; ++i)
            u[i] = (uint_t)f2bf(f[2 * i]) | ((uint_t)f2bf(f[2 * i + 1]) << 16);
        uint4* dsta = (uint4*)&As[srow * 32 + shalf * 16];
        dsta[0] = make_uint4(u[0], u[1], u[2], u[3]);
        dsta[1] = make_uint4(u[4], u[5], u[6], u[7]);

        #pragma unroll
        for (int s = tid; s < NFRAG * 64; s += 256) {
            const int col = s >> 2, part = s & 3;
            *(uint4*)&Ws[col * 32 + part * 8] =
                *(const uint4*)(WT + (size_t)col * K + k0 + part * 8);
        }
        __syncthreads();

        float fn_[16];
        const bool more = (t + 1 < ktiles);
        if (more) {
            if (arow_ok) {
                const float4* p = (const float4*)(aptr + k0 + 32);
                #pragma unroll
                for (int i = 0; i < 4; ++i) {
                    const float4 t4 = p[i];
                    fn_[i * 4 + 0] = t4.x; fn_[i * 4 + 1] = t4.y;
                    fn_[i * 4 + 2] = t4.z; fn_[i * 4 + 3] = t4.w;
                }
            } else {
                #pragma unroll
                for (int i = 0; i < 16; ++i) fn_[i] = 0.f;
            }
        }

        const bf16x8 a0 = *(const bf16x8*)&As[(w * 32 + l15) * 32 + quad * 8];
        const bf16x8 a1 = *(const bf16x8*)&As[(w * 32 + 16 + l15) * 32 + quad * 8];
        #pragma unroll
        for (int nf = 0; nf < NFRAG; ++nf) {
            const bf16x8 b = *(const bf16x8*)&Ws[(nf * 16 + l15) * 32 + quad * 8];
            acc[0][nf] = __builtin_amdgcn_mfma_f32_16x16x32_bf16(a0, b, acc[0][nf], 0, 0, 0);
            acc[1][nf] = __builtin_amdgcn_mfma_f32_16x16x32_bf16(a1, b, acc[1][nf], 0, 0, 0);
        }
        __syncthreads();
        if (more) {
            #pragma unroll
            for (int i = 0; i < 16; ++i) f[i] = fn_[i];
        }
    }

    #pragma unroll
    for (int m = 0; m < 2; ++m) {
        #pragma unroll
        for (int reg = 0; reg < 4; ++reg) {
            const int gr = row0 + w * 32 + m * 16 + quad * 4 + reg;
            if (gr >= n) continue;
            #pragma unroll
            for (int nf = 0; nf < NFRAG; ++nf) {
                const int col = nf * 16 + l15;
                float x = acc[m][nf][reg] + (BIAS ? bias[col] : 0.f);
                if (RELU) x = lrelu(x);
                C[(size_t)gr * ldc + col] = x;
            }
        }
    }
}

// ---------------------------------------------------------------------------
// Fused double GEMM, 8-wave / reg-A-fragment / double-buffered-W version.
// C = epi2( epi1(A@Wa + ba) @ Wb + bb [+ res] ).  BM=128, K=M=192.
// Each wave owns 16 rows; its A-fragment is loaded straight to registers
// (16 rows x 128B contiguous per tile), W tiles double-buffer in LDS with
// one barrier per K-tile.  The 128x192 bf16 intermediate V is wave-private
// in LDS (phase-1 output rows == phase-2 input rows per wave).
// ---------------------------------------------------------------------------
template <bool ABF, bool RELU1, bool RELU2, bool RES, bool LNORM, bool BN,
          bool BNSTAT, bool CF32, bool CBF>
__global__ __launch_bounds__(512, 4) void gemm2_mfma(
    const void* __restrict__ Ain, const ushort_t* __restrict__ wta,
    const float* __restrict__ bias1, const ushort_t* __restrict__ wtb,
    const float* __restrict__ bias2, const void* __restrict__ resin,
    float* __restrict__ C, ushort_t* __restrict__ Cbf,
    const float* __restrict__ bnsum, const float* __restrict__ bng,
    const float* __restrict__ bnb, float* __restrict__ bnacc,
    const float* __restrict__ lg, const float* __restrict__ lb, int n)
{
    constexpr int VST = 200;
    __shared__ ushort_t Vs[128 * VST];      // 51200 B (wave-private 16-row slabs)
    __shared__ ushort_t Ws[2][192 * 32];    // 2 x 12288 B double buffer
    __shared__ float scs[DDIM], shs[DDIM];
    const int tid = threadIdx.x;
    const int lane = tid & 63, w = tid >> 6;      // 8 waves
    const int quad = lane >> 4, l15 = lane & 15;
    const int row0 = blockIdx.x * 128;
    const int myrow = row0 + w * 16 + l15;        // A-fragment row
    const bool rok = myrow < n;

    if constexpr (BN) {
        const float invN = 1.0f / (float)NN;
        for (int j = tid; j < DDIM; j += 512) {
            const float mu = bnsum[j] * invN;
            const float var = bnsum[DDIM + j] * invN - mu * mu;
            const float sc = bng[j] * rsqrtf(var + EPS_LN);
            scs[j] = sc;
            shs[j] = fmaf(-mu, sc, bnb[j]);
        }
    }

    f32x4 acc[12];
    #pragma unroll
    for (int nf = 0; nf < 12; ++nf) acc[nf] = (f32x4){0.f, 0.f, 0.f, 0.f};

    const float*    aF = (const float*)Ain    + (size_t)myrow * DDIM + quad * 8;
    const ushort_t* aB = (const ushort_t*)Ain + (size_t)myrow * DDIM + quad * 8;

    // ---- helpers -----------------------------------------------------------
    auto stageW = [&](const ushort_t* wt, int t, int b) {
        const int k0 = t << 5;
        for (int s = tid; s < 768; s += 512) {
            const int col = s >> 2, part = s & 3;
            *(uint4*)&Ws[b][col * 32 + part * 8] =
                *(const uint4*)(wt + (size_t)col * DDIM + k0 + part * 8);
        }
    };
    auto loadA = [&](int t, float* fo, uint4& uo) {
        if constexpr (!ABF) {
            if (rok) {
                const float4 p0 = *(const float4*)(aF + t * 32);
                const float4 p1 = *(const float4*)(aF + t * 32 + 4);
                fo[0] = p0.x; fo[1] = p0.y; fo[2] = p0.z; fo[3] = p0.w;
                fo[4] = p1.x; fo[5] = p1.y; fo[6] = p1.z; fo[7] = p1.w;
            } else {
                #pragma unroll
                for (int i = 0; i < 8; ++i) fo[i] = 0.f;
            }
        } else {
            uo = rok ? *(const uint4*)(aB + t * 32) : make_uint4(0u, 0u, 0u, 0u);
        }
    };
    auto makeA = [&](const float* fi, const uint4& ui, int t) -> bf16x8 {
        if constexpr (!ABF) {
            union { uint_t u[4]; bf16x8 v; } r;
            #pragma unroll
            for (int i = 0; i < 4; ++i)
                r.u[i] = (uint_t)f2bf(fi[2 * i]) | ((uint_t)f2bf(fi[2 * i + 1]) << 16);
            return r.v;
        } else if constexpr (BN) {
            const int c0 = (t << 5) + quad * 8;
            const float4 sc0 = *(const float4*)&scs[c0];
            const float4 sc1 = *(const float4*)&scs[c0 + 4];
            const float4 sh0 = *(const float4*)&shs[c0];
            const float4 sh1 = *(const float4*)&shs[c0 + 4];
            const uint_t* uw = (const uint_t*)&ui;
            float x[8];
            #pragma unroll
            for (int i = 0; i < 4; ++i) {
                x[2 * i]     = bf2f((ushort_t)(uw[i] & 0xffffu));
                x[2 * i + 1] = bf2f((ushort_t)(uw[i] >> 16));
            }
            x[0] = fmaf(x[0], sc0.x, sh0.x); x[1] = fmaf(x[1], sc0.y, sh0.y);
            x[2] = fmaf(x[2], sc0.z, sh0.z); x[3] = fmaf(x[3], sc0.w, sh0.w);
            x[4] = fmaf(x[4], sc1.x, sh1.x); x[5] = fmaf(x[5], sc1.y, sh1.y);
            x[6] = fmaf(x[6], sc1.z, sh1.z); x[7] = fmaf(x[7], sc1.w, sh1.w);
            union { uint_t u[4]; bf16x8 v; } r;
            #pragma unroll
            for (int i = 0; i < 4; ++i)
                r.u[i] = (uint_t)f2bf(x[2 * i]) | ((uint_t)f2bf(x[2 * i + 1]) << 16);
            return r.v;
        } else {
            return __builtin_bit_cast(bf16x8, ui);
        }
    };

    // ---------------- phase 1: acc = A @ Wa ----------------
    float fc[8]; uint4 uc;
    stageW(wta, 0, 0);
    loadA(0, fc, uc);
    __syncthreads();
    #pragma unroll 2
    for (int t = 0; t < 6; ++t) {
        const int b = t & 1;
        if (t < 5) stageW(wta, t + 1, b ^ 1);
        float fn[8]; uint4 un;
        if (t < 5) loadA(t + 1, fn, un);
        const bf16x8 a = makeA(fc, uc, t);
        #pragma unroll
        for (int nf = 0; nf < 12; ++nf) {
            const bf16x8 bb = *(const bf16x8*)&Ws[b][(nf * 16 + l15) * 32 + quad * 8];
            acc[nf] = __builtin_amdgcn_mfma_f32_16x16x32_bf16(a, bb, acc[nf], 0, 0, 0);
        }
        __syncthreads();
        if (t < 5) {
            if constexpr (!ABF) {
                #pragma unroll
                for (int i = 0; i < 8; ++i) fc[i] = fn[i];
            } else uc = un;
        }
    }

    // ---- phase-1 epilogue: bias (+relu) -> Vs bf16 (wave-private); re-zero
    {
        float b1r[12];
        #pragma unroll
        for (int nf = 0; nf < 12; ++nf) b1r[nf] = bias1[nf * 16 + l15];
        #pragma unroll
        for (int reg = 0; reg < 4; ++reg) {
            ushort_t* vrow = &Vs[(w * 16 + quad * 4 + reg) * VST + l15];
            #pragma unroll
            for (int nf = 0; nf < 12; ++nf) {
                float x = acc[nf][reg] + b1r[nf];
                if (RELU1) x = lrelu(x);
                vrow[nf * 16] = f2bf(x);
                acc[nf][reg] = 0.f;
            }
        }
    }
    stageW(wtb, 0, 0);
    __syncthreads();

    // ---------------- phase 2: acc = V @ Wb ----------------
    #pragma unroll 2
    for (int t = 0; t < 6; ++t) {
        const int b = t & 1;
        if (t < 5) stageW(wtb, t + 1, b ^ 1);
        const bf16x8 a = *(const bf16x8*)&Vs[(w * 16 + l15) * VST + (t << 5) + quad * 8];
        #pragma unroll
        for (int nf = 0; nf < 12; ++nf) {
            const bf16x8 bb = *(const bf16x8*)&Ws[b][(nf * 16 + l15) * 32 + quad * 8];
            acc[nf] = __builtin_amdgcn_mfma_f32_16x16x32_bf16(a, bb, acc[nf], 0, 0, 0);
        }
        __syncthreads();
    }

    // ---------------- phase-2 epilogue ----------------
    int   col[12];
    float bia[12];
    #pragma unroll
    for (int nf = 0; nf < 12; ++nf) {
        col[nf] = nf * 16 + l15;
        bia[nf] = bias2[col[nf]];
    }
    float rsc[12], rsh[12];
    if constexpr (BN && RES) {
        #pragma unroll
        for (int nf = 0; nf < 12; ++nf) {
            rsc[nf] = scs[col[nf]];
            rsh[nf] = shs[col[nf]];
        }
    }
    float cs[12], cs2[12];
    if constexpr (BNSTAT) {
        #pragma unroll
        for (int nf = 0; nf < 12; ++nf) { cs[nf] = 0.f; cs2[nf] = 0.f; }
    }
    #pragma unroll
    for (int reg = 0; reg < 4; ++reg) {
        const int gr = row0 + w * 16 + quad * 4 + reg;
        const bool ok = gr < n;
        float v[12];
        #pragma unroll
        for (int nf = 0; nf < 12; ++nf) {
            float x = acc[nf][reg] + bia[nf];
            if constexpr (RES) {
                float r;
                if constexpr (ABF)
                    r = ok ? bf2f(((const ushort_t*)resin)[(size_t)gr * DDIM + col[nf]]) : 0.f;
                else
                    r = ok ? ((const float*)resin)[(size_t)gr * DDIM + col[nf]] : 0.f;
                if constexpr (BN) r = fmaf(r, rsc[nf], rsh[nf]);
                x += r;
            }
            v[nf] = x;
        }
        if constexpr (LNORM) {
            float s = 0.f, s2 = 0.f;
            #pragma unroll
            for (int nf = 0; nf < 12; ++nf) { s += v[nf]; s2 = fmaf(v[nf], v[nf], s2); }
            #pragma unroll
            for (int off = 1; off < 16; off <<= 1) {
                s  += __shfl_xor(s, off);
                s2 += __shfl_xor(s2, off);
            }
            const float mu = s * (1.0f / DDIM);
            const float var = s2 * (1.0f / DDIM) - mu * mu;
            const float rs = rsqrtf(var + EPS_LN);
            #pragma unroll
            for (int nf = 0; nf < 12; ++nf)
                v[nf] = fmaf((v[nf] - mu) * rs, lg[col[nf]], lb[col[nf]]);
        }
        #pragma unroll
        for (int nf = 0; nf < 12; ++nf) {
            float x = v[nf];
            if (RELU2) x = lrelu(x);
            if constexpr (BNSTAT) {
                const float xa = ok ? x : 0.f;
                cs[nf] += xa;
                cs2[nf] = fmaf(xa, xa, cs2[nf]);
            }
            if (ok) {
                if constexpr (CF32) C[(size_t)gr * DDIM + col[nf]] = x;
                if constexpr (CBF)  Cbf[(size_t)gr * DDIM + col[nf]] = f2bf(x);
            }
        }
    }
    if constexpr (BNSTAT) {
        float* bsA = (float*)&Ws[0][0];     // [8][192] sums   (aliases Ws[0])
        float* bsB = bsA + 8 * 192;         // [8][192] sumsq  (fills rest of Ws[0])
        #pragma unroll
        for (int nf = 0; nf < 12; ++nf) {
            cs[nf]  += __shfl_xor(cs[nf], 16);  cs[nf]  += __shfl_xor(cs[nf], 32);
            cs2[nf] += __shfl_xor(cs2[nf], 16); cs2[nf] += __shfl_xor(cs2[nf], 32);
        }
        if (quad == 0) {
            #pragma unroll
            for (int nf = 0; nf < 12; ++nf) {
                bsA[w * 192 + col[nf]] = cs[nf];
                bsB[w * 192 + col[nf]] = cs2[nf];
            }
        }
        __syncthreads();
        if (tid < DDIM) {
            float s = 0.f, s2 = 0.f;
            #pragma unroll
            for (int k = 0; k < 8; ++k) {
                s  += bsA[k * 192 + tid];
                s2 += bsB[k * 192 + tid];
            }
            atomicAdd(&bnacc[tid], s);
            atomicAdd(&bnacc[DDIM + tid], s2);
        }
    }
}

// ---------------------------------------------------------------------------
// RGCN concat GEMM, 8-wave / reg-A / double-buffered-W version:
// Cbf = bf16([A1(bf16,K=192) | A2(bf16,K=384)] @ WT[192][576] + b).
// In-place safe for Cbf == A1 (per-block rows fully consumed before write).
// ---------------------------------------------------------------------------
__global__ __launch_bounds__(512, 4) void gemm_cat(
    const ushort_t* __restrict__ A1, const ushort_t* __restrict__ A2,
    const ushort_t* __restrict__ WT, const float* __restrict__ bias,
    ushort_t* __restrict__ Cbf, int n)
{
    __shared__ ushort_t Ws[2][192 * 32];    // 24 KB
    const int tid = threadIdx.x;
    const int lane = tid & 63, w = tid >> 6;
    const int quad = lane >> 4, l15 = lane & 15;
    const int row0 = blockIdx.x * 128;
    const int myrow = row0 + w * 16 + l15;
    const bool rok = myrow < n;

    f32x4 acc[12];
    #pragma unroll
    for (int nf = 0; nf < 12; ++nf) acc[nf] = (f32x4){0.f, 0.f, 0.f, 0.f};

    const ushort_t* a1p = A1 + (size_t)myrow * 192 + quad * 8;
    const ushort_t* a2p = A2 + (size_t)myrow * 384 + quad * 8;

    auto stageW = [&](int t, int b) {
        const int k0 = t << 5;
        for (int s = tid; s < 768; s += 512) {
            const int col = s >> 2, part = s & 3;
            *(uint4*)&Ws[b][col * 32 + part * 8] =
                *(const uint4*)(WT + (size_t)col * 576 + k0 + part * 8);
        }
    };
    auto loadA = [&](int t) -> uint4 {
        if (!rok) return make_uint4(0u, 0u, 0u, 0u);
        const ushort_t* p = (t < 6) ? (a1p + t * 32) : (a2p + (t - 6) * 32);
        return *(const uint4*)p;
    };

    uint4 uc;
    stageW(0, 0);
    uc = loadA(0);
    __syncthreads();

    #pragma unroll 2
    for (int t = 0; t < 18; ++t) {
        const int b = t & 1;
        if (t < 17) stageW(t + 1, b ^ 1);
        uint4 un;
        if (t < 17) un = loadA(t + 1);
        const bf16x8 a = __builtin_bit_cast(bf16x8, uc);
        #pragma unroll
        for (int nf = 0; nf < 12; ++nf) {
            const bf16x8 bb = *(const bf16x8*)&Ws[b][(nf * 16 + l15) * 32 + quad * 8];
            acc[nf] = __builtin_amdgcn_mfma_f32_16x16x32_bf16(a, bb, acc[nf], 0, 0, 0);
        }
        __syncthreads();
        if (t < 17) uc = un;
    }

    #pragma unroll
    for (int reg = 0; reg < 4; ++reg) {
        const int gr = row0 + w * 16 + quad * 4 + reg;
        if (gr >= n) continue;
        #pragma unroll
        for (int nf = 0; nf < 12; ++nf) {
            const int col = nf * 16 + l15;
            Cbf[(size_t)gr * DDIM + col] = f2bf(acc[nf][reg] + bias[col]);
        }
    }
}

// ---------------------------------------------------------------------------
__global__ __launch_bounds__(256) void embed_nc_k(
    const float* __restrict__ np_, const float* __restrict__ cp,
    const float* __restrict__ Wn, const float* __restrict__ bnum,
    const float* __restrict__ Wc, const float* __restrict__ bc,
    float* __restrict__ x)
{
    const int idx = blockIdx.x * 256 + threadIdx.x;
    if (idx >= NN * 128) return;
    const int node = idx >> 7;
    const int c = idx & 127;
    float acc;
    if (c < 64) {
        acc = bnum[c];
        #pragma unroll
        for (int k = 0; k < 6; ++k) acc = fmaf(np_[node * 6 + k], Wn[k * 64 + c], acc);
    } else {
        const int cc = c - 64;
        acc = bc[cc];
        #pragma unroll
        for (int k = 0; k < 7; ++k) acc = fmaf(cp[node * 7 + k], Wc[k * 64 + cc], acc);
    }
    x[(size_t)node * DDIM + 64 + c] = lrelu(acc);
}

// ---------------------------------------------------------------------------
// Contrastive: fnorm -> bf16 rows, MFMA sim, closs
// ---------------------------------------------------------------------------
__global__ __launch_bounds__(256) void fnorm_k(const float* __restrict__ x,
                                               ushort_t* __restrict__ fnb)
{
    const int wave = threadIdx.x >> 6, lane = threadIdx.x & 63;
    const int row = blockIdx.x * 4 + wave;
    if (row >= TRAIN) return;
    const float* xr = x + (size_t)row * DDIM;
    const float v0 = xr[lane], v1 = xr[lane + 64], v2 = xr[lane + 128];
    const float q = wave_sum(v0 * v0 + v1 * v1 + v2 * v2);
    const float inv = 1.0f / sqrtf(q);
    ushort_t* fr = fnb + (size_t)row * DDIM;
    fr[lane]       = f2bf(v0 * inv);
    fr[lane + 64]  = f2bf(v1 * inv);
    fr[lane + 128] = f2bf(v2 * inv);
}

__global__ __launch_bounds__(256) void sim_mfma(const ushort_t* __restrict__ fnb,
    const int* __restrict__ lab, float* __restrict__ row_ex, float* __restrict__ row_mt)
{
    __shared__ ushort_t Ai[128 * 32];
    __shared__ ushort_t Bj[128 * 32];
    __shared__ int Li[128], Lj[128];
    const int tid = threadIdx.x, lane = tid & 63, w = tid >> 6;
    const int quad = lane >> 4, l15 = lane & 15;
    const int i0 = blockIdx.x * 128, j0 = blockIdx.y * 128;
    if (tid < 128) Li[tid] = lab[i0 + tid];
    else           Lj[tid - 128] = lab[j0 + tid - 128];
    const int iw = (w >> 1) * 64, jw = (w & 1) * 64;

    f32x4 acc[4][4];
    #pragma unroll
    for (int m = 0; m < 4; ++m)
        #pragma unroll
        for (int nf = 0; nf < 4; ++nf)
            acc[m][nf] = (f32x4){0.f, 0.f, 0.f, 0.f};

    for (int k0 = 0; k0 < DDIM; k0 += 32) {
        #pragma unroll
        for (int s = tid; s < 512; s += 256) {
            const int row = s >> 2, part = s & 3;
            *(uint4*)&Ai[row * 32 + part * 8] =
                *(const uint4*)(fnb + (size_t)(i0 + row) * DDIM + k0 + part * 8);
            *(uint4*)&Bj[row * 32 + part * 8] =
                *(const uint4*)(fnb + (size_t)(j0 + row) * DDIM + k0 + part * 8);
        }
        __syncthreads();
        bf16x8 a[4], b[4];
        #pragma unroll
        for (int m = 0; m < 4; ++m)
            a[m] = *(const bf16x8*)&Ai[(iw + m * 16 + l15) * 32 + quad * 8];
        #pragma unroll
        for (int nf = 0; nf < 4; ++nf)
            b[nf] = *(const bf16x8*)&Bj[(jw + nf * 16 + l15) * 32 + quad * 8];
        #pragma unroll
        for (int m = 0; m < 4; ++m)
            #pragma unroll
            for (int nf = 0; nf < 4; ++nf)
                acc[m][nf] = __builtin_amdgcn_mfma_f32_16x16x32_bf16(a[m], b[nf], acc[m][nf], 0, 0, 0);
        __syncthreads();
    }

    int lj[4];
    #pragma unroll
    for (int nf = 0; nf < 4; ++nf) lj[nf] = Lj[jw + nf * 16 + l15];
    #pragma unroll
    for (int m = 0; m < 4; ++m) {
        #pragma unroll
        for (int reg = 0; reg < 4; ++reg) {
            const int rl = iw + m * 16 + quad * 4 + reg;
            const int li = Li[rl];
            float se = 0.f, sm = 0.f;
            #pragma unroll
            for (int nf = 0; nf < 4; ++nf) {
                const float e = __expf(acc[m][nf][reg] * 2.0f);  // 1/TEMP = 2
                se += e;
                if (li == lj[nf]) sm += e;
            }
            #pragma unroll
            for (int off = 1; off < 16; off <<= 1) {
                se += __shfl_xor(se, off);
                sm += __shfl_xor(sm, off);
            }
            if (l15 == 0) {
                atomicAdd(&row_ex[i0 + rl], se);
                atomicAdd(&row_mt[i0 + rl], sm);
            }
        }
    }
}

__global__ __launch_bounds__(256) void closs_k(const float* __restrict__ ex,
    const float* __restrict__ mt, float* __restrict__ out)
{
    float s = 0.f;
    for (int i = threadIdx.x; i < TRAIN; i += 256) s += -logf(mt[i] / ex[i]);
    s = wave_sum(s);
    __shared__ float red[4];
    const int wave = threadIdx.x >> 6, lane = threadIdx.x & 63;
    if (lane == 0) red[wave] = s;
    __syncthreads();
    if (threadIdx.x == 0) out[0] = (red[0] + red[1] + red[2] + red[3]) / (float)TRAIN;
}

// ---------------------------------------------------------------------------
// CSR build: counts -> 3-kernel parallel exclusive scan -> fill.
// ---------------------------------------------------------------------------
__global__ __launch_bounds__(256) void cnt_i_k(const int* __restrict__ dst,
    const int* __restrict__ ety, int* __restrict__ cnti)
{
    const int e = blockIdx.x * 256 + threadIdx.x;
    if (e >= EE) return;
    atomicAdd(&cnti[(size_t)ety[e] * NN + dst[e]], 1);
}

__global__ __launch_bounds__(256) void part_k(const int* __restrict__ cnti,
                                              int* __restrict__ part)
{
    __shared__ int sh[256];
    const int tid = threadIdx.x;
    const int i0 = blockIdx.x * 2048 + tid * 8;
    int s = 0;
    #pragma unroll
    for (int j = 0; j < 8; ++j) {
        const int i = i0 + j;
        s += (i < TOTSEG) ? cnti[i] : 0;
    }
    sh[tid] = s;
    __syncthreads();
    #pragma unroll
    for (int off = 128; off > 0; off >>= 1) {
        if (tid < off) sh[tid] += sh[tid + off];
        __syncthreads();
    }
    if (tid == 0) part[blockIdx.x] = sh[0];
}

__global__ __launch_bounds__(128) void scanp_k(int* __restrict__ part)
{
    __shared__ int sh[128];
    const int tid = threadIdx.x;
    const int v = (tid < SCAN_NB) ? part[tid] : 0;
    sh[tid] = v;
    __syncthreads();
    #pragma unroll
    for (int off = 1; off < 128; off <<= 1) {
        const int t = (tid >= off) ? sh[tid - off] : 0;
        __syncthreads();
        sh[tid] += t;
        __syncthreads();
    }
    if (tid < SCAN_NB) part[tid] = sh[tid] - v;   // exclusive
}

__global__ __launch_bounds__(256) void offs_k(const int* __restrict__ cnti,
    const int* __restrict__ part, int* __restrict__ offs)
{
    __shared__ int sh[256];
    const int tid = threadIdx.x;
    const int i0 = blockIdx.x * 2048 + tid * 8;
    int v[8];
    int loc = 0;
    #pragma unroll
    for (int j = 0; j < 8; ++j) {
        const int i = i0 + j;
        v[j] = (i < TOTSEG) ? cnti[i] : 0;
        loc += v[j];
    }
    sh[tid] = loc;
    __syncthreads();
    #pragma unroll
    for (int off = 1; off < 256; off <<= 1) {
        const int t = (tid >= off) ? sh[tid - off] : 0;
        __syncthreads();
        sh[tid] += t;
        __syncthreads();
    }
    int pre = part[blockIdx.x] + sh[tid] - loc;
    #pragma unroll
    for (int j = 0; j < 8; ++j) {
        const int i = i0 + j;
        if (i < TOTSEG) offs[i] = pre;
        pre += v[j];
    }
}

__global__ __launch_bounds__(256) void fill_k(const int* __restrict__ src,
    const int* __restrict__ dst, const int* __restrict__ ety,
    int* __restrict__ offs, int* __restrict__ elist)
{
    const int e = blockIdx.x * 256 + threadIdx.x;
    if (e >= EE) return;
    const int pos = atomicAdd(&offs[(size_t)ety[e] * NN + dst[e]], 1);
    elist[pos] = src[e];
}

// ---------------------------------------------------------------------------
// Gather (bf16 in, bf16 out), uint-vectorized: row of 192 bf16 = 96 uints;
// lane handles uints {lane, lane+64 (lane<32)} = cols {2l,2l+1, 128+2l,129+2l}.
// ---------------------------------------------------------------------------
__global__ __launch_bounds__(256) void gather_bf_k(const ushort_t* __restrict__ xb,
    const int* __restrict__ elist, const int* __restrict__ offs,
    const int* __restrict__ cnti, ushort_t* __restrict__ aggb)
{
    const int wave = threadIdx.x >> 6, lane = threadIdx.x & 63;
    const int d = blockIdx.x * 4 + wave;
    if (d >= NN) return;
    const bool lo = lane < 32;
    #pragma unroll
    for (int r = 0; r < 2; ++r) {
        const int seg = r * NN + d;
        const int end = offs[seg];
        const int c = cnti[seg];
        float a0 = 0.f, a1 = 0.f, b0 = 0.f, b1 = 0.f;
        int e = end - c;
        for (; e + 1 < end; e += 2) {
            const int s0 = elist[e], s1 = elist[e + 1];
            const uint_t* r0 = (const uint_t*)(xb + (size_t)s0 * DDIM);
            const uint_t* r1 = (const uint_t*)(xb + (size_t)s1 * DDIM);
            const uint_t x0 = r0[lane], x1 = r1[lane];
            uint_t y0 = 0u, y1 = 0u;
            if (lo) { y0 = r0[64 + lane]; y1 = r1[64 + lane]; }
            a0 += bf2f((ushort_t)(x0 & 0xffffu)) + bf2f((ushort_t)(x1 & 0xffffu));
            a1 += bf2f((ushort_t)(x0 >> 16))     + bf2f((ushort_t)(x1 >> 16));
            b0 += bf2f((ushort_t)(y0 & 0xffffu)) + bf2f((ushort_t)(y1 & 0xffffu));
            b1 += bf2f((ushort_t)(y0 >> 16))     + bf2f((ushort_t)(y1 >> 16));
        }
        if (e < end) {
            const int s0 = elist[e];
            const uint_t* r0 = (const uint_t*)(xb + (size_t)s0 * DDIM);
            const uint_t x0 = r0[lane];
            uint_t y0 = 0u;
            if (lo) y0 = r0[64 + lane];
            a0 += bf2f((ushort_t)(x0 & 0xffffu));
            a1 += bf2f((ushort_t)(x0 >> 16));
            b0 += bf2f((ushort_t)(y0 & 0xffffu));
            b1 += bf2f((ushort_t)(y0 >> 16));
        }
        const float inv = 1.0f / (float)max(c, 1);
        uint_t* ar = (uint_t*)(aggb + (size_t)d * 384 + r * DDIM);
        ar[lane] = (uint_t)f2bf(a0 * inv) | ((uint_t)f2bf(a1 * inv) << 16);
        if (lo)
            ar[64 + lane] = (uint_t)f2bf(b0 * inv) | ((uint_t)f2bf(b1 * inv) << 16);
    }
}

__global__ __launch_bounds__(256) void logits_k(const float* __restrict__ h,
    const float* __restrict__ Wm3, const float* __restrict__ bm3, float* __restrict__ out)
{
    const int wave = threadIdx.x >> 6, lane = threadIdx.x & 63;
    const int row = blockIdx.x * 4 + wave;
    if (row >= NN) return;
    const float* hr = h + (size_t)row * DDIM;
    float s0 = 0.f, s1 = 0.f;
    #pragma unroll
    for (int p = 0; p < 3; ++p) {
        const int k = lane + p * 64;
        const float v = hr[k];
        s0 = fmaf(v, Wm3[k * 2 + 0], s0);
        s1 = fmaf(v, Wm3[k * 2 + 1], s1);
    }
    #pragma unroll
    for (int off = 32; off > 0; off >>= 1) {
        s0 += __shfl_down(s0, off);
        s1 += __shfl_down(s1, off);
    }
    if (lane == 0) {
        out[(size_t)row * 2 + 0] = s0 + bm3[0];
        out[(size_t)row * 2 + 1] = s1 + bm3[1];
    }
}

// ---------------------------------------------------------------------------
extern "C" void kernel_launch(void* const* d_in, const int* in_sizes, int n_in,
                              void* d_out, int out_size, void* d_ws, size_t ws_size,
                              hipStream_t stream)
{
    const float* tweet   = (const float*)d_in[0];
    const float* np_     = (const float*)d_in[1];
    const float* cp      = (const float*)d_in[2];
    const float* Wt      = (const float*)d_in[3];
    const float* bt      = (const float*)d_in[4];
    const float* Wn      = (const float*)d_in[5];
    const float* bnum    = (const float*)d_in[6];
    const float* Wc      = (const float*)d_in[7];
    const float* bc      = (const float*)d_in[8];
    const float* Wv      = (const float*)d_in[9];
    const float* bv      = (const float*)d_in[10];
    const float* Wo      = (const float*)d_in[11];
    const float* bo      = (const float*)d_in[12];
    const float* ln1g    = (const float*)d_in[13];
    const float* ln1b    = (const float*)d_in[14];
    const float* bng     = (const float*)d_in[15];
    const float* bnb     = (const float*)d_in[16];
    const float* W1      = (const float*)d_in[17];
    const float* b1      = (const float*)d_in[18];
    const float* W2      = (const float*)d_in[19];
    const float* b2      = (const float*)d_in[20];
    const float* ln2g    = (const float*)d_in[21];
    const float* ln2b    = (const float*)d_in[22];
    const float* Wrel    = (const float*)d_in[23];
    const float* Wroot   = (const float*)d_in[24];
    const float* rgcnb   = (const float*)d_in[25];
    const float* Wm1     = (const float*)d_in[26];
    const float* bm1     = (const float*)d_in[27];
    const float* Wm2     = (const float*)d_in[28];
    const float* bm2     = (const float*)d_in[29];
    const float* Wm3     = (const float*)d_in[30];
    const float* bm3     = (const float*)d_in[31];
    const int*   eidx    = (const int*)d_in[32];
    const int*   esrc    = eidx;
    const int*   edst    = eidx + EE;
    const int*   ety     = (const int*)d_in[33];
    const int*   labels  = (const int*)d_in[34];
    float* out = (float*)d_out;

    float* ws = (float*)d_ws;
    const size_t ND = (size_t)NN * DDIM;
    float* B0    = ws;
    float* B1    = B0 + ND;       // unused (layout keeper)
    float* B2    = B1 + ND;       // X1BF (bf16 ln1-out); AGGB during RGCN; MLP f32 out
    float* B3    = B2 + ND;       // front: XBF (bf16 x/h); then WTg
    float* ROWEX = B3 + ND;
    float* ROWMT = ROWEX + TRAIN;
    float* BNS   = ROWMT + TRAIN;             // 6 layers x [sum(192) | sumsq(192)]
    int*   CNTI  = (int*)(BNS + 12 * DDIM);   // 2*NN
    int*   OFFS  = CNTI + 2 * NN;             // 2*NN (becomes end-offsets)
    int*   ELIST = OFFS + 2 * NN;             // EE
    int*   PART  = ELIST + EE;                // 128
    ushort_t* FNb = (ushort_t*)(PART + 128);
    ushort_t* WTt = FNb + (size_t)TRAIN * DDIM;   // 64x768
    ushort_t* WTs = WTt + 49152;                  // 29 x 36864 (24/25/26 unused)
    ushort_t* WTv    = WTs;
    ushort_t* WTo    = WTs + (size_t)6  * 36864;
    ushort_t* WT1    = WTs + (size_t)12 * 36864;
    ushort_t* WT2    = WTs + (size_t)18 * 36864;
    ushort_t* WTm1   = WTs + (size_t)27 * 36864;
    ushort_t* WTm2   = WTs + (size_t)28 * 36864;
    ushort_t* XBF  = (ushort_t*)B3;               // NN x 192 bf16 (x, then h1, h2)
    ushort_t* WTg  = (ushort_t*)B3 + ND;          // 192 x 576 bf16 (in B3 tail)
    ushort_t* X1BF = (ushort_t*)B2;               // NN x 192 bf16 (ln1 out)
    ushort_t* AGGB = (ushort_t*)B2;               // NN x 384 bf16 (RGCN only)

    const int gx = (NN + 127) / 128;   // 782
    const dim3 blk(256);
    const dim3 blk5(512);

    prep_w<<<29 * 144 + 192, blk, 0, stream>>>(Wt, Wv, Wo, W1, W2, Wrel, Wroot, Wm1, Wm2, WTt, WTs, WTg);

    // ---- CSR build (edge structure only; reused by both RGCN layers)
    hipMemsetAsync(CNTI, 0, 2 * NN * sizeof(int), stream);
    cnt_i_k<<<(EE + 255) / 256, blk, 0, stream>>>(edst, ety, CNTI);
    part_k<<<SCAN_NB, blk, 0, stream>>>(CNTI, PART);
    scanp_k<<<1, 128, 0, stream>>>(PART);
    offs_k<<<SCAN_NB, blk, 0, stream>>>(CNTI, PART, OFFS);
    fill_k<<<(EE + 255) / 256, blk, 0, stream>>>(esrc, edst, ety, OFFS, ELIST);

    // ---- input embedding
    gemm_mfma<4, true, true><<<gx, blk, 0, stream>>>(tweet, WTt, bt, B0, NN, 768, DDIM);
    embed_nc_k<<<(NN * 128 + 255) / 256, blk, 0, stream>>>(np_, cp, Wn, bnum, Wc, bc, B0);

    // ---- 6 layers, each = 2 fused double-GEMMs (BN finalize folded in)
    hipMemsetAsync(BNS, 0, 12 * DDIM * sizeof(float), stream);
    for (int i = 0; i < NLAYER; ++i) {
        const size_t wo = (size_t)i * 36864;
        float* bnacc_i = BNS + (size_t)i * 2 * DDIM;
        // X1BF = bf16( ln1(B0 + (B0@Wv+bv)@Wo + bo) ), BN-stat accumulate
        gemm2_mfma<false, false, false, true, true, false, true, false, true>
            <<<gx, blk5, 0, stream>>>(
            B0, WTv + wo, bv + i * DDIM, WTo + wo, bo + i * DDIM, B0,
            nullptr, X1BF, nullptr, nullptr, nullptr, bnacc_i,
            ln1g + i * DDIM, ln1b + i * DDIM, NN);
        // B0 = ln2( bn(x1) + lrelu(bn(x1)@W1+b1)@W2 + b2 ); last layer also bf16 x
        if (i < NLAYER - 1)
            gemm2_mfma<true, true, false, true, true, true, false, true, false>
                <<<gx, blk5, 0, stream>>>(
                X1BF, WT1 + wo, b1 + i * DDIM, WT2 + wo, b2 + i * DDIM, X1BF,
                B0, nullptr, bnacc_i, bng + i * DDIM, bnb + i * DDIM, nullptr,
                ln2g + i * DDIM, ln2b + i * DDIM, NN);
        else
            gemm2_mfma<true, true, false, true, true, true, false, true, true>
                <<<gx, blk5, 0, stream>>>(
                X1BF, WT1 + wo, b1 + i * DDIM, WT2 + wo, b2 + i * DDIM, X1BF,
                B0, XBF, bnacc_i, bng + i * DDIM, bnb + i * DDIM, nullptr,
                ln2g + i * DDIM, ln2b + i * DDIM, NN);
    }

    // ---- contrastive loss (before RGCN so B2/B3 can be reused)
    hipMemsetAsync(ROWEX, 0, 2 * TRAIN * sizeof(float), stream);
    fnorm_k<<<TRAIN / 4, blk, 0, stream>>>(B0, FNb);
    sim_mfma<<<dim3(TRAIN / 128, TRAIN / 128), blk, 0, stream>>>(FNb, labels, ROWEX, ROWMT);
    closs_k<<<1, blk, 0, stream>>>(ROWEX, ROWMT, out + 2 * (size_t)NN);

    // ---- RGCN pass 1: h1 = bf16([x | agg(x)] @ [Wroot;Wcat] + b), in place
    gather_bf_k<<<(NN + 3) / 4, blk, 0, stream>>>(XBF, ELIST, OFFS, CNTI, AGGB);
    gemm_cat<<<gx, blk5, 0, stream>>>(XBF, AGGB, WTg, rgcnb, XBF, NN);

    // ---- RGCN pass 2
    gather_bf_k<<<(NN + 3) / 4, blk, 0, stream>>>(XBF, ELIST, OFFS, CNTI, AGGB);
    gemm_cat<<<gx, blk5, 0, stream>>>(XBF, AGGB, WTg, rgcnb, XBF, NN);

    // ---- MLP head (fused pair, bf16 in) + logits
    gemm2_mfma<true, true, true, false, false, false, false, true, false>
        <<<gx, blk5, 0, stream>>>(
        XBF, WTm1, bm1, WTm2, bm2, nullptr, B2, nullptr,
        nullptr, nullptr, nullptr, nullptr, nullptr, nullptr, NN);
    logits_k<<<(NN + 3) / 4, blk, 0, stream>>>(B2, Wm3, bm3, out);
}

// Round 4
// 1851.976 us; speedup vs baseline: 1.6533x; 1.0225x over previous
//
#include <hip/hip_runtime.h>

#define NN 100000
#define EE 1000000
#define DDIM 192
#define NLAYER 6
#define TRAIN 8192
#define SLOPE 0.01f
#define EPS_LN 1e-5f
#define TOTSEG (2 * NN)
#define SCAN_NB 98           /* ceil(200000 / 2048) */

typedef float f32x4 __attribute__((ext_vector_type(4)));
typedef __bf16 bf16x8 __attribute__((ext_vector_type(8)));
typedef unsigned short ushort_t;
typedef unsigned int uint_t;

__device__ __forceinline__ float lrelu(float v) { return v > 0.0f ? v : SLOPE * v; }

__device__ __forceinline__ ushort_t f2bf(float f) {
    __bf16 h = (__bf16)f;              // HW RNE convert
    return __builtin_bit_cast(ushort_t, h);
}

__device__ __forceinline__ float bf2f(ushort_t b) {
    union { uint_t u; float f; } v; v.u = ((uint_t)b) << 16; return v.f;
}

__device__ __forceinline__ float wave_sum(float s) {
    #pragma unroll
    for (int off = 32; off > 0; off >>= 1) s += __shfl_down(s, off);
    return __shfl(s, 0);
}

// ---------------------------------------------------------------------------
// One-shot weight prep: transpose + convert to bf16.  WT[m][k] = W[k][m].
// Wroot+Wrel go into the concat matrix WTg[m][576] = [Wroot^T | W0^T | W1^T].
// ---------------------------------------------------------------------------
__global__ __launch_bounds__(256) void prep_w(
    const float* __restrict__ Wt, const float* __restrict__ Wv,
    const float* __restrict__ Wo, const float* __restrict__ W1,
    const float* __restrict__ W2, const float* __restrict__ Wrel,
    const float* __restrict__ Wroot, const float* __restrict__ Wm1,
    const float* __restrict__ Wm2, ushort_t* __restrict__ WTt,
    ushort_t* __restrict__ WTs, ushort_t* __restrict__ WTg)
{
    const int bid = blockIdx.x;
    if (bid < 29 * 144) {
        const int mat = bid / 144;
        const int o = (bid % 144) * 256 + threadIdx.x;   // < 36864
        const float* src;
        if      (mat <  6) src = Wv   + (size_t)mat * 36864;
        else if (mat < 12) src = Wo   + (size_t)(mat - 6)  * 36864;
        else if (mat < 18) src = W1   + (size_t)(mat - 12) * 36864;
        else if (mat < 24) src = W2   + (size_t)(mat - 18) * 36864;
        else if (mat < 26) src = Wrel + (size_t)(mat - 24) * 36864;
        else if (mat == 26) src = Wroot;
        else if (mat == 27) src = Wm1;
        else                src = Wm2;
        const int m = o / 192, k = o - m * 192;
        const ushort_t b = f2bf(src[(size_t)k * 192 + m]);
        if (mat == 24 || mat == 25)
            WTg[(size_t)m * 576 + 192 + (mat - 24) * 192 + k] = b;
        else if (mat == 26)
            WTg[(size_t)m * 576 + k] = b;
        else
            WTs[(size_t)mat * 36864 + o] = b;
    } else {
        const int o = (bid - 29 * 144) * 256 + threadIdx.x;  // < 49152
        const int m = o / 768, k = o - m * 768;
        WTt[o] = f2bf(Wt[(size_t)k * 64 + m]);
    }
}

// ---------------------------------------------------------------------------
// Tweet embedding GEMM, 8-wave / reg-A / dbuf-W: Cbf[:, 0:64] = bf16(lrelu(
// tweet[n x 768] @ WTt^T + bt)).  One barrier per K-tile, 24 tiles.
// ---------------------------------------------------------------------------
__global__ __launch_bounds__(512) void gemm_tweet(
    const float* __restrict__ A, const ushort_t* __restrict__ WT,
    const float* __restrict__ bias, ushort_t* __restrict__ Cbf, int n)
{
    __shared__ ushort_t Ws[2][64 * 32];     // 2 x 4 KB
    const int tid = threadIdx.x;
    const int lane = tid & 63, w = tid >> 6;
    const int quad = lane >> 4, l15 = lane & 15;
    const int row0 = blockIdx.x * 128;
    const int myrow = row0 + w * 16 + l15;
    const bool rok = myrow < n;

    f32x4 acc[4];
    #pragma unroll
    for (int nf = 0; nf < 4; ++nf) acc[nf] = (f32x4){0.f, 0.f, 0.f, 0.f};

    const float* aF = A + (size_t)myrow * 768 + quad * 8;

    auto stageW = [&](int t, int b) {
        if (tid < 256) {
            const int col = tid >> 2, part = tid & 3;
            *(uint4*)&Ws[b][col * 32 + part * 8] =
                *(const uint4*)(WT + (size_t)col * 768 + (t << 5) + part * 8);
        }
    };
    auto loadA = [&](int t, float* fo) {
        if (rok) {
            const float4 p0 = *(const float4*)(aF + t * 32);
            const float4 p1 = *(const float4*)(aF + t * 32 + 4);
            fo[0] = p0.x; fo[1] = p0.y; fo[2] = p0.z; fo[3] = p0.w;
            fo[4] = p1.x; fo[5] = p1.y; fo[6] = p1.z; fo[7] = p1.w;
        } else {
            #pragma unroll
            for (int i = 0; i < 8; ++i) fo[i] = 0.f;
        }
    };

    float fc[8];
    stageW(0, 0);
    loadA(0, fc);
    __syncthreads();
    #pragma unroll 2
    for (int t = 0; t < 24; ++t) {
        const int b = t & 1;
        if (t < 23) stageW(t + 1, b ^ 1);
        float fn[8];
        if (t < 23) loadA(t + 1, fn);
        union { uint_t u[4]; bf16x8 v; } r;
        #pragma unroll
        for (int i = 0; i < 4; ++i)
            r.u[i] = (uint_t)f2bf(fc[2 * i]) | ((uint_t)f2bf(fc[2 * i + 1]) << 16);
        #pragma unroll
        for (int nf = 0; nf < 4; ++nf) {
            const bf16x8 bb = *(const bf16x8*)&Ws[b][(nf * 16 + l15) * 32 + quad * 8];
            acc[nf] = __builtin_amdgcn_mfma_f32_16x16x32_bf16(r.v, bb, acc[nf], 0, 0, 0);
        }
        __syncthreads();
        if (t < 23) {
            #pragma unroll
            for (int i = 0; i < 8; ++i) fc[i] = fn[i];
        }
    }

    #pragma unroll
    for (int reg = 0; reg < 4; ++reg) {
        const int gr = row0 + w * 16 + quad * 4 + reg;
        if (gr >= n) continue;
        #pragma unroll
        for (int nf = 0; nf < 4; ++nf) {
            const int col = nf * 16 + l15;
            Cbf[(size_t)gr * DDIM + col] = f2bf(lrelu(acc[nf][reg] + bias[col]));
        }
    }
}

// ---------------------------------------------------------------------------
// Fused double GEMM, 8-wave / reg-A / dbuf-W.  All activations bf16.
// Cbf = epi2( epi1(A@Wa + ba) @ Wb + bb [+ res] ).  BM=128, K=M=192.
// BN: apply batchnorm (from raw sums bnsum + bng/bnb) to A on load and to
// res on the residual add.  BNSTAT: accumulate output BN stats into bnacc.
// LOGITS: epilogue emits out[row][2] = x @ Wm3 + bm3 (no Cbf store needed).
// FNORM: rows < TRAIN also emit fnb = bf16(x / ||x||) from the f32 values.
// ---------------------------------------------------------------------------
template <bool RELU1, bool RELU2, bool RES, bool LNORM, bool BN,
          bool BNSTAT, bool CBF, bool LOGITS, bool FNORM>
__global__ __launch_bounds__(512, 4) void gemm2_mfma(
    const ushort_t* __restrict__ Ain, const ushort_t* __restrict__ wta,
    const float* __restrict__ bias1, const ushort_t* __restrict__ wtb,
    const float* __restrict__ bias2, const ushort_t* __restrict__ resin,
    ushort_t* __restrict__ Cbf,
    const float* __restrict__ bnsum, const float* __restrict__ bng,
    const float* __restrict__ bnb, float* __restrict__ bnacc,
    const float* __restrict__ lg, const float* __restrict__ lb,
    const float* __restrict__ Wm3, const float* __restrict__ bm3,
    float* __restrict__ outp, ushort_t* __restrict__ fnb, int n)
{
    constexpr int VST = 200;
    __shared__ ushort_t Vs[128 * VST];      // 51200 B (wave-private 16-row slabs)
    __shared__ ushort_t Ws[2][192 * 32];    // 2 x 12288 B double buffer
    __shared__ float scs[DDIM], shs[DDIM];
    const int tid = threadIdx.x;
    const int lane = tid & 63, w = tid >> 6;      // 8 waves
    const int quad = lane >> 4, l15 = lane & 15;
    const int row0 = blockIdx.x * 128;
    const int myrow = row0 + w * 16 + l15;        // A-fragment row
    const bool rok = myrow < n;

    if constexpr (BN) {
        const float invN = 1.0f / (float)NN;
        for (int j = tid; j < DDIM; j += 512) {
            const float mu = bnsum[j] * invN;
            const float var = bnsum[DDIM + j] * invN - mu * mu;
            const float sc = bng[j] * rsqrtf(var + EPS_LN);
            scs[j] = sc;
            shs[j] = fmaf(-mu, sc, bnb[j]);
        }
    }

    f32x4 acc[12];
    #pragma unroll
    for (int nf = 0; nf < 12; ++nf) acc[nf] = (f32x4){0.f, 0.f, 0.f, 0.f};

    const ushort_t* aB = Ain + (size_t)myrow * DDIM + quad * 8;

    auto stageW = [&](const ushort_t* wt, int t, int b) {
        const int k0 = t << 5;
        for (int s = tid; s < 768; s += 512) {
            const int col = s >> 2, part = s & 3;
            *(uint4*)&Ws[b][col * 32 + part * 8] =
                *(const uint4*)(wt + (size_t)col * DDIM + k0 + part * 8);
        }
    };
    auto loadA = [&](int t) -> uint4 {
        return rok ? *(const uint4*)(aB + t * 32) : make_uint4(0u, 0u, 0u, 0u);
    };
    auto makeA = [&](const uint4& ui, int t) -> bf16x8 {
        if constexpr (BN) {
            const int c0 = (t << 5) + quad * 8;
            const float4 sc0 = *(const float4*)&scs[c0];
            const float4 sc1 = *(const float4*)&scs[c0 + 4];
            const float4 sh0 = *(const float4*)&shs[c0];
            const float4 sh1 = *(const float4*)&shs[c0 + 4];
            const uint_t* uw = (const uint_t*)&ui;
            float x[8];
            #pragma unroll
            for (int i = 0; i < 4; ++i) {
                x[2 * i]     = bf2f((ushort_t)(uw[i] & 0xffffu));
                x[2 * i + 1] = bf2f((ushort_t)(uw[i] >> 16));
            }
            x[0] = fmaf(x[0], sc0.x, sh0.x); x[1] = fmaf(x[1], sc0.y, sh0.y);
            x[2] = fmaf(x[2], sc0.z, sh0.z); x[3] = fmaf(x[3], sc0.w, sh0.w);
            x[4] = fmaf(x[4], sc1.x, sh1.x); x[5] = fmaf(x[5], sc1.y, sh1.y);
            x[6] = fmaf(x[6], sc1.z, sh1.z); x[7] = fmaf(x[7], sc1.w, sh1.w);
            union { uint_t u[4]; bf16x8 v; } r;
            #pragma unroll
            for (int i = 0; i < 4; ++i)
                r.u[i] = (uint_t)f2bf(x[2 * i]) | ((uint_t)f2bf(x[2 * i + 1]) << 16);
            return r.v;
        } else {
            return __builtin_bit_cast(bf16x8, ui);
        }
    };

    // ---------------- phase 1: acc = A @ Wa ----------------
    uint4 uc;
    stageW(wta, 0, 0);
    uc = loadA(0);
    __syncthreads();
    #pragma unroll 2
    for (int t = 0; t < 6; ++t) {
        const int b = t & 1;
        if (t < 5) stageW(wta, t + 1, b ^ 1);
        uint4 un;
        if (t < 5) un = loadA(t + 1);
        const bf16x8 a = makeA(uc, t);
        #pragma unroll
        for (int nf = 0; nf < 12; ++nf) {
            const bf16x8 bb = *(const bf16x8*)&Ws[b][(nf * 16 + l15) * 32 + quad * 8];
            acc[nf] = __builtin_amdgcn_mfma_f32_16x16x32_bf16(a, bb, acc[nf], 0, 0, 0);
        }
        __syncthreads();
        if (t < 5) uc = un;
    }

    // ---- phase-1 epilogue: bias (+relu) -> Vs bf16 (wave-private); re-zero
    {
        float b1r[12];
        #pragma unroll
        for (int nf = 0; nf < 12; ++nf) b1r[nf] = bias1[nf * 16 + l15];
        #pragma unroll
        for (int reg = 0; reg < 4; ++reg) {
            ushort_t* vrow = &Vs[(w * 16 + quad * 4 + reg) * VST + l15];
            #pragma unroll
            for (int nf = 0; nf < 12; ++nf) {
                float x = acc[nf][reg] + b1r[nf];
                if (RELU1) x = lrelu(x);
                vrow[nf * 16] = f2bf(x);
                acc[nf][reg] = 0.f;
            }
        }
    }
    stageW(wtb, 0, 0);
    __syncthreads();

    // ---------------- phase 2: acc = V @ Wb ----------------
    #pragma unroll 2
    for (int t = 0; t < 6; ++t) {
        const int b = t & 1;
        if (t < 5) stageW(wtb, t + 1, b ^ 1);
        const bf16x8 a = *(const bf16x8*)&Vs[(w * 16 + l15) * VST + (t << 5) + quad * 8];
        #pragma unroll
        for (int nf = 0; nf < 12; ++nf) {
            const bf16x8 bb = *(const bf16x8*)&Ws[b][(nf * 16 + l15) * 32 + quad * 8];
            acc[nf] = __builtin_amdgcn_mfma_f32_16x16x32_bf16(a, bb, acc[nf], 0, 0, 0);
        }
        __syncthreads();
    }

    // ---------------- phase-2 epilogue ----------------
    int   col[12];
    float bia[12];
    #pragma unroll
    for (int nf = 0; nf < 12; ++nf) {
        col[nf] = nf * 16 + l15;
        bia[nf] = bias2[col[nf]];
    }
    float rsc[12], rsh[12];
    if constexpr (BN && RES) {
        #pragma unroll
        for (int nf = 0; nf < 12; ++nf) {
            rsc[nf] = scs[col[nf]];
            rsh[nf] = shs[col[nf]];
        }
    }
    float w3a[12], w3b[12];
    if constexpr (LOGITS) {
        #pragma unroll
        for (int nf = 0; nf < 12; ++nf) {
            w3a[nf] = Wm3[col[nf] * 2 + 0];
            w3b[nf] = Wm3[col[nf] * 2 + 1];
        }
    }
    float cs[12], cs2[12];
    if constexpr (BNSTAT) {
        #pragma unroll
        for (int nf = 0; nf < 12; ++nf) { cs[nf] = 0.f; cs2[nf] = 0.f; }
    }
    #pragma unroll
    for (int reg = 0; reg < 4; ++reg) {
        const int gr = row0 + w * 16 + quad * 4 + reg;
        const bool ok = gr < n;
        float v[12];
        #pragma unroll
        for (int nf = 0; nf < 12; ++nf) {
            float x = acc[nf][reg] + bia[nf];
            if constexpr (RES) {
                float r = ok ? bf2f(resin[(size_t)gr * DDIM + col[nf]]) : 0.f;
                if constexpr (BN) r = fmaf(r, rsc[nf], rsh[nf]);
                x += r;
            }
            v[nf] = x;
        }
        if constexpr (LNORM) {
            float s = 0.f, s2 = 0.f;
            #pragma unroll
            for (int nf = 0; nf < 12; ++nf) { s += v[nf]; s2 = fmaf(v[nf], v[nf], s2); }
            #pragma unroll
            for (int off = 1; off < 16; off <<= 1) {
                s  += __shfl_xor(s, off);
                s2 += __shfl_xor(s2, off);
            }
            const float mu = s * (1.0f / DDIM);
            const float var = s2 * (1.0f / DDIM) - mu * mu;
            const float rs = rsqrtf(var + EPS_LN);
            #pragma unroll
            for (int nf = 0; nf < 12; ++nf)
                v[nf] = fmaf((v[nf] - mu) * rs, lg[col[nf]], lb[col[nf]]);
        }
        float s0 = 0.f, s1 = 0.f;
        #pragma unroll
        for (int nf = 0; nf < 12; ++nf) {
            float x = v[nf];
            if (RELU2) x = lrelu(x);
            if constexpr (BNSTAT) {
                const float xa = ok ? x : 0.f;
                cs[nf] += xa;
                cs2[nf] = fmaf(xa, xa, cs2[nf]);
            }
            if constexpr (LOGITS) {
                s0 = fmaf(x, w3a[nf], s0);
                s1 = fmaf(x, w3b[nf], s1);
            }
            if (ok) {
                if constexpr (CBF) Cbf[(size_t)gr * DDIM + col[nf]] = f2bf(x);
            }
        }
        if constexpr (LOGITS) {
            #pragma unroll
            for (int off = 1; off < 16; off <<= 1) {
                s0 += __shfl_xor(s0, off);
                s1 += __shfl_xor(s1, off);
            }
            if (l15 == 0 && ok) {
                outp[(size_t)gr * 2 + 0] = s0 + bm3[0];
                outp[(size_t)gr * 2 + 1] = s1 + bm3[1];
            }
        }
        if constexpr (FNORM) {
            if (gr < TRAIN) {
                float q = 0.f;
                #pragma unroll
                for (int nf = 0; nf < 12; ++nf) q = fmaf(v[nf], v[nf], q);
                #pragma unroll
                for (int off = 1; off < 16; off <<= 1) q += __shfl_xor(q, off);
                const float inv = 1.0f / sqrtf(q);
                #pragma unroll
                for (int nf = 0; nf < 12; ++nf)
                    fnb[(size_t)gr * DDIM + col[nf]] = f2bf(v[nf] * inv);
            }
        }
    }
    if constexpr (BNSTAT) {
        float* bsA = (float*)&Ws[0][0];     // [8][192] sums   (aliases Ws)
        float* bsB = bsA + 8 * 192;         // [8][192] sumsq
        #pragma unroll
        for (int nf = 0; nf < 12; ++nf) {
            cs[nf]  += __shfl_xor(cs[nf], 16);  cs[nf]  += __shfl_xor(cs[nf], 32);
            cs2[nf] += __shfl_xor(cs2[nf], 16); cs2[nf] += __shfl_xor(cs2[nf], 32);
        }
        if (quad == 0) {
            #pragma unroll
            for (int nf = 0; nf < 12; ++nf) {
                bsA[w * 192 + col[nf]] = cs[nf];
                bsB[w * 192 + col[nf]] = cs2[nf];
            }
        }
        __syncthreads();
        if (tid < DDIM) {
            float s = 0.f, s2 = 0.f;
            #pragma unroll
            for (int k = 0; k < 8; ++k) {
                s  += bsA[k * 192 + tid];
                s2 += bsB[k * 192 + tid];
            }
            atomicAdd(&bnacc[tid], s);
            atomicAdd(&bnacc[DDIM + tid], s2);
        }
    }
}

// ---------------------------------------------------------------------------
// RGCN concat GEMM, 8-wave / reg-A / double-buffered-W version:
// Cbf = bf16([A1(bf16,K=192) | A2(bf16,K=384)] @ WT[192][576] + b).
// In-place safe for Cbf == A1 (per-block rows fully consumed before write).
// ---------------------------------------------------------------------------
__global__ __launch_bounds__(512, 4) void gemm_cat(
    const ushort_t* __restrict__ A1, const ushort_t* __restrict__ A2,
    const ushort_t* __restrict__ WT, const float* __restrict__ bias,
    ushort_t* __restrict__ Cbf, int n)
{
    __shared__ ushort_t Ws[2][192 * 32];    // 24 KB
    const int tid = threadIdx.x;
    const int lane = tid & 63, w = tid >> 6;
    const int quad = lane >> 4, l15 = lane & 15;
    const int row0 = blockIdx.x * 128;
    const int myrow = row0 + w * 16 + l15;
    const bool rok = myrow < n;

    f32x4 acc[12];
    #pragma unroll
    for (int nf = 0; nf < 12; ++nf) acc[nf] = (f32x4){0.f, 0.f, 0.f, 0.f};

    const ushort_t* a1p = A1 + (size_t)myrow * 192 + quad * 8;
    const ushort_t* a2p = A2 + (size_t)myrow * 384 + quad * 8;

    auto stageW = [&](int t, int b) {
        const int k0 = t << 5;
        for (int s = tid; s < 768; s += 512) {
            const int col = s >> 2, part = s & 3;
            *(uint4*)&Ws[b][col * 32 + part * 8] =
                *(const uint4*)(WT + (size_t)col * 576 + k0 + part * 8);
        }
    };
    auto loadA = [&](int t) -> uint4 {
        if (!rok) return make_uint4(0u, 0u, 0u, 0u);
        const ushort_t* p = (t < 6) ? (a1p + t * 32) : (a2p + (t - 6) * 32);
        return *(const uint4*)p;
    };

    uint4 uc;
    stageW(0, 0);
    uc = loadA(0);
    __syncthreads();

    #pragma unroll 2
    for (int t = 0; t < 18; ++t) {
        const int b = t & 1;
        if (t < 17) stageW(t + 1, b ^ 1);
        uint4 un;
        if (t < 17) un = loadA(t + 1);
        const bf16x8 a = __builtin_bit_cast(bf16x8, uc);
        #pragma unroll
        for (int nf = 0; nf < 12; ++nf) {
            const bf16x8 bb = *(const bf16x8*)&Ws[b][(nf * 16 + l15) * 32 + quad * 8];
            acc[nf] = __builtin_amdgcn_mfma_f32_16x16x32_bf16(a, bb, acc[nf], 0, 0, 0);
        }
        __syncthreads();
        if (t < 17) uc = un;
    }

    #pragma unroll
    for (int reg = 0; reg < 4; ++reg) {
        const int gr = row0 + w * 16 + quad * 4 + reg;
        if (gr >= n) continue;
        #pragma unroll
        for (int nf = 0; nf < 12; ++nf) {
            const int col = nf * 16 + l15;
            Cbf[(size_t)gr * DDIM + col] = f2bf(acc[nf][reg] + bias[col]);
        }
    }
}

// ---------------------------------------------------------------------------
__global__ __launch_bounds__(256) void embed_nc_k(
    const float* __restrict__ np_, const float* __restrict__ cp,
    const float* __restrict__ Wn, const float* __restrict__ bnum,
    const float* __restrict__ Wc, const float* __restrict__ bc,
    ushort_t* __restrict__ xb)
{
    const int idx = blockIdx.x * 256 + threadIdx.x;
    if (idx >= NN * 128) return;
    const int node = idx >> 7;
    const int c = idx & 127;
    float acc;
    if (c < 64) {
        acc = bnum[c];
        #pragma unroll
        for (int k = 0; k < 6; ++k) acc = fmaf(np_[node * 6 + k], Wn[k * 64 + c], acc);
    } else {
        const int cc = c - 64;
        acc = bc[cc];
        #pragma unroll
        for (int k = 0; k < 7; ++k) acc = fmaf(cp[node * 7 + k], Wc[k * 64 + cc], acc);
    }
    xb[(size_t)node * DDIM + 64 + c] = f2bf(lrelu(acc));
}

// ---------------------------------------------------------------------------
// Contrastive similarity, symmetric-triangular: block bid -> tile (ti,tj),
// tj <= ti.  Off-diagonal blocks credit BOTH the i-tile rows (row-side, over
// l15) and the j-tile rows (col-side, over quad) -- S = fn@fn^T is symmetric.
// ---------------------------------------------------------------------------
__global__ __launch_bounds__(256) void sim_mfma(const ushort_t* __restrict__ fnb,
    const int* __restrict__ lab, float* __restrict__ row_ex, float* __restrict__ row_mt)
{
    __shared__ ushort_t Ai[128 * 32];
    __shared__ ushort_t Bj[128 * 32];
    __shared__ int Li[128], Lj[128];
    const int bid = blockIdx.x;
    int ti = (int)((sqrtf(8.0f * (float)bid + 1.0f) - 1.0f) * 0.5f);
    while ((ti + 1) * (ti + 2) / 2 <= bid) ++ti;
    while (ti * (ti + 1) / 2 > bid) --ti;
    const int tj = bid - ti * (ti + 1) / 2;
    const int i0 = ti * 128, j0 = tj * 128;
    const bool offd = (ti != tj);

    const int tid = threadIdx.x, lane = tid & 63, w = tid >> 6;
    const int quad = lane >> 4, l15 = lane & 15;
    if (tid < 128) Li[tid] = lab[i0 + tid];
    else           Lj[tid - 128] = lab[j0 + tid - 128];
    const int iw = (w >> 1) * 64, jw = (w & 1) * 64;

    f32x4 acc[4][4];
    #pragma unroll
    for (int m = 0; m < 4; ++m)
        #pragma unroll
        for (int nf = 0; nf < 4; ++nf)
            acc[m][nf] = (f32x4){0.f, 0.f, 0.f, 0.f};

    for (int k0 = 0; k0 < DDIM; k0 += 32) {
        #pragma unroll
        for (int s = tid; s < 512; s += 256) {
            const int row = s >> 2, part = s & 3;
            *(uint4*)&Ai[row * 32 + part * 8] =
                *(const uint4*)(fnb + (size_t)(i0 + row) * DDIM + k0 + part * 8);
            *(uint4*)&Bj[row * 32 + part * 8] =
                *(const uint4*)(fnb + (size_t)(j0 + row) * DDIM + k0 + part * 8);
        }
        __syncthreads();
        bf16x8 a[4], b[4];
        #pragma unroll
        for (int m = 0; m < 4; ++m)
            a[m] = *(const bf16x8*)&Ai[(iw + m * 16 + l15) * 32 + quad * 8];
        #pragma unroll
        for (int nf = 0; nf < 4; ++nf)
            b[nf] = *(const bf16x8*)&Bj[(jw + nf * 16 + l15) * 32 + quad * 8];
        #pragma unroll
        for (int m = 0; m < 4; ++m)
            #pragma unroll
            for (int nf = 0; nf < 4; ++nf)
                acc[m][nf] = __builtin_amdgcn_mfma_f32_16x16x32_bf16(a[m], b[nf], acc[m][nf], 0, 0, 0);
        __syncthreads();
    }

    int lj[4];
    #pragma unroll
    for (int nf = 0; nf < 4; ++nf) lj[nf] = Lj[jw + nf * 16 + l15];
    float ce[4], cm[4];
    #pragma unroll
    for (int nf = 0; nf < 4; ++nf) { ce[nf] = 0.f; cm[nf] = 0.f; }

    #pragma unroll
    for (int m = 0; m < 4; ++m) {
        #pragma unroll
        for (int reg = 0; reg < 4; ++reg) {
            const int rl = iw + m * 16 + quad * 4 + reg;
            const int li = Li[rl];
            float se = 0.f, sm = 0.f;
            #pragma unroll
            for (int nf = 0; nf < 4; ++nf) {
                const float e = __expf(acc[m][nf][reg] * 2.0f);  // 1/TEMP = 2
                se += e;
                const bool mt = (li == lj[nf]);
                if (mt) sm += e;
                if (offd) {
                    ce[nf] += e;
                    if (mt) cm[nf] += e;
                }
            }
            #pragma unroll
            for (int off = 1; off < 16; off <<= 1) {
                se += __shfl_xor(se, off);
                sm += __shfl_xor(sm, off);
            }
            if (l15 == 0) {
                atomicAdd(&row_ex[i0 + rl], se);
                atomicAdd(&row_mt[i0 + rl], sm);
            }
        }
    }
    if (offd) {
        #pragma unroll
        for (int nf = 0; nf < 4; ++nf) {
            ce[nf] += __shfl_xor(ce[nf], 16); ce[nf] += __shfl_xor(ce[nf], 32);
            cm[nf] += __shfl_xor(cm[nf], 16); cm[nf] += __shfl_xor(cm[nf], 32);
        }
        if (quad == 0) {
            #pragma unroll
            for (int nf = 0; nf < 4; ++nf) {
                atomicAdd(&row_ex[j0 + jw + nf * 16 + l15], ce[nf]);
                atomicAdd(&row_mt[j0 + jw + nf * 16 + l15], cm[nf]);
            }
        }
    }
}

__global__ __launch_bounds__(256) void closs_k(const float* __restrict__ ex,
    const float* __restrict__ mt, float* __restrict__ out)
{
    float s = 0.f;
    for (int i = threadIdx.x; i < TRAIN; i += 256) s += -logf(mt[i] / ex[i]);
    s = wave_sum(s);
    __shared__ float red[4];
    const int wave = threadIdx.x >> 6, lane = threadIdx.x & 63;
    if (lane == 0) red[wave] = s;
    __syncthreads();
    if (threadIdx.x == 0) out[0] = (red[0] + red[1] + red[2] + red[3]) / (float)TRAIN;
}

// ---------------------------------------------------------------------------
// CSR build: counts -> 3-kernel parallel exclusive scan -> fill.
// ---------------------------------------------------------------------------
__global__ __launch_bounds__(256) void cnt_i_k(const int* __restrict__ dst,
    const int* __restrict__ ety, int* __restrict__ cnti)
{
    const int e = blockIdx.x * 256 + threadIdx.x;
    if (e >= EE) return;
    atomicAdd(&cnti[(size_t)ety[e] * NN + dst[e]], 1);
}

__global__ __launch_bounds__(256) void part_k(const int* __restrict__ cnti,
                                              int* __restrict__ part)
{
    __shared__ int sh[256];
    const int tid = threadIdx.x;
    const int i0 = blockIdx.x * 2048 + tid * 8;
    int s = 0;
    #pragma unroll
    for (int j = 0; j < 8; ++j) {
        const int i = i0 + j;
        s += (i < TOTSEG) ? cnti[i] : 0;
    }
    sh[tid] = s;
    __syncthreads();
    #pragma unroll
    for (int off = 128; off > 0; off >>= 1) {
        if (tid < off) sh[tid] += sh[tid + off];
        __syncthreads();
    }
    if (tid == 0) part[blockIdx.x] = sh[0];
}

__global__ __launch_bounds__(128) void scanp_k(int* __restrict__ part)
{
    __shared__ int sh[128];
    const int tid = threadIdx.x;
    const int v = (tid < SCAN_NB) ? part[tid] : 0;
    sh[tid] = v;
    __syncthreads();
    #pragma unroll
    for (int off = 1; off < 128; off <<= 1) {
        const int t = (tid >= off) ? sh[tid - off] : 0;
        __syncthreads();
        sh[tid] += t;
        __syncthreads();
    }
    if (tid < SCAN_NB) part[tid] = sh[tid] - v;   // exclusive
}

__global__ __launch_bounds__(256) void offs_k(const int* __restrict__ cnti,
    const int* __restrict__ part, int* __restrict__ offs)
{
    __shared__ int sh[256];
    const int tid = threadIdx.x;
    const int i0 = blockIdx.x * 2048 + tid * 8;
    int v[8];
    int loc = 0;
    #pragma unroll
    for (int j = 0; j < 8; ++j) {
        const int i = i0 + j;
        v[j] = (i < TOTSEG) ? cnti[i] : 0;
        loc += v[j];
    }
    sh[tid] = loc;
    __syncthreads();
    #pragma unroll
    for (int off = 1; off < 256; off <<= 1) {
        const int t = (tid >= off) ? sh[tid - off] : 0;
        __syncthreads();
        sh[tid] += t;
        __syncthreads();
    }
    int pre = part[blockIdx.x] + sh[tid] - loc;
    #pragma unroll
    for (int j = 0; j < 8; ++j) {
        const int i = i0 + j;
        if (i < TOTSEG) offs[i] = pre;
        pre += v[j];
    }
}

__global__ __launch_bounds__(256) void fill_k(const int* __restrict__ src,
    const int* __restrict__ dst, const int* __restrict__ ety,
    int* __restrict__ offs, int* __restrict__ elist)
{
    const int e = blockIdx.x * 256 + threadIdx.x;
    if (e >= EE) return;
    const int pos = atomicAdd(&offs[(size_t)ety[e] * NN + dst[e]], 1);
    elist[pos] = src[e];
}

// ---------------------------------------------------------------------------
// Gather (bf16 in, bf16 out), uint-vectorized: row of 192 bf16 = 96 uints;
// lane handles uints {lane, lane+64 (lane<32)} = cols {2l,2l+1, 128+2l,129+2l}.
// ---------------------------------------------------------------------------
__global__ __launch_bounds__(256) void gather_bf_k(const ushort_t* __restrict__ xb,
    const int* __restrict__ elist, const int* __restrict__ offs,
    const int* __restrict__ cnti, ushort_t* __restrict__ aggb)
{
    const int wave = threadIdx.x >> 6, lane = threadIdx.x & 63;
    const int d = blockIdx.x * 4 + wave;
    if (d >= NN) return;
    const bool lo = lane < 32;
    #pragma unroll
    for (int r = 0; r < 2; ++r) {
        const int seg = r * NN + d;
        const int end = offs[seg];
        const int c = cnti[seg];
        float a0 = 0.f, a1 = 0.f, b0 = 0.f, b1 = 0.f;
        int e = end - c;
        for (; e + 1 < end; e += 2) {
            const int s0 = elist[e], s1 = elist[e + 1];
            const uint_t* r0 = (const uint_t*)(xb + (size_t)s0 * DDIM);
            const uint_t* r1 = (const uint_t*)(xb + (size_t)s1 * DDIM);
            const uint_t x0 = r0[lane], x1 = r1[lane];
            uint_t y0 = 0u, y1 = 0u;
            if (lo) { y0 = r0[64 + lane]; y1 = r1[64 + lane]; }
            a0 += bf2f((ushort_t)(x0 & 0xffffu)) + bf2f((ushort_t)(x1 & 0xffffu));
            a1 += bf2f((ushort_t)(x0 >> 16))     + bf2f((ushort_t)(x1 >> 16));
            b0 += bf2f((ushort_t)(y0 & 0xffffu)) + bf2f((ushort_t)(y1 & 0xffffu));
            b1 += bf2f((ushort_t)(y0 >> 16))     + bf2f((ushort_t)(y1 >> 16));
        }
        if (e < end) {
            const int s0 = elist[e];
            const uint_t* r0 = (const uint_t*)(xb + (size_t)s0 * DDIM);
            const uint_t x0 = r0[lane];
            uint_t y0 = 0u;
            if (lo) y0 = r0[64 + lane];
            a0 += bf2f((ushort_t)(x0 & 0xffffu));
            a1 += bf2f((ushort_t)(x0 >> 16));
            b0 += bf2f((ushort_t)(y0 & 0xffffu));
            b1 += bf2f((ushort_t)(y0 >> 16));
        }
        const float inv = 1.0f / (float)max(c, 1);
        uint_t* ar = (uint_t*)(aggb + (size_t)d * 384 + r * DDIM);
        ar[lane] = (uint_t)f2bf(a0 * inv) | ((uint_t)f2bf(a1 * inv) << 16);
        if (lo)
            ar[64 + lane] = (uint_t)f2bf(b0 * inv) | ((uint_t)f2bf(b1 * inv) << 16);
    }
}

// ---------------------------------------------------------------------------
extern "C" void kernel_launch(void* const* d_in, const int* in_sizes, int n_in,
                              void* d_out, int out_size, void* d_ws, size_t ws_size,
                              hipStream_t stream)
{
    const float* tweet   = (const float*)d_in[0];
    const float* np_     = (const float*)d_in[1];
    const float* cp      = (const float*)d_in[2];
    const float* Wt      = (const float*)d_in[3];
    const float* bt      = (const float*)d_in[4];
    const float* Wn      = (const float*)d_in[5];
    const float* bnum    = (const float*)d_in[6];
    const float* Wc      = (const float*)d_in[7];
    const float* bc      = (const float*)d_in[8];
    const float* Wv      = (const float*)d_in[9];
    const float* bv      = (const float*)d_in[10];
    const float* Wo      = (const float*)d_in[11];
    const float* bo      = (const float*)d_in[12];
    const float* ln1g    = (const float*)d_in[13];
    const float* ln1b    = (const float*)d_in[14];
    const float* bng     = (const float*)d_in[15];
    const float* bnb     = (const float*)d_in[16];
    const float* W1      = (const float*)d_in[17];
    const float* b1      = (const float*)d_in[18];
    const float* W2      = (const float*)d_in[19];
    const float* b2      = (const float*)d_in[20];
    const float* ln2g    = (const float*)d_in[21];
    const float* ln2b    = (const float*)d_in[22];
    const float* Wrel    = (const float*)d_in[23];
    const float* Wroot   = (const float*)d_in[24];
    const float* rgcnb   = (const float*)d_in[25];
    const float* Wm1     = (const float*)d_in[26];
    const float* bm1     = (const float*)d_in[27];
    const float* Wm2     = (const float*)d_in[28];
    const float* bm2     = (const float*)d_in[29];
    const float* Wm3     = (const float*)d_in[30];
    const float* bm3     = (const float*)d_in[31];
    const int*   eidx    = (const int*)d_in[32];
    const int*   esrc    = eidx;
    const int*   edst    = eidx + EE;
    const int*   ety     = (const int*)d_in[33];
    const int*   labels  = (const int*)d_in[34];
    float* out = (float*)d_out;

    const size_t ND = (size_t)NN * DDIM;
    ushort_t* XBF  = (ushort_t*)d_ws;             // ND  (x / h, bf16)
    ushort_t* X1BF = XBF + ND;                    // ND  (ln1-out, bf16)
    ushort_t* AGGB = X1BF + ND;                   // 2*ND (RGCN gather out)
    ushort_t* FNb  = AGGB + 2 * ND;               // TRAIN*DDIM
    ushort_t* WTt  = FNb + (size_t)TRAIN * DDIM;  // 64x768
    ushort_t* WTs  = WTt + 49152;                 // 29 x 36864 (24/25/26 unused)
    ushort_t* WTg  = WTs + (size_t)29 * 36864;    // 192 x 576
    float* ROWEX = (float*)(WTg + 110592);
    float* ROWMT = ROWEX + TRAIN;
    float* BNS   = ROWMT + TRAIN;                 // 6 layers x [sum|sumsq]
    int*   CNTI  = (int*)(BNS + 12 * DDIM);       // 2*NN
    int*   OFFS  = CNTI + 2 * NN;                 // 2*NN (becomes end-offsets)
    int*   ELIST = OFFS + 2 * NN;                 // EE
    int*   PART  = ELIST + EE;                    // 128
    ushort_t* WTv  = WTs;
    ushort_t* WTo  = WTs + (size_t)6  * 36864;
    ushort_t* WT1  = WTs + (size_t)12 * 36864;
    ushort_t* WT2  = WTs + (size_t)18 * 36864;
    ushort_t* WTm1 = WTs + (size_t)27 * 36864;
    ushort_t* WTm2 = WTs + (size_t)28 * 36864;

    const int gx = (NN + 127) / 128;   // 782
    const dim3 blk(256);
    const dim3 blk5(512);

    prep_w<<<29 * 144 + 192, blk, 0, stream>>>(Wt, Wv, Wo, W1, W2, Wrel, Wroot, Wm1, Wm2, WTt, WTs, WTg);

    // ---- CSR build (edge structure only; reused by both RGCN layers)
    hipMemsetAsync(CNTI, 0, 2 * NN * sizeof(int), stream);
    cnt_i_k<<<(EE + 255) / 256, blk, 0, stream>>>(edst, ety, CNTI);
    part_k<<<SCAN_NB, blk, 0, stream>>>(CNTI, PART);
    scanp_k<<<1, 128, 0, stream>>>(PART);
    offs_k<<<SCAN_NB, blk, 0, stream>>>(CNTI, PART, OFFS);
    fill_k<<<(EE + 255) / 256, blk, 0, stream>>>(esrc, edst, ety, OFFS, ELIST);

    // ---- input embedding (bf16 x)
    gemm_tweet<<<gx, blk5, 0, stream>>>(tweet, WTt, bt, XBF, NN);
    embed_nc_k<<<(NN * 128 + 255) / 256, blk, 0, stream>>>(np_, cp, Wn, bnum, Wc, bc, XBF);

    // ---- 6 layers, each = 2 fused double-GEMMs (BN finalize folded in)
    hipMemsetAsync(BNS, 0, 12 * DDIM * sizeof(float), stream);
    for (int i = 0; i < NLAYER; ++i) {
        const size_t wo = (size_t)i * 36864;
        float* bnacc_i = BNS + (size_t)i * 2 * DDIM;
        // X1BF = bf16( ln1(x + (x@Wv+bv)@Wo + bo) ), BN-stat accumulate
        gemm2_mfma<false, false, true, true, false, true, true, false, false>
            <<<gx, blk5, 0, stream>>>(
            XBF, WTv + wo, bv + i * DDIM, WTo + wo, bo + i * DDIM, XBF,
            X1BF, nullptr, nullptr, nullptr, bnacc_i,
            ln1g + i * DDIM, ln1b + i * DDIM, nullptr, nullptr, nullptr, nullptr, NN);
        // XBF = bf16( ln2(bn(x1) + lrelu(bn(x1)@W1+b1)@W2 + b2) ); last: +fnorm
        if (i < NLAYER - 1)
            gemm2_mfma<true, false, true, true, true, false, true, false, false>
                <<<gx, blk5, 0, stream>>>(
                X1BF, WT1 + wo, b1 + i * DDIM, WT2 + wo, b2 + i * DDIM, X1BF,
                XBF, bnacc_i, bng + i * DDIM, bnb + i * DDIM, nullptr,
                ln2g + i * DDIM, ln2b + i * DDIM, nullptr, nullptr, nullptr, nullptr, NN);
        else
            gemm2_mfma<true, false, true, true, true, false, true, false, true>
                <<<gx, blk5, 0, stream>>>(
                X1BF, WT1 + wo, b1 + i * DDIM, WT2 + wo, b2 + i * DDIM, X1BF,
                XBF, bnacc_i, bng + i * DDIM, bnb + i * DDIM, nullptr,
                ln2g + i * DDIM, ln2b + i * DDIM, nullptr, nullptr, nullptr, FNb, NN);
    }

    // ---- contrastive loss (fnorm fused above; symmetric-triangular sim)
    hipMemsetAsync(ROWEX, 0, 2 * TRAIN * sizeof(float), stream);
    sim_mfma<<<(TRAIN / 128) * (TRAIN / 128 + 1) / 2, blk, 0, stream>>>(FNb, labels, ROWEX, ROWMT);
    closs_k<<<1, blk, 0, stream>>>(ROWEX, ROWMT, out + 2 * (size_t)NN);

    // ---- RGCN pass 1: h1 = bf16([x | agg(x)] @ [Wroot;Wcat] + b), in place
    gather_bf_k<<<(NN + 3) / 4, blk, 0, stream>>>(XBF, ELIST, OFFS, CNTI, AGGB);
    gemm_cat<<<gx, blk5, 0, stream>>>(XBF, AGGB, WTg, rgcnb, XBF, NN);

    // ---- RGCN pass 2
    gather_bf_k<<<(NN + 3) / 4, blk, 0, stream>>>(XBF, ELIST, OFFS, CNTI, AGGB);
    gemm_cat<<<gx, blk5, 0, stream>>>(XBF, AGGB, WTg, rgcnb, XBF, NN);

    // ---- MLP head fused with logits (bf16 in, direct logits out)
    gemm2_mfma<true, true, false, false, false, false, false, true, false>
        <<<gx, blk5, 0, stream>>>(
        XBF, WTm1, bm1, WTm2, bm2, nullptr, nullptr,
        nullptr, nullptr, nullptr, nullptr, nullptr, nullptr,
        Wm3, bm3, out, nullptr, NN);
}

// Round 5
// 1816.672 us; speedup vs baseline: 1.6855x; 1.0194x over previous
//
#include <hip/hip_runtime.h>

#define NN 100000
#define EE 1000000
#define DDIM 192
#define NLAYER 6
#define TRAIN 8192
#define SLOPE 0.01f
#define EPS_LN 1e-5f
#define TOTSEG (2 * NN)
#define SCAN_NB 98           /* ceil(200000 / 2048) */

typedef float f32x4 __attribute__((ext_vector_type(4)));
typedef __bf16 bf16x8 __attribute__((ext_vector_type(8)));
typedef unsigned short ushort_t;
typedef unsigned int uint_t;

__device__ __forceinline__ float lrelu(float v) { return v > 0.0f ? v : SLOPE * v; }

__device__ __forceinline__ ushort_t f2bf(float f) {
    __bf16 h = (__bf16)f;              // HW RNE convert
    return __builtin_bit_cast(ushort_t, h);
}

__device__ __forceinline__ float bf2f(ushort_t b) {
    union { uint_t u; float f; } v; v.u = ((uint_t)b) << 16; return v.f;
}

__device__ __forceinline__ float wave_sum(float s) {
    #pragma unroll
    for (int off = 32; off > 0; off >>= 1) s += __shfl_down(s, off);
    return __shfl(s, 0);
}

// ---------------------------------------------------------------------------
// One-shot weight prep: transpose + convert to bf16.  WT[m][k] = W[k][m].
// Wroot+Wrel go into the concat matrix WTg[m][576] = [Wroot^T | W0^T | W1^T].
// ---------------------------------------------------------------------------
__global__ __launch_bounds__(256) void prep_w(
    const float* __restrict__ Wt, const float* __restrict__ Wv,
    const float* __restrict__ Wo, const float* __restrict__ W1,
    const float* __restrict__ W2, const float* __restrict__ Wrel,
    const float* __restrict__ Wroot, const float* __restrict__ Wm1,
    const float* __restrict__ Wm2, ushort_t* __restrict__ WTt,
    ushort_t* __restrict__ WTs, ushort_t* __restrict__ WTg)
{
    const int bid = blockIdx.x;
    if (bid < 29 * 144) {
        const int mat = bid / 144;
        const int o = (bid % 144) * 256 + threadIdx.x;   // < 36864
        const float* src;
        if      (mat <  6) src = Wv   + (size_t)mat * 36864;
        else if (mat < 12) src = Wo   + (size_t)(mat - 6)  * 36864;
        else if (mat < 18) src = W1   + (size_t)(mat - 12) * 36864;
        else if (mat < 24) src = W2   + (size_t)(mat - 18) * 36864;
        else if (mat < 26) src = Wrel + (size_t)(mat - 24) * 36864;
        else if (mat == 26) src = Wroot;
        else if (mat == 27) src = Wm1;
        else                src = Wm2;
        const int m = o / 192, k = o - m * 192;
        const ushort_t b = f2bf(src[(size_t)k * 192 + m]);
        if (mat == 24 || mat == 25)
            WTg[(size_t)m * 576 + 192 + (mat - 24) * 192 + k] = b;
        else if (mat == 26)
            WTg[(size_t)m * 576 + k] = b;
        else
            WTs[(size_t)mat * 36864 + o] = b;
    } else {
        const int o = (bid - 29 * 144) * 256 + threadIdx.x;  // < 49152
        const int m = o / 768, k = o - m * 768;
        WTt[o] = f2bf(Wt[(size_t)k * 64 + m]);
    }
}

// ---------------------------------------------------------------------------
// Tweet embedding GEMM + fused num/comments projections, 8-wave / reg-A /
// dbuf-W.  Produces the FULL bf16 x row: cols 0..63 from the MFMA GEMM,
// cols 64..191 from the tiny dense projections (same fmaf order as before).
// Output staged in LDS and stored as coalesced uint4.
// ---------------------------------------------------------------------------
__global__ __launch_bounds__(512) void gemm_tweet(
    const float* __restrict__ A, const ushort_t* __restrict__ WT,
    const float* __restrict__ bias,
    const float* __restrict__ np_, const float* __restrict__ cp,
    const float* __restrict__ Wn, const float* __restrict__ bnum,
    const float* __restrict__ Wc, const float* __restrict__ bc,
    ushort_t* __restrict__ Cbf, int n)
{
    constexpr int VST = 200;
    __shared__ ushort_t Ws[2][64 * 32];     // 2 x 4 KB
    __shared__ ushort_t Cs[128 * VST];      // 51200 B output staging
    const int tid = threadIdx.x;
    const int lane = tid & 63, w = tid >> 6;
    const int quad = lane >> 4, l15 = lane & 15;
    const int row0 = blockIdx.x * 128;
    const int myrow = row0 + w * 16 + l15;
    const bool rok = myrow < n;

    f32x4 acc[4];
    #pragma unroll
    for (int nf = 0; nf < 4; ++nf) acc[nf] = (f32x4){0.f, 0.f, 0.f, 0.f};

    const float* aF = A + (size_t)myrow * 768 + quad * 8;

    auto stageW = [&](int t, int b) {
        if (tid < 256) {
            const int col = tid >> 2, part = tid & 3;
            *(uint4*)&Ws[b][col * 32 + part * 8] =
                *(const uint4*)(WT + (size_t)col * 768 + (t << 5) + part * 8);
        }
    };
    auto loadA = [&](int t, float* fo) {
        if (rok) {
            const float4 p0 = *(const float4*)(aF + t * 32);
            const float4 p1 = *(const float4*)(aF + t * 32 + 4);
            fo[0] = p0.x; fo[1] = p0.y; fo[2] = p0.z; fo[3] = p0.w;
            fo[4] = p1.x; fo[5] = p1.y; fo[6] = p1.z; fo[7] = p1.w;
        } else {
            #pragma unroll
            for (int i = 0; i < 8; ++i) fo[i] = 0.f;
        }
    };

    float fc[8];
    stageW(0, 0);
    loadA(0, fc);
    __syncthreads();
    #pragma unroll 2
    for (int t = 0; t < 24; ++t) {
        const int b = t & 1;
        if (t < 23) stageW(t + 1, b ^ 1);
        float fn[8];
        if (t < 23) loadA(t + 1, fn);
        union { uint_t u[4]; bf16x8 v; } r;
        #pragma unroll
        for (int i = 0; i < 4; ++i)
            r.u[i] = (uint_t)f2bf(fc[2 * i]) | ((uint_t)f2bf(fc[2 * i + 1]) << 16);
        #pragma unroll
        for (int nf = 0; nf < 4; ++nf) {
            const bf16x8 bb = *(const bf16x8*)&Ws[b][(nf * 16 + l15) * 32 + quad * 8];
            acc[nf] = __builtin_amdgcn_mfma_f32_16x16x32_bf16(r.v, bb, acc[nf], 0, 0, 0);
        }
        __syncthreads();
        if (t < 23) {
            #pragma unroll
            for (int i = 0; i < 8; ++i) fc[i] = fn[i];
        }
    }

    // epilogue: cols 0..63 from MFMA, cols 64..191 from fused projections.
    #pragma unroll
    for (int reg = 0; reg < 4; ++reg) {
        const int lrow = w * 16 + quad * 4 + reg;
        const int gr = row0 + lrow;
        #pragma unroll
        for (int nf = 0; nf < 4; ++nf) {
            const int col = nf * 16 + l15;
            Cs[lrow * VST + col] = f2bf(lrelu(acc[nf][reg] + bias[col]));
        }
        if (gr < n) {
            const float* nrow = np_ + (size_t)gr * 6;
            const float* crow = cp + (size_t)gr * 7;
            for (int cj = 64 + l15; cj < 192; cj += 16) {
                float a;
                if (cj < 128) {
                    const int c = cj - 64;
                    a = bnum[c];
                    #pragma unroll
                    for (int k = 0; k < 6; ++k) a = fmaf(nrow[k], Wn[k * 64 + c], a);
                } else {
                    const int cc = cj - 128;
                    a = bc[cc];
                    #pragma unroll
                    for (int k = 0; k < 7; ++k) a = fmaf(crow[k], Wc[k * 64 + cc], a);
                }
                Cs[lrow * VST + cj] = f2bf(lrelu(a));
            }
        }
    }
    // coalesced store (wave-private rows -> no barrier needed)
    if (rok) {
        const uint4* vp = (const uint4*)&Cs[(size_t)(w * 16 + l15) * VST];
        uint4* gp = (uint4*)(Cbf + (size_t)myrow * DDIM);
        #pragma unroll
        for (int j = 0; j < 6; ++j) gp[quad * 6 + j] = vp[quad * 6 + j];
    }
}

// ---------------------------------------------------------------------------
// Fused double GEMM, 8-wave / reg-A / dbuf-W.  All activations bf16.
// Cbf = epi2( epi1(A@Wa + ba) @ Wb + bb [+ res] ).  BM=128, K=M=192.
// Epilogue res read and C store go through the (free) Vs LDS buffer:
// coalesced uint4 global <-> LDS, scalar LDS for the scattered pattern.
// Wave-private rows -> no extra barriers.
// ---------------------------------------------------------------------------
template <bool RELU1, bool RELU2, bool RES, bool LNORM, bool BN,
          bool BNSTAT, bool CBF, bool LOGITS, bool FNORM>
__global__ __launch_bounds__(512, 4) void gemm2_mfma(
    const ushort_t* __restrict__ Ain, const ushort_t* __restrict__ wta,
    const float* __restrict__ bias1, const ushort_t* __restrict__ wtb,
    const float* __restrict__ bias2, const ushort_t* __restrict__ resin,
    ushort_t* __restrict__ Cbf,
    const float* __restrict__ bnsum, const float* __restrict__ bng,
    const float* __restrict__ bnb, float* __restrict__ bnacc,
    const float* __restrict__ lg, const float* __restrict__ lb,
    const float* __restrict__ Wm3, const float* __restrict__ bm3,
    float* __restrict__ outp, ushort_t* __restrict__ fnb, int n)
{
    constexpr int VST = 200;
    __shared__ ushort_t Vs[128 * VST];      // 51200 B (wave-private 16-row slabs)
    __shared__ ushort_t Ws[2][192 * 32];    // 2 x 12288 B double buffer
    __shared__ float scs[DDIM], shs[DDIM];
    const int tid = threadIdx.x;
    const int lane = tid & 63, w = tid >> 6;      // 8 waves
    const int quad = lane >> 4, l15 = lane & 15;
    const int row0 = blockIdx.x * 128;
    const int myrow = row0 + w * 16 + l15;        // A-fragment / staging row
    const bool rok = myrow < n;

    if constexpr (BN) {
        const float invN = 1.0f / (float)NN;
        for (int j = tid; j < DDIM; j += 512) {
            const float mu = bnsum[j] * invN;
            const float var = bnsum[DDIM + j] * invN - mu * mu;
            const float sc = bng[j] * rsqrtf(var + EPS_LN);
            scs[j] = sc;
            shs[j] = fmaf(-mu, sc, bnb[j]);
        }
    }

    f32x4 acc[12];
    #pragma unroll
    for (int nf = 0; nf < 12; ++nf) acc[nf] = (f32x4){0.f, 0.f, 0.f, 0.f};

    const ushort_t* aB = Ain + (size_t)myrow * DDIM + quad * 8;

    auto stageW = [&](const ushort_t* wt, int t, int b) {
        const int k0 = t << 5;
        for (int s = tid; s < 768; s += 512) {
            const int col = s >> 2, part = s & 3;
            *(uint4*)&Ws[b][col * 32 + part * 8] =
                *(const uint4*)(wt + (size_t)col * DDIM + k0 + part * 8);
        }
    };
    auto loadA = [&](int t) -> uint4 {
        return rok ? *(const uint4*)(aB + t * 32) : make_uint4(0u, 0u, 0u, 0u);
    };
    auto makeA = [&](const uint4& ui, int t) -> bf16x8 {
        if constexpr (BN) {
            const int c0 = (t << 5) + quad * 8;
            const float4 sc0 = *(const float4*)&scs[c0];
            const float4 sc1 = *(const float4*)&scs[c0 + 4];
            const float4 sh0 = *(const float4*)&shs[c0];
            const float4 sh1 = *(const float4*)&shs[c0 + 4];
            const uint_t* uw = (const uint_t*)&ui;
            float x[8];
            #pragma unroll
            for (int i = 0; i < 4; ++i) {
                x[2 * i]     = bf2f((ushort_t)(uw[i] & 0xffffu));
                x[2 * i + 1] = bf2f((ushort_t)(uw[i] >> 16));
            }
            x[0] = fmaf(x[0], sc0.x, sh0.x); x[1] = fmaf(x[1], sc0.y, sh0.y);
            x[2] = fmaf(x[2], sc0.z, sh0.z); x[3] = fmaf(x[3], sc0.w, sh0.w);
            x[4] = fmaf(x[4], sc1.x, sh1.x); x[5] = fmaf(x[5], sc1.y, sh1.y);
            x[6] = fmaf(x[6], sc1.z, sh1.z); x[7] = fmaf(x[7], sc1.w, sh1.w);
            union { uint_t u[4]; bf16x8 v; } r;
            #pragma unroll
            for (int i = 0; i < 4; ++i)
                r.u[i] = (uint_t)f2bf(x[2 * i]) | ((uint_t)f2bf(x[2 * i + 1]) << 16);
            return r.v;
        } else {
            return __builtin_bit_cast(bf16x8, ui);
        }
    };

    // ---------------- phase 1: acc = A @ Wa ----------------
    uint4 uc;
    stageW(wta, 0, 0);
    uc = loadA(0);
    __syncthreads();
    #pragma unroll 2
    for (int t = 0; t < 6; ++t) {
        const int b = t & 1;
        if (t < 5) stageW(wta, t + 1, b ^ 1);
        uint4 un;
        if (t < 5) un = loadA(t + 1);
        const bf16x8 a = makeA(uc, t);
        #pragma unroll
        for (int nf = 0; nf < 12; ++nf) {
            const bf16x8 bb = *(const bf16x8*)&Ws[b][(nf * 16 + l15) * 32 + quad * 8];
            acc[nf] = __builtin_amdgcn_mfma_f32_16x16x32_bf16(a, bb, acc[nf], 0, 0, 0);
        }
        __syncthreads();
        if (t < 5) uc = un;
    }

    // ---- phase-1 epilogue: bias (+relu) -> Vs bf16 (wave-private); re-zero
    {
        float b1r[12];
        #pragma unroll
        for (int nf = 0; nf < 12; ++nf) b1r[nf] = bias1[nf * 16 + l15];
        #pragma unroll
        for (int reg = 0; reg < 4; ++reg) {
            ushort_t* vrow = &Vs[(w * 16 + quad * 4 + reg) * VST + l15];
            #pragma unroll
            for (int nf = 0; nf < 12; ++nf) {
                float x = acc[nf][reg] + b1r[nf];
                if (RELU1) x = lrelu(x);
                vrow[nf * 16] = f2bf(x);
                acc[nf][reg] = 0.f;
            }
        }
    }
    stageW(wtb, 0, 0);
    __syncthreads();

    // ---------------- phase 2: acc = V @ Wb ----------------
    #pragma unroll 2
    for (int t = 0; t < 6; ++t) {
        const int b = t & 1;
        if (t < 5) stageW(wtb, t + 1, b ^ 1);
        const bf16x8 a = *(const bf16x8*)&Vs[(w * 16 + l15) * VST + (t << 5) + quad * 8];
        #pragma unroll
        for (int nf = 0; nf < 12; ++nf) {
            const bf16x8 bb = *(const bf16x8*)&Ws[b][(nf * 16 + l15) * 32 + quad * 8];
            acc[nf] = __builtin_amdgcn_mfma_f32_16x16x32_bf16(a, bb, acc[nf], 0, 0, 0);
        }
        __syncthreads();
    }

    // ---- stage res rows into Vs (coalesced); wave-private, no barrier ----
    if constexpr (RES) {
        if (rok) {
            const uint4* rp = (const uint4*)(resin + (size_t)myrow * DDIM);
            uint4* vp = (uint4*)&Vs[(size_t)(w * 16 + l15) * VST];
            #pragma unroll
            for (int j = 0; j < 6; ++j) vp[quad * 6 + j] = rp[quad * 6 + j];
        }
    }

    // ---------------- phase-2 epilogue ----------------
    int   col[12];
    float bia[12];
    #pragma unroll
    for (int nf = 0; nf < 12; ++nf) {
        col[nf] = nf * 16 + l15;
        bia[nf] = bias2[col[nf]];
    }
    float rsc[12], rsh[12];
    if constexpr (BN && RES) {
        #pragma unroll
        for (int nf = 0; nf < 12; ++nf) {
            rsc[nf] = scs[col[nf]];
            rsh[nf] = shs[col[nf]];
        }
    }
    float w3a[12], w3b[12];
    if constexpr (LOGITS) {
        #pragma unroll
        for (int nf = 0; nf < 12; ++nf) {
            w3a[nf] = Wm3[col[nf] * 2 + 0];
            w3b[nf] = Wm3[col[nf] * 2 + 1];
        }
    }
    float cs[12], cs2[12];
    if constexpr (BNSTAT) {
        #pragma unroll
        for (int nf = 0; nf < 12; ++nf) { cs[nf] = 0.f; cs2[nf] = 0.f; }
    }
    #pragma unroll
    for (int reg = 0; reg < 4; ++reg) {
        const int lrow = w * 16 + quad * 4 + reg;
        const int gr = row0 + lrow;
        const bool ok = gr < n;
        float v[12];
        #pragma unroll
        for (int nf = 0; nf < 12; ++nf) {
            float x = acc[nf][reg] + bia[nf];
            if constexpr (RES) {
                float r = ok ? bf2f(Vs[lrow * VST + col[nf]]) : 0.f;
                if constexpr (BN) r = fmaf(r, rsc[nf], rsh[nf]);
                x += r;
            }
            v[nf] = x;
        }
        if constexpr (LNORM) {
            float s = 0.f, s2 = 0.f;
            #pragma unroll
            for (int nf = 0; nf < 12; ++nf) { s += v[nf]; s2 = fmaf(v[nf], v[nf], s2); }
            #pragma unroll
            for (int off = 1; off < 16; off <<= 1) {
                s  += __shfl_xor(s, off);
                s2 += __shfl_xor(s2, off);
            }
            const float mu = s * (1.0f / DDIM);
            const float var = s2 * (1.0f / DDIM) - mu * mu;
            const float rs = rsqrtf(var + EPS_LN);
            #pragma unroll
            for (int nf = 0; nf < 12; ++nf)
                v[nf] = fmaf((v[nf] - mu) * rs, lg[col[nf]], lb[col[nf]]);
        }
        float s0 = 0.f, s1 = 0.f;
        #pragma unroll
        for (int nf = 0; nf < 12; ++nf) {
            float x = v[nf];
            if (RELU2) x = lrelu(x);
            if constexpr (BNSTAT) {
                const float xa = ok ? x : 0.f;
                cs[nf] += xa;
                cs2[nf] = fmaf(xa, xa, cs2[nf]);
            }
            if constexpr (LOGITS) {
                s0 = fmaf(x, w3a[nf], s0);
                s1 = fmaf(x, w3b[nf], s1);
            }
            if constexpr (CBF) Vs[lrow * VST + col[nf]] = f2bf(x);
        }
        if constexpr (LOGITS) {
            #pragma unroll
            for (int off = 1; off < 16; off <<= 1) {
                s0 += __shfl_xor(s0, off);
                s1 += __shfl_xor(s1, off);
            }
            if (l15 == 0 && ok) {
                outp[(size_t)gr * 2 + 0] = s0 + bm3[0];
                outp[(size_t)gr * 2 + 1] = s1 + bm3[1];
            }
        }
        if constexpr (FNORM) {
            if (gr < TRAIN) {
                float q = 0.f;
                #pragma unroll
                for (int nf = 0; nf < 12; ++nf) q = fmaf(v[nf], v[nf], q);
                #pragma unroll
                for (int off = 1; off < 16; off <<= 1) q += __shfl_xor(q, off);
                const float inv = 1.0f / sqrtf(q);
                #pragma unroll
                for (int nf = 0; nf < 12; ++nf)
                    fnb[(size_t)gr * DDIM + col[nf]] = f2bf(v[nf] * inv);
            }
        }
    }
    // ---- coalesced C store from Vs (wave-private rows) ----
    if constexpr (CBF) {
        if (rok) {
            const uint4* vp = (const uint4*)&Vs[(size_t)(w * 16 + l15) * VST];
            uint4* gp = (uint4*)(Cbf + (size_t)myrow * DDIM);
            #pragma unroll
            for (int j = 0; j < 6; ++j) gp[quad * 6 + j] = vp[quad * 6 + j];
        }
    }
    if constexpr (BNSTAT) {
        float* bsA = (float*)&Ws[0][0];     // [8][192] sums   (aliases Ws)
        float* bsB = bsA + 8 * 192;         // [8][192] sumsq
        #pragma unroll
        for (int nf = 0; nf < 12; ++nf) {
            cs[nf]  += __shfl_xor(cs[nf], 16);  cs[nf]  += __shfl_xor(cs[nf], 32);
            cs2[nf] += __shfl_xor(cs2[nf], 16); cs2[nf] += __shfl_xor(cs2[nf], 32);
        }
        if (quad == 0) {
            #pragma unroll
            for (int nf = 0; nf < 12; ++nf) {
                bsA[w * 192 + col[nf]] = cs[nf];
                bsB[w * 192 + col[nf]] = cs2[nf];
            }
        }
        __syncthreads();
        if (tid < DDIM) {
            float s = 0.f, s2 = 0.f;
            #pragma unroll
            for (int k = 0; k < 8; ++k) {
                s  += bsA[k * 192 + tid];
                s2 += bsB[k * 192 + tid];
            }
            atomicAdd(&bnacc[tid], s);
            atomicAdd(&bnacc[DDIM + tid], s2);
        }
    }
}

// ---------------------------------------------------------------------------
// RGCN concat GEMM, 8-wave / reg-A / dbuf-W, LDS-staged coalesced store:
// Cbf = bf16([A1(bf16,K=192) | A2(bf16,K=384)] @ WT[192][576] + b).
// In-place safe for Cbf == A1 (per-block rows fully consumed before write).
// ---------------------------------------------------------------------------
__global__ __launch_bounds__(512, 4) void gemm_cat(
    const ushort_t* __restrict__ A1, const ushort_t* __restrict__ A2,
    const ushort_t* __restrict__ WT, const float* __restrict__ bias,
    ushort_t* __restrict__ Cbf, int n)
{
    constexpr int VST = 200;
    __shared__ ushort_t Ws[2][192 * 32];    // 24 KB
    __shared__ ushort_t Cs[128 * VST];      // 51200 B output staging
    const int tid = threadIdx.x;
    const int lane = tid & 63, w = tid >> 6;
    const int quad = lane >> 4, l15 = lane & 15;
    const int row0 = blockIdx.x * 128;
    const int myrow = row0 + w * 16 + l15;
    const bool rok = myrow < n;

    f32x4 acc[12];
    #pragma unroll
    for (int nf = 0; nf < 12; ++nf) acc[nf] = (f32x4){0.f, 0.f, 0.f, 0.f};

    const ushort_t* a1p = A1 + (size_t)myrow * 192 + quad * 8;
    const ushort_t* a2p = A2 + (size_t)myrow * 384 + quad * 8;

    auto stageW = [&](int t, int b) {
        const int k0 = t << 5;
        for (int s = tid; s < 768; s += 512) {
            const int col = s >> 2, part = s & 3;
            *(uint4*)&Ws[b][col * 32 + part * 8] =
                *(const uint4*)(WT + (size_t)col * 576 + k0 + part * 8);
        }
    };
    auto loadA = [&](int t) -> uint4 {
        if (!rok) return make_uint4(0u, 0u, 0u, 0u);
        const ushort_t* p = (t < 6) ? (a1p + t * 32) : (a2p + (t - 6) * 32);
        return *(const uint4*)p;
    };

    uint4 uc;
    stageW(0, 0);
    uc = loadA(0);
    __syncthreads();

    #pragma unroll 2
    for (int t = 0; t < 18; ++t) {
        const int b = t & 1;
        if (t < 17) stageW(t + 1, b ^ 1);
        uint4 un;
        if (t < 17) un = loadA(t + 1);
        const bf16x8 a = __builtin_bit_cast(bf16x8, uc);
        #pragma unroll
        for (int nf = 0; nf < 12; ++nf) {
            const bf16x8 bb = *(const bf16x8*)&Ws[b][(nf * 16 + l15) * 32 + quad * 8];
            acc[nf] = __builtin_amdgcn_mfma_f32_16x16x32_bf16(a, bb, acc[nf], 0, 0, 0);
        }
        __syncthreads();
        if (t < 17) uc = un;
    }

    #pragma unroll
    for (int reg = 0; reg < 4; ++reg) {
        const int lrow = w * 16 + quad * 4 + reg;
        #pragma unroll
        for (int nf = 0; nf < 12; ++nf) {
            const int col = nf * 16 + l15;
            Cs[lrow * VST + col] = f2bf(acc[nf][reg] + bias[col]);
        }
    }
    if (rok) {
        const uint4* vp = (const uint4*)&Cs[(size_t)(w * 16 + l15) * VST];
        uint4* gp = (uint4*)(Cbf + (size_t)myrow * DDIM);
        #pragma unroll
        for (int j = 0; j < 6; ++j) gp[quad * 6 + j] = vp[quad * 6 + j];
    }
}

// ---------------------------------------------------------------------------
// Contrastive similarity, symmetric-triangular: block bid -> tile (ti,tj),
// tj <= ti.  Off-diagonal blocks credit BOTH the i-tile rows (row-side, over
// l15) and the j-tile rows (col-side, over quad) -- S = fn@fn^T is symmetric.
// ---------------------------------------------------------------------------
__global__ __launch_bounds__(256) void sim_mfma(const ushort_t* __restrict__ fnb,
    const int* __restrict__ lab, float* __restrict__ row_ex, float* __restrict__ row_mt)
{
    __shared__ ushort_t Ai[128 * 32];
    __shared__ ushort_t Bj[128 * 32];
    __shared__ int Li[128], Lj[128];
    const int bid = blockIdx.x;
    int ti = (int)((sqrtf(8.0f * (float)bid + 1.0f) - 1.0f) * 0.5f);
    while ((ti + 1) * (ti + 2) / 2 <= bid) ++ti;
    while (ti * (ti + 1) / 2 > bid) --ti;
    const int tj = bid - ti * (ti + 1) / 2;
    const int i0 = ti * 128, j0 = tj * 128;
    const bool offd = (ti != tj);

    const int tid = threadIdx.x, lane = tid & 63, w = tid >> 6;
    const int quad = lane >> 4, l15 = lane & 15;
    if (tid < 128) Li[tid] = lab[i0 + tid];
    else           Lj[tid - 128] = lab[j0 + tid - 128];
    const int iw = (w >> 1) * 64, jw = (w & 1) * 64;

    f32x4 acc[4][4];
    #pragma unroll
    for (int m = 0; m < 4; ++m)
        #pragma unroll
        for (int nf = 0; nf < 4; ++nf)
            acc[m][nf] = (f32x4){0.f, 0.f, 0.f, 0.f};

    for (int k0 = 0; k0 < DDIM; k0 += 32) {
        #pragma unroll
        for (int s = tid; s < 512; s += 256) {
            const int row = s >> 2, part = s & 3;
            *(uint4*)&Ai[row * 32 + part * 8] =
                *(const uint4*)(fnb + (size_t)(i0 + row) * DDIM + k0 + part * 8);
            *(uint4*)&Bj[row * 32 + part * 8] =
                *(const uint4*)(fnb + (size_t)(j0 + row) * DDIM + k0 + part * 8);
        }
        __syncthreads();
        bf16x8 a[4], b[4];
        #pragma unroll
        for (int m = 0; m < 4; ++m)
            a[m] = *(const bf16x8*)&Ai[(iw + m * 16 + l15) * 32 + quad * 8];
        #pragma unroll
        for (int nf = 0; nf < 4; ++nf)
            b[nf] = *(const bf16x8*)&Bj[(jw + nf * 16 + l15) * 32 + quad * 8];
        #pragma unroll
        for (int m = 0; m < 4; ++m)
            #pragma unroll
            for (int nf = 0; nf < 4; ++nf)
                acc[m][nf] = __builtin_amdgcn_mfma_f32_16x16x32_bf16(a[m], b[nf], acc[m][nf], 0, 0, 0);
        __syncthreads();
    }

    int lj[4];
    #pragma unroll
    for (int nf = 0; nf < 4; ++nf) lj[nf] = Lj[jw + nf * 16 + l15];
    float ce[4], cm[4];
    #pragma unroll
    for (int nf = 0; nf < 4; ++nf) { ce[nf] = 0.f; cm[nf] = 0.f; }

    #pragma unroll
    for (int m = 0; m < 4; ++m) {
        #pragma unroll
        for (int reg = 0; reg < 4; ++reg) {
            const int rl = iw + m * 16 + quad * 4 + reg;
            const int li = Li[rl];
            float se = 0.f, sm = 0.f;
            #pragma unroll
            for (int nf = 0; nf < 4; ++nf) {
                const float e = __expf(acc[m][nf][reg] * 2.0f);  // 1/TEMP = 2
                se += e;
                const bool mt = (li == lj[nf]);
                if (mt) sm += e;
                if (offd) {
                    ce[nf] += e;
                    if (mt) cm[nf] += e;
                }
            }
            #pragma unroll
            for (int off = 1; off < 16; off <<= 1) {
                se += __shfl_xor(se, off);
                sm += __shfl_xor(sm, off);
            }
            if (l15 == 0) {
                atomicAdd(&row_ex[i0 + rl], se);
                atomicAdd(&row_mt[i0 + rl], sm);
            }
        }
    }
    if (offd) {
        #pragma unroll
        for (int nf = 0; nf < 4; ++nf) {
            ce[nf] += __shfl_xor(ce[nf], 16); ce[nf] += __shfl_xor(ce[nf], 32);
            cm[nf] += __shfl_xor(cm[nf], 16); cm[nf] += __shfl_xor(cm[nf], 32);
        }
        if (quad == 0) {
            #pragma unroll
            for (int nf = 0; nf < 4; ++nf) {
                atomicAdd(&row_ex[j0 + jw + nf * 16 + l15], ce[nf]);
                atomicAdd(&row_mt[j0 + jw + nf * 16 + l15], cm[nf]);
            }
        }
    }
}

__global__ __launch_bounds__(256) void closs_k(const float* __restrict__ ex,
    const float* __restrict__ mt, float* __restrict__ out)
{
    float s = 0.f;
    for (int i = threadIdx.x; i < TRAIN; i += 256) s += -logf(mt[i] / ex[i]);
    s = wave_sum(s);
    __shared__ float red[4];
    const int wave = threadIdx.x >> 6, lane = threadIdx.x & 63;
    if (lane == 0) red[wave] = s;
    __syncthreads();
    if (threadIdx.x == 0) out[0] = (red[0] + red[1] + red[2] + red[3]) / (float)TRAIN;
}

// ---------------------------------------------------------------------------
// CSR build: counts -> 3-kernel parallel exclusive scan -> fill.
// ---------------------------------------------------------------------------
__global__ __launch_bounds__(256) void cnt_i_k(const int* __restrict__ dst,
    const int* __restrict__ ety, int* __restrict__ cnti)
{
    const int e = blockIdx.x * 256 + threadIdx.x;
    if (e >= EE) return;
    atomicAdd(&cnti[(size_t)ety[e] * NN + dst[e]], 1);
}

__global__ __launch_bounds__(256) void part_k(const int* __restrict__ cnti,
                                              int* __restrict__ part)
{
    __shared__ int sh[256];
    const int tid = threadIdx.x;
    const int i0 = blockIdx.x * 2048 + tid * 8;
    int s = 0;
    #pragma unroll
    for (int j = 0; j < 8; ++j) {
        const int i = i0 + j;
        s += (i < TOTSEG) ? cnti[i] : 0;
    }
    sh[tid] = s;
    __syncthreads();
    #pragma unroll
    for (int off = 128; off > 0; off >>= 1) {
        if (tid < off) sh[tid] += sh[tid + off];
        __syncthreads();
    }
    if (tid == 0) part[blockIdx.x] = sh[0];
}

__global__ __launch_bounds__(128) void scanp_k(int* __restrict__ part)
{
    __shared__ int sh[128];
    const int tid = threadIdx.x;
    const int v = (tid < SCAN_NB) ? part[tid] : 0;
    sh[tid] = v;
    __syncthreads();
    #pragma unroll
    for (int off = 1; off < 128; off <<= 1) {
        const int t = (tid >= off) ? sh[tid - off] : 0;
        __syncthreads();
        sh[tid] += t;
        __syncthreads();
    }
    if (tid < SCAN_NB) part[tid] = sh[tid] - v;   // exclusive
}

__global__ __launch_bounds__(256) void offs_k(const int* __restrict__ cnti,
    const int* __restrict__ part, int* __restrict__ offs)
{
    __shared__ int sh[256];
    const int tid = threadIdx.x;
    const int i0 = blockIdx.x * 2048 + tid * 8;
    int v[8];
    int loc = 0;
    #pragma unroll
    for (int j = 0; j < 8; ++j) {
        const int i = i0 + j;
        v[j] = (i < TOTSEG) ? cnti[i] : 0;
        loc += v[j];
    }
    sh[tid] = loc;
    __syncthreads();
    #pragma unroll
    for (int off = 1; off < 256; off <<= 1) {
        const int t = (tid >= off) ? sh[tid - off] : 0;
        __syncthreads();
        sh[tid] += t;
        __syncthreads();
    }
    int pre = part[blockIdx.x] + sh[tid] - loc;
    #pragma unroll
    for (int j = 0; j < 8; ++j) {
        const int i = i0 + j;
        if (i < TOTSEG) offs[i] = pre;
        pre += v[j];
    }
}

__global__ __launch_bounds__(256) void fill_k(const int* __restrict__ src,
    const int* __restrict__ dst, const int* __restrict__ ety,
    int* __restrict__ offs, int* __restrict__ elist)
{
    const int e = blockIdx.x * 256 + threadIdx.x;
    if (e >= EE) return;
    const int pos = atomicAdd(&offs[(size_t)ety[e] * NN + dst[e]], 1);
    elist[pos] = src[e];
}

// ---------------------------------------------------------------------------
// Gather (bf16 in, bf16 out), one WAVE per SEGMENT (was per node, 2 segs
// serial).  uint-vectorized rows; per-segment accumulation order unchanged.
// ---------------------------------------------------------------------------
__global__ __launch_bounds__(256) void gather_bf_k(const ushort_t* __restrict__ xb,
    const int* __restrict__ elist, const int* __restrict__ offs,
    const int* __restrict__ cnti, ushort_t* __restrict__ aggb)
{
    const int wave = threadIdx.x >> 6, lane = threadIdx.x & 63;
    const int seg = blockIdx.x * 4 + wave;
    if (seg >= TOTSEG) return;
    const int r = (seg < NN) ? 0 : 1;
    const int d = seg - r * NN;
    const bool lo = lane < 32;

    const int end = offs[seg];
    const int c = cnti[seg];
    float a0 = 0.f, a1 = 0.f, b0 = 0.f, b1 = 0.f;
    int e = end - c;
    for (; e + 1 < end; e += 2) {
        const int s0 = elist[e], s1 = elist[e + 1];
        const uint_t* r0 = (const uint_t*)(xb + (size_t)s0 * DDIM);
        const uint_t* r1 = (const uint_t*)(xb + (size_t)s1 * DDIM);
        const uint_t x0 = r0[lane], x1 = r1[lane];
        uint_t y0 = 0u, y1 = 0u;
        if (lo) { y0 = r0[64 + lane]; y1 = r1[64 + lane]; }
        a0 += bf2f((ushort_t)(x0 & 0xffffu)) + bf2f((ushort_t)(x1 & 0xffffu));
        a1 += bf2f((ushort_t)(x0 >> 16))     + bf2f((ushort_t)(x1 >> 16));
        b0 += bf2f((ushort_t)(y0 & 0xffffu)) + bf2f((ushort_t)(y1 & 0xffffu));
        b1 += bf2f((ushort_t)(y0 >> 16))     + bf2f((ushort_t)(y1 >> 16));
    }
    if (e < end) {
        const int s0 = elist[e];
        const uint_t* r0 = (const uint_t*)(xb + (size_t)s0 * DDIM);
        const uint_t x0 = r0[lane];
        uint_t y0 = 0u;
        if (lo) y0 = r0[64 + lane];
        a0 += bf2f((ushort_t)(x0 & 0xffffu));
        a1 += bf2f((ushort_t)(x0 >> 16));
        b0 += bf2f((ushort_t)(y0 & 0xffffu));
        b1 += bf2f((ushort_t)(y0 >> 16));
    }
    const float inv = 1.0f / (float)max(c, 1);
    uint_t* ar = (uint_t*)(aggb + (size_t)d * 384 + r * DDIM);
    ar[lane] = (uint_t)f2bf(a0 * inv) | ((uint_t)f2bf(a1 * inv) << 16);
    if (lo)
        ar[64 + lane] = (uint_t)f2bf(b0 * inv) | ((uint_t)f2bf(b1 * inv) << 16);
}

// ---------------------------------------------------------------------------
extern "C" void kernel_launch(void* const* d_in, const int* in_sizes, int n_in,
                              void* d_out, int out_size, void* d_ws, size_t ws_size,
                              hipStream_t stream)
{
    const float* tweet   = (const float*)d_in[0];
    const float* np_     = (const float*)d_in[1];
    const float* cp      = (const float*)d_in[2];
    const float* Wt      = (const float*)d_in[3];
    const float* bt      = (const float*)d_in[4];
    const float* Wn      = (const float*)d_in[5];
    const float* bnum    = (const float*)d_in[6];
    const float* Wc      = (const float*)d_in[7];
    const float* bc      = (const float*)d_in[8];
    const float* Wv      = (const float*)d_in[9];
    const float* bv      = (const float*)d_in[10];
    const float* Wo      = (const float*)d_in[11];
    const float* bo      = (const float*)d_in[12];
    const float* ln1g    = (const float*)d_in[13];
    const float* ln1b    = (const float*)d_in[14];
    const float* bng     = (const float*)d_in[15];
    const float* bnb     = (const float*)d_in[16];
    const float* W1      = (const float*)d_in[17];
    const float* b1      = (const float*)d_in[18];
    const float* W2      = (const float*)d_in[19];
    const float* b2      = (const float*)d_in[20];
    const float* ln2g    = (const float*)d_in[21];
    const float* ln2b    = (const float*)d_in[22];
    const float* Wrel    = (const float*)d_in[23];
    const float* Wroot   = (const float*)d_in[24];
    const float* rgcnb   = (const float*)d_in[25];
    const float* Wm1     = (const float*)d_in[26];
    const float* bm1     = (const float*)d_in[27];
    const float* Wm2     = (const float*)d_in[28];
    const float* bm2     = (const float*)d_in[29];
    const float* Wm3     = (const float*)d_in[30];
    const float* bm3     = (const float*)d_in[31];
    const int*   eidx    = (const int*)d_in[32];
    const int*   esrc    = eidx;
    const int*   edst    = eidx + EE;
    const int*   ety     = (const int*)d_in[33];
    const int*   labels  = (const int*)d_in[34];
    float* out = (float*)d_out;

    const size_t ND = (size_t)NN * DDIM;
    ushort_t* XBF  = (ushort_t*)d_ws;             // ND  (x / h, bf16)
    ushort_t* X1BF = XBF + ND;                    // ND  (ln1-out, bf16)
    ushort_t* AGGB = X1BF + ND;                   // 2*ND (RGCN gather out)
    ushort_t* FNb  = AGGB + 2 * ND;               // TRAIN*DDIM
    ushort_t* WTt  = FNb + (size_t)TRAIN * DDIM;  // 64x768
    ushort_t* WTs  = WTt + 49152;                 // 29 x 36864 (24/25/26 unused)
    ushort_t* WTg  = WTs + (size_t)29 * 36864;    // 192 x 576
    // zero-init region: CNTI | ROWEX | ROWMT | BNS  (one memset)
    int*   CNTI  = (int*)(WTg + 110592);          // 2*NN
    float* ROWEX = (float*)(CNTI + 2 * NN);       // TRAIN
    float* ROWMT = ROWEX + TRAIN;                 // TRAIN
    float* BNS   = ROWMT + TRAIN;                 // 12*DDIM
    int*   OFFS  = (int*)(BNS + 12 * DDIM);       // 2*NN (becomes end-offsets)
    int*   ELIST = OFFS + 2 * NN;                 // EE
    int*   PART  = ELIST + EE;                    // 128
    ushort_t* WTv  = WTs;
    ushort_t* WTo  = WTs + (size_t)6  * 36864;
    ushort_t* WT1  = WTs + (size_t)12 * 36864;
    ushort_t* WT2  = WTs + (size_t)18 * 36864;
    ushort_t* WTm1 = WTs + (size_t)27 * 36864;
    ushort_t* WTm2 = WTs + (size_t)28 * 36864;

    const int gx = (NN + 127) / 128;   // 782
    const dim3 blk(256);
    const dim3 blk5(512);

    hipMemsetAsync(CNTI, 0, (size_t)(2 * NN + 2 * TRAIN + 12 * DDIM) * 4, stream);
    prep_w<<<29 * 144 + 192, blk, 0, stream>>>(Wt, Wv, Wo, W1, W2, Wrel, Wroot, Wm1, Wm2, WTt, WTs, WTg);

    // ---- CSR build (edge structure only; reused by both RGCN layers)
    cnt_i_k<<<(EE + 255) / 256, blk, 0, stream>>>(edst, ety, CNTI);
    part_k<<<SCAN_NB, blk, 0, stream>>>(CNTI, PART);
    scanp_k<<<1, 128, 0, stream>>>(PART);
    offs_k<<<SCAN_NB, blk, 0, stream>>>(CNTI, PART, OFFS);
    fill_k<<<(EE + 255) / 256, blk, 0, stream>>>(esrc, edst, ety, OFFS, ELIST);

    // ---- input embedding (tweet GEMM + fused num/comments, bf16 x)
    gemm_tweet<<<gx, blk5, 0, stream>>>(tweet, WTt, bt, np_, cp, Wn, bnum, Wc, bc, XBF, NN);

    // ---- 6 layers, each = 2 fused double-GEMMs (BN finalize folded in)
    for (int i = 0; i < NLAYER; ++i) {
        const size_t wo = (size_t)i * 36864;
        float* bnacc_i = BNS + (size_t)i * 2 * DDIM;
        // X1BF = bf16( ln1(x + (x@Wv+bv)@Wo + bo) ), BN-stat accumulate
        gemm2_mfma<false, false, true, true, false, true, true, false, false>
            <<<gx, blk5, 0, stream>>>(
            XBF, WTv + wo, bv + i * DDIM, WTo + wo, bo + i * DDIM, XBF,
            X1BF, nullptr, nullptr, nullptr, bnacc_i,
            ln1g + i * DDIM, ln1b + i * DDIM, nullptr, nullptr, nullptr, nullptr, NN);
        // XBF = bf16( ln2(bn(x1) + lrelu(bn(x1)@W1+b1)@W2 + b2) ); last: +fnorm
        if (i < NLAYER - 1)
            gemm2_mfma<true, false, true, true, true, false, true, false, false>
                <<<gx, blk5, 0, stream>>>(
                X1BF, WT1 + wo, b1 + i * DDIM, WT2 + wo, b2 + i * DDIM, X1BF,
                XBF, bnacc_i, bng + i * DDIM, bnb + i * DDIM, nullptr,
                ln2g + i * DDIM, ln2b + i * DDIM, nullptr, nullptr, nullptr, nullptr, NN);
        else
            gemm2_mfma<true, false, true, true, true, false, true, false, true>
                <<<gx, blk5, 0, stream>>>(
                X1BF, WT1 + wo, b1 + i * DDIM, WT2 + wo, b2 + i * DDIM, X1BF,
                XBF, bnacc_i, bng + i * DDIM, bnb + i * DDIM, nullptr,
                ln2g + i * DDIM, ln2b + i * DDIM, nullptr, nullptr, nullptr, FNb, NN);
    }

    // ---- contrastive loss (fnorm fused above; symmetric-triangular sim)
    sim_mfma<<<(TRAIN / 128) * (TRAIN / 128 + 1) / 2, blk, 0, stream>>>(FNb, labels, ROWEX, ROWMT);
    closs_k<<<1, blk, 0, stream>>>(ROWEX, ROWMT, out + 2 * (size_t)NN);

    // ---- RGCN pass 1: h1 = bf16([x | agg(x)] @ [Wroot;Wcat] + b), in place
    gather_bf_k<<<(TOTSEG + 3) / 4, blk, 0, stream>>>(XBF, ELIST, OFFS, CNTI, AGGB);
    gemm_cat<<<gx, blk5, 0, stream>>>(XBF, AGGB, WTg, rgcnb, XBF, NN);

    // ---- RGCN pass 2
    gather_bf_k<<<(TOTSEG + 3) / 4, blk, 0, stream>>>(XBF, ELIST, OFFS, CNTI, AGGB);
    gemm_cat<<<gx, blk5, 0, stream>>>(XBF, AGGB, WTg, rgcnb, XBF, NN);

    // ---- MLP head fused with logits (bf16 in, direct logits out)
    gemm2_mfma<true, true, false, false, false, false, false, true, false>
        <<<gx, blk5, 0, stream>>>(
        XBF, WTm1, bm1, WTm2, bm2, nullptr, nullptr,
        nullptr, nullptr, nullptr, nullptr, nullptr, nullptr,
        Wm3, bm3, out, nullptr, NN);
}